// Round 15
// baseline (1632.048 us; speedup 1.0000x reference)
//
#include <hip/hip_runtime.h>
#include <hip/hip_bf16.h>
#include <math.h>

#define NTOK 8192
#define DN   1024
#define HN   16
#define HSN  64
#define EN   8
#define DFN  4096
#define TN   1024
#define NQ   8388608u   // B*H*T*HS elements per q/k/v buffer
#define NPB  144        // max 128-row panels (16384 + 8*255 pad, 256-aligned segments)

typedef _Float16 f16x8 __attribute__((ext_vector_type(8)));
typedef _Float16 f16x4 __attribute__((ext_vector_type(4)));
typedef float    f32x4 __attribute__((ext_vector_type(4)));
typedef short    s16x8 __attribute__((ext_vector_type(8)));

#define MFMA_F16(A,B,C)  __builtin_amdgcn_mfma_f32_16x16x32_f16((A),(B),(C),0,0,0)
#define MFMA_BF16(A,B,C) __builtin_amdgcn_mfma_f32_16x16x32_bf16((A),(B),(C),0,0,0)

__device__ __forceinline__ unsigned short f2bf(float f){
  union { float f; unsigned u; } v; v.f = f;
  unsigned r = v.u + 0x7fffu + ((v.u >> 16) & 1u);
  return (unsigned short)(r >> 16);
}
__device__ __forceinline__ void fsplit(float v, _Float16& hi, _Float16& lo){
  hi = (_Float16)v; lo = (_Float16)(v - (float)hi);
}
// async global->LDS, 16B per lane; LDS dest is wave-uniform base (+lane*16 implicit)
__device__ __forceinline__ void gload16(const void* g, void* l){
  __builtin_amdgcn_global_load_lds((const __attribute__((address_space(1))) unsigned int*)g,
                                   (__attribute__((address_space(3))) unsigned int*)l, 16, 0, 0);
}

// ---------------- LN1: x -> h1 panel images (x64, hi/lo) ----------------
__global__ __launch_bounds__(128) void ln1_kernel(
    const float* __restrict__ x, const float* __restrict__ g, const float* __restrict__ be,
    unsigned char* __restrict__ aph, unsigned char* __restrict__ apl)
{
  const int row = blockIdx.x;
  const int t = threadIdx.x;             // 0..127, handles 8 cols
  __shared__ float red[2];
  float4 va = ((const float4*)(x + (size_t)row*DN))[t*2];
  float4 vb = ((const float4*)(x + (size_t)row*DN))[t*2+1];
  float s = va.x+va.y+va.z+va.w + vb.x+vb.y+vb.z+vb.w;
  #pragma unroll
  for (int m = 32; m >= 1; m >>= 1) s += __shfl_xor(s, m);
  if ((t & 63) == 0) red[t >> 6] = s;
  __syncthreads();
  const float mu = (red[0] + red[1]) * (1.0f / DN);
  float e[8] = { va.x-mu, va.y-mu, va.z-mu, va.w-mu, vb.x-mu, vb.y-mu, vb.z-mu, vb.w-mu };
  float s2 = 0.0f;
  #pragma unroll
  for (int i = 0; i < 8; i++) s2 += e[i]*e[i];
  #pragma unroll
  for (int m = 32; m >= 1; m >>= 1) s2 += __shfl_xor(s2, m);
  __syncthreads();
  if ((t & 63) == 0) red[t >> 6] = s2;
  __syncthreads();
  const float var = (red[0] + red[1]) * (1.0f / DN);
  const float rs = 1.0f / sqrtf(var + 1e-5f);
  float4 ga = ((const float4*)g)[t*2], gb = ((const float4*)g)[t*2+1];
  float4 ba = ((const float4*)be)[t*2], bb = ((const float4*)be)[t*2+1];
  float gg[8] = { ga.x,ga.y,ga.z,ga.w, gb.x,gb.y,gb.z,gb.w };
  float bbv[8] = { ba.x,ba.y,ba.z,ba.w, bb.x,bb.y,bb.z,bb.w };
  f16x8 hi8, lo8;
  #pragma unroll
  for (int i = 0; i < 8; i++){
    _Float16 hi, lo; fsplit((e[i]*rs*gg[i] + bbv[i]) * 64.0f, hi, lo);
    hi8[i] = hi; lo8[i] = lo;
  }
  const int pb = row >> 7, r = row & 127, kt = t >> 3, kk8 = t & 7;
  size_t po = ((size_t)(pb*16 + kt))*16384 + r*128 + (size_t)((kk8 ^ (r & 7)) << 4);
  *(f16x8*)(aph + po) = hi8;
  *(f16x8*)(apl + po) = lo8;
}

// ---------------- attention weights -> B panel images (x1024, hi/lo) ----------------
__global__ __launch_bounds__(256) void wsplit_kernel(
    const float* __restrict__ Wq, const float* __restrict__ Wk, const float* __restrict__ Wv,
    const float* __restrict__ Wp,
    unsigned char* __restrict__ bqh, unsigned char* __restrict__ bql,
    unsigned char* __restrict__ bph, unsigned char* __restrict__ bpl)
{
  int b = blockIdx.x;
  const int t = threadIdx.x;
  const int r = t & 127;
  const int c0 = (t >> 7) * 4;     // physical slots c0..c0+3
  if (b < 384){
    int nb = b >> 4, kt = b & 15;
    int n = nb*128 + r;
    int mat = n >> 10, h = (n >> 6) & 15, hs = n & 63;
    const float* W = (mat == 0) ? Wq : ((mat == 1) ? Wk : Wv);
    const float* src = W + (size_t)h*65536 + hs;     // + k*64
    unsigned char* ph = bqh + ((size_t)(nb*16 + kt))*16384 + r*128;
    unsigned char* pl = bql + ((size_t)(nb*16 + kt))*16384 + r*128;
    #pragma unroll
    for (int c = c0; c < c0 + 4; c++){
      int kk8 = c ^ (r & 7);
      f16x8 hi8, lo8;
      #pragma unroll
      for (int j = 0; j < 8; j++){
        _Float16 hi, lo; fsplit(src[(size_t)(kt*64 + kk8*8 + j)*64] * 1024.0f, hi, lo);
        hi8[j] = hi; lo8[j] = lo;
      }
      *(f16x8*)(ph + c*16) = hi8;
      *(f16x8*)(pl + c*16) = lo8;
    }
  } else {
    b -= 384;
    int nb = b >> 4, kt = b & 15;
    int n = nb*128 + r;
    unsigned char* ph = bph + ((size_t)(nb*16 + kt))*16384 + r*128;
    unsigned char* pl = bpl + ((size_t)(nb*16 + kt))*16384 + r*128;
    #pragma unroll
    for (int c = c0; c < c0 + 4; c++){
      int kk8 = c ^ (r & 7);
      f16x8 hi8, lo8;
      #pragma unroll
      for (int j = 0; j < 8; j++){
        _Float16 hi, lo; fsplit(Wp[(size_t)(kt*64 + kk8*8 + j)*DN + n] * 1024.0f, hi, lo);
        hi8[j] = hi; lo8[j] = lo;
      }
      *(f16x8*)(ph + c*16) = hi8;
      *(f16x8*)(pl + c*16) = lo8;
    }
  }
}

// ---------------- QKV GEMM: 128x128, fused 3-product split (one K pass) ----------------
// V (mat==2) is written TRANSPOSED: [b,h,hs,t] so attention can stage V^T vectorized.
__global__ __launch_bounds__(256) void qkv_gemm_kernel(
    const unsigned char* __restrict__ aph, const unsigned char* __restrict__ apl,
    const unsigned char* __restrict__ bqh, const unsigned char* __restrict__ bql,
    _Float16* __restrict__ qkvout)
{
  const int mb = blockIdx.x;    // 0..63
  const int nb = blockIdx.y;    // 0..23
  __shared__ __align__(16) unsigned char Ah[16384], Al[16384], Bh[16384], Bl[16384];
  const int t = threadIdx.x, w = t >> 6, lane = t & 63, lg = lane >> 4, lr = lane & 15;
  const int wr = w >> 1, wc = w & 1;
  const unsigned char* sb;
  unsigned char* dp;
  if (w == 0){ sb = aph + ((size_t)(mb*16))*16384; dp = Ah; }
  else if (w == 1){ sb = apl + ((size_t)(mb*16))*16384; dp = Al; }
  else if (w == 2){ sb = bqh + ((size_t)(nb*16))*16384; dp = Bh; }
  else { sb = bql + ((size_t)(nb*16))*16384; dp = Bl; }
  sb += lane*16;
  f32x4 acc[4][4] = {};
  for (int kt = 0; kt < 16; kt++){
    const unsigned char* s2 = sb + (size_t)kt*16384;
    #pragma unroll
    for (int j = 0; j < 16; j++) gload16(s2 + j*1024, dp + j*1024);
    __syncthreads();
    #pragma unroll
    for (int ks = 0; ks < 2; ks++){
      f16x8 ah[4], al[4], bh[4], bl[4];
      #pragma unroll
      for (int f = 0; f < 4; f++){
        int ra = wr*64 + f*16 + lr;
        int off = (ks*64 + lg*16) ^ ((ra & 7) << 4);
        ah[f] = *(const f16x8*)(Ah + ra*128 + off);
        al[f] = *(const f16x8*)(Al + ra*128 + off);
      }
      #pragma unroll
      for (int f = 0; f < 4; f++){
        int rb = wc*64 + f*16 + lr;
        int off = (ks*64 + lg*16) ^ ((rb & 7) << 4);
        bh[f] = *(const f16x8*)(Bh + rb*128 + off);
        bl[f] = *(const f16x8*)(Bl + rb*128 + off);
      }
      #pragma unroll
      for (int fm = 0; fm < 4; fm++)
      #pragma unroll
      for (int fn = 0; fn < 4; fn++){
        acc[fm][fn] = MFMA_F16(ah[fm], bh[fn], acc[fm][fn]);
        acc[fm][fn] = MFMA_F16(al[fm], bh[fn], acc[fm][fn]);
        acc[fm][fn] = MFMA_F16(ah[fm], bl[fn], acc[fm][fn]);
      }
    }
    __syncthreads();
  }
  #pragma unroll
  for (int fm = 0; fm < 4; fm++)
  #pragma unroll
  for (int fn = 0; fn < 4; fn++)
  #pragma unroll
  for (int rr = 0; rr < 4; rr++){
    int m = mb*128 + wr*64 + fm*16 + lg*4 + rr;
    int n = nb*128 + wc*64 + fn*16 + lr;
    int mat = n >> 10, h = (n >> 6) & 15, hs = n & 63;
    int bb = m >> 10, tt = m & 1023;
    _Float16* dsthi = qkvout + (size_t)mat * 2u * NQ;
    _Float16* dstlo = dsthi + NQ;
    size_t oi;
    if (mat == 2)  // V transposed: [b][h][hs][t]
      oi = (((size_t)(bb*HN + h))*HSN + hs)*TN + tt;
    else
      oi = (((size_t)(bb*HN + h))*TN + tt)*HSN + hs;
    _Float16 hi, lo; fsplit(acc[fm][fn][rr] * (1.0f/1024.0f), hi, lo);  // = 64*q
    dsthi[oi] = hi; dstlo[oi] = lo;
  }
}

// ---------------- flash attention (split f16, V^T input) ----------------
__global__ __launch_bounds__(256) void attn_kernel(
    const _Float16* __restrict__ qkv,
    _Float16* __restrict__ ohi_, _Float16* __restrict__ olo_)
{
  const _Float16* qhi = qkv;
  const _Float16* qlo = qkv + NQ;
  const _Float16* khi = qkv + 2u*NQ;
  const _Float16* klo = qkv + 3u*NQ;
  const _Float16* vhi = qkv + 4u*NQ;   // layout [b,h,hs,t]
  const _Float16* vlo = qkv + 5u*NQ;
  const int qt = blockIdx.x;     // 0..15
  const int bh = blockIdx.y;     // 0..127
  const size_t base = (size_t)bh * TN * HSN;   // same element count for V^T
  const int t = threadIdx.x, wid = t >> 6, lane = t & 63, lg = lane >> 4, lr = lane & 15;
  __shared__ _Float16 Khi[64][72], Klo[64][72], Vthi[64][72], Vtlo[64][72], Phi[64][72], Plo[64][72];
  f16x8 qh[2], ql[2];
  {
    const int qrow = qt*64 + wid*16 + lr;
    const _Float16* qp  = qhi + base + (size_t)qrow*HSN;
    const _Float16* qpl = qlo + base + (size_t)qrow*HSN;
    #pragma unroll
    for (int c = 0; c < 2; c++){
      qh[c] = *(const f16x8*)(qp  + c*32 + lg*8);
      ql[c] = *(const f16x8*)(qpl + c*32 + lg*8);
    }
  }
  f32x4 oacc[4] = {};
  float mrow[4], lsum[4];
  #pragma unroll
  for (int r = 0; r < 4; r++){ mrow[r] = -INFINITY; lsum[r] = 0.0f; }
  const int sr = t >> 2, sc = (t & 3) * 16;
  const float sscale = 1.0f / (4096.0f * 32.0f);
  for (int kvt = 0; kvt <= qt; kvt++){
    {
      const size_t gr = base + (size_t)(kvt*64 + sr)*HSN + sc;
      *(f16x8*)&Khi[sr][sc]     = *(const f16x8*)(khi + gr);
      *(f16x8*)&Khi[sr][sc + 8] = *(const f16x8*)(khi + gr + 8);
      *(f16x8*)&Klo[sr][sc]     = *(const f16x8*)(klo + gr);
      *(f16x8*)&Klo[sr][sc + 8] = *(const f16x8*)(klo + gr + 8);
      // V^T: row sr = hs, cols = t within tile (vectorized, no transpose)
      const size_t gv = base + (size_t)sr*TN + kvt*64 + sc;
      *(f16x8*)&Vthi[sr][sc]     = *(const f16x8*)(vhi + gv);
      *(f16x8*)&Vthi[sr][sc + 8] = *(const f16x8*)(vhi + gv + 8);
      *(f16x8*)&Vtlo[sr][sc]     = *(const f16x8*)(vlo + gv);
      *(f16x8*)&Vtlo[sr][sc + 8] = *(const f16x8*)(vlo + gv + 8);
    }
    __syncthreads();
    f32x4 sacc[4] = {};
    #pragma unroll
    for (int c = 0; c < 2; c++)
    #pragma unroll
    for (int fn = 0; fn < 4; fn++){
      f16x8 kh = *(const f16x8*)&Khi[fn*16 + lr][c*32 + lg*8];
      f16x8 kl = *(const f16x8*)&Klo[fn*16 + lr][c*32 + lg*8];
      sacc[fn] = MFMA_F16(qh[c], kh, sacc[fn]);
      sacc[fn] = MFMA_F16(qh[c], kl, sacc[fn]);
      sacc[fn] = MFMA_F16(ql[c], kh, sacc[fn]);
    }
    float sv[4][4], pmax[4];
    #pragma unroll
    for (int r = 0; r < 4; r++) pmax[r] = -INFINITY;
    const int qg0 = qt*64 + wid*16 + lg*4;
    #pragma unroll
    for (int fn = 0; fn < 4; fn++)
    #pragma unroll
    for (int r = 0; r < 4; r++){
      float xv = sacc[fn][r] * sscale;
      int kvg = kvt*64 + fn*16 + lr;
      xv = (kvg <= qg0 + r) ? xv : -INFINITY;
      sv[fn][r] = xv;
      pmax[r] = fmaxf(pmax[r], xv);
    }
    #pragma unroll
    for (int r = 0; r < 4; r++){
      #pragma unroll
      for (int m = 1; m < 16; m <<= 1) pmax[r] = fmaxf(pmax[r], __shfl_xor(pmax[r], m));
    }
    float alpha[4], mnew[4], psum[4];
    #pragma unroll
    for (int r = 0; r < 4; r++){
      mnew[r] = fmaxf(mrow[r], pmax[r]);
      alpha[r] = __expf(mrow[r] - mnew[r]);
      psum[r] = 0.0f;
    }
    #pragma unroll
    for (int fn = 0; fn < 4; fn++)
    #pragma unroll
    for (int r = 0; r < 4; r++){
      float p = __expf(sv[fn][r] - mnew[r]);
      psum[r] += p;
      _Float16 hi, lo; fsplit(p * 512.0f, hi, lo);
      Phi[wid*16 + lg*4 + r][fn*16 + lr] = hi;
      Plo[wid*16 + lg*4 + r][fn*16 + lr] = lo;
    }
    #pragma unroll
    for (int r = 0; r < 4; r++){
      #pragma unroll
      for (int m = 1; m < 16; m <<= 1) psum[r] += __shfl_xor(psum[r], m);
      lsum[r] = lsum[r]*alpha[r] + psum[r];
      mrow[r] = mnew[r];
    }
    #pragma unroll
    for (int fn = 0; fn < 4; fn++)
    #pragma unroll
    for (int r = 0; r < 4; r++) oacc[fn][r] *= alpha[r];
    #pragma unroll
    for (int c2 = 0; c2 < 2; c2++){
      f16x8 ph = *(const f16x8*)&Phi[wid*16 + lr][c2*32 + lg*8];
      f16x8 pl = *(const f16x8*)&Plo[wid*16 + lr][c2*32 + lg*8];
      #pragma unroll
      for (int fn = 0; fn < 4; fn++){
        f16x8 vh = *(const f16x8*)&Vthi[fn*16 + lr][c2*32 + lg*8];
        f16x8 vl = *(const f16x8*)&Vtlo[fn*16 + lr][c2*32 + lg*8];
        oacc[fn] = MFMA_F16(ph, vh, oacc[fn]);
        oacc[fn] = MFMA_F16(ph, vl, oacc[fn]);
        oacc[fn] = MFMA_F16(pl, vh, oacc[fn]);
      }
    }
    __syncthreads();
  }
  const int bb = bh >> 4, hh = bh & 15;
  #pragma unroll
  for (int fn = 0; fn < 4; fn++)
  #pragma unroll
  for (int r = 0; r < 4; r++){
    float ov = oacc[fn][r] / (32768.0f * lsum[r]);   // 512*64 scale
    int m = qt*64 + wid*16 + lg*4 + r;
    size_t oi = ((size_t)(bb*TN + m))*DN + hh*HSN + fn*16 + lr;
    _Float16 hi, lo; fsplit(ov * 64.0f, hi, lo);
    ohi_[oi] = hi; olo_[oi] = lo;
  }
}

// ---------------- proj GEMM + residual: 128x128, fused 3-product split -----------------
__global__ __launch_bounds__(256) void proj_gemm_kernel(
    const _Float16* __restrict__ ohi, const _Float16* __restrict__ olo,
    const unsigned char* __restrict__ bph, const unsigned char* __restrict__ bpl,
    const float* __restrict__ x, const float* __restrict__ bproj,
    float* __restrict__ out)
{
  const int mb = blockIdx.x;    // 0..63
  const int nb = blockIdx.y;    // 0..7
  __shared__ __align__(16) unsigned char Ah[16384], Al[16384], Bh[16384], Bl[16384];
  const int t = threadIdx.x, w = t >> 6, lane = t & 63, lg = lane >> 4, lr = lane & 15;
  const int wr = w >> 1, wc = w & 1;
  f32x4 acc[4][4] = {};
  const unsigned char* sbB = ((w == 2) ? bph : bpl) + ((size_t)(nb*16))*16384 + lane*16;
  unsigned char* dpB = (w == 2) ? Bh : Bl;
  const _Float16* aSrc = (w == 0) ? ohi : olo;
  unsigned char* dpA = (w == 0) ? Ah : Al;
  const int rA = lane >> 3;          // + j*8
  const int cA = lane & 7;
  for (int kt = 0; kt < 16; kt++){
    if (w < 2){
      #pragma unroll
      for (int j = 0; j < 16; j++){
        int r = rA + j*8;
        const unsigned char* s2 = (const unsigned char*)(aSrc + (size_t)(mb*128 + r)*DN)
                                  + kt*128 + ((cA ^ (r & 7)) << 4);
        gload16(s2, dpA + j*1024);
      }
    } else {
      const unsigned char* s2 = sbB + (size_t)kt*16384;
      #pragma unroll
      for (int j = 0; j < 16; j++) gload16(s2 + j*1024, dpB + j*1024);
    }
    __syncthreads();
    #pragma unroll
    for (int ks = 0; ks < 2; ks++){
      f16x8 ah[4], al[4], bh[4], bl[4];
      #pragma unroll
      for (int f = 0; f < 4; f++){
        int ra = wr*64 + f*16 + lr;
        int off = (ks*64 + lg*16) ^ ((ra & 7) << 4);
        ah[f] = *(const f16x8*)(Ah + ra*128 + off);
        al[f] = *(const f16x8*)(Al + ra*128 + off);
      }
      #pragma unroll
      for (int f = 0; f < 4; f++){
        int rb = wc*64 + f*16 + lr;
        int off = (ks*64 + lg*16) ^ ((rb & 7) << 4);
        bh[f] = *(const f16x8*)(Bh + rb*128 + off);
        bl[f] = *(const f16x8*)(Bl + rb*128 + off);
      }
      #pragma unroll
      for (int fm = 0; fm < 4; fm++)
      #pragma unroll
      for (int fn = 0; fn < 4; fn++){
        acc[fm][fn] = MFMA_F16(ah[fm], bh[fn], acc[fm][fn]);
        acc[fm][fn] = MFMA_F16(al[fm], bh[fn], acc[fm][fn]);
        acc[fm][fn] = MFMA_F16(ah[fm], bl[fn], acc[fm][fn]);
      }
    }
    __syncthreads();
  }
  #pragma unroll
  for (int fm = 0; fm < 4; fm++)
  #pragma unroll
  for (int fn = 0; fn < 4; fn++)
  #pragma unroll
  for (int rr = 0; rr < 4; rr++){
    int m = mb*128 + wr*64 + fm*16 + lg*4 + rr;
    int n = nb*128 + wc*64 + fn*16 + lr;
    size_t oi = (size_t)m*DN + n;
    out[oi] = x[oi] + acc[fm][fn][rr] * (1.0f/65536.0f) + bproj[n];
  }
}

// ---------------- router: LN2 (fp32) + logits + noisy top-2 + h2(bf16) ----------------
__global__ __launch_bounds__(256) void router_kernel(
    const float* __restrict__ x1, const float* __restrict__ g, const float* __restrict__ be,
    const float* __restrict__ Wr, const float* __restrict__ br,
    const float* __restrict__ Wn, const float* __restrict__ bn,
    const float* __restrict__ noise, unsigned short* __restrict__ h2bf,
    int* __restrict__ topk_e, float* __restrict__ topk_g, int* __restrict__ counts)
{
  const int token = blockIdx.x;
  const int t = threadIdx.x;
  __shared__ float redsum[4];
  __shared__ float red[64];
  float4 v = ((const float4*)(x1 + (size_t)token * DN))[t];
  float s = v.x + v.y + v.z + v.w;
  #pragma unroll
  for (int m = 32; m >= 1; m >>= 1) s += __shfl_xor(s, m);
  if ((t & 63) == 0) redsum[t >> 6] = s;
  __syncthreads();
  const float mu = (redsum[0] + redsum[1] + redsum[2] + redsum[3]) * (1.0f / DN);
  const float d0 = v.x - mu, d1 = v.y - mu, d2 = v.z - mu, d3 = v.w - mu;
  float s2 = d0*d0 + d1*d1 + d2*d2 + d3*d3;
  #pragma unroll
  for (int m = 32; m >= 1; m >>= 1) s2 += __shfl_xor(s2, m);
  __syncthreads();
  if ((t & 63) == 0) redsum[t >> 6] = s2;
  __syncthreads();
  const float var = (redsum[0] + redsum[1] + redsum[2] + redsum[3]) * (1.0f / DN);
  const float rs = 1.0f / sqrtf(var + 1e-5f);
  float4 gv = ((const float4*)g)[t];
  float4 bv = ((const float4*)be)[t];
  float h0 = d0*rs*gv.x + bv.x, h1v = d1*rs*gv.y + bv.y, h2v = d2*rs*gv.z + bv.z, h3 = d3*rs*gv.w + bv.w;
  ushort4 hb;
  hb.x = f2bf(h0); hb.y = f2bf(h1v); hb.z = f2bf(h2v); hb.w = f2bf(h3);
  *(ushort4*)(h2bf + (size_t)token*DN + t*4) = hb;
  float acc[16];
  const int j = t * 4;
  #pragma unroll
  for (int e = 0; e < 8; e++){
    acc[e]     = h0*Wr[(j+0)*8+e] + h1v*Wr[(j+1)*8+e] + h2v*Wr[(j+2)*8+e] + h3*Wr[(j+3)*8+e];
    acc[8 + e] = h0*Wn[(j+0)*8+e] + h1v*Wn[(j+1)*8+e] + h2v*Wn[(j+2)*8+e] + h3*Wn[(j+3)*8+e];
  }
  #pragma unroll
  for (int q = 0; q < 16; q++){
    #pragma unroll
    for (int m = 32; m >= 1; m >>= 1) acc[q] += __shfl_xor(acc[q], m);
  }
  if ((t & 63) == 0){
    #pragma unroll
    for (int q = 0; q < 16; q++) red[(t >> 6)*16 + q] = acc[q];
  }
  __syncthreads();
  if (t < 16) red[t] = red[t] + red[16 + t] + red[32 + t] + red[48 + t];
  __syncthreads();
  if (t == 0){
    float nz[8];
    #pragma unroll
    for (int e = 0; e < 8; e++){
      float logit = red[e] + br[e];
      float a = red[8 + e] + bn[e];
      float sp = (a > 20.0f) ? a : log1pf(expf(a));
      nz[e] = logit + noise[(size_t)token*EN + e] * sp;
    }
    float v1 = -INFINITY, v2 = -INFINITY; int i1 = 0, i2 = 0;
    #pragma unroll
    for (int e = 0; e < 8; e++){
      float z = nz[e];
      if (z > v1){ v2 = v1; i2 = i1; v1 = z; i1 = e; }
      else if (z > v2){ v2 = z; i2 = e; }
    }
    float e2 = expf(v2 - v1);
    float den = 1.0f + e2;
    topk_e[token*2]     = i1; topk_e[token*2 + 1] = i2;
    topk_g[token*2]     = 1.0f/den; topk_g[token*2 + 1] = e2/den;
    atomicAdd(&counts[i1], 1); atomicAdd(&counts[i2], 1);
  }
}

// 256-aligned expert segment offsets (moe tiles are 256 rows)
__global__ void scan_kernel(const int* __restrict__ counts, int* __restrict__ offs)
{
  if (threadIdx.x == 0 && blockIdx.x == 0){
    int a = 0;
    for (int e = 0; e < EN; e++){ offs[e] = a; a += (counts[e] + 255) & ~255; }
  }
}

__global__ __launch_bounds__(256) void scatter_kernel(
    const int* __restrict__ topk_e, const float* __restrict__ topk_g,
    const int* __restrict__ offs, int* __restrict__ fill,
    int* __restrict__ rows, float* __restrict__ grow)
{
  const int token = blockIdx.x*256 + threadIdx.x;
  #pragma unroll
  for (int i = 0; i < 2; i++){
    int e = topk_e[token*2 + i];
    int pos = offs[e] + atomicAdd(&fill[e], 1);
    rows[pos] = token;
    grow[pos] = topk_g[token*2 + i];
  }
}

// ---------------- expert weights -> 16KB LDS-image panels (bf16, swizzle baked) --------
__global__ __launch_bounds__(256) void wconv_kernel(
    const float* __restrict__ W1, const float* __restrict__ W2,
    unsigned char* __restrict__ w1p, unsigned char* __restrict__ w2p)
{
  int b = blockIdx.x;
  const float* W; unsigned char* pan; int Nd, kt, n;
  if (b < 2048){
    int e = b >> 8, rem = b & 255, nb2 = rem >> 4; kt = rem & 15;
    n = nb2*256 + threadIdx.x;                       // 0..4095
    W = W1 + (size_t)e * DN * DFN; Nd = DFN;
    pan = w1p + (((size_t)e*32 + (n >> 7))*16 + kt) * 16384;
  } else {
    b -= 2048;
    int e = b >> 8, rem = b & 255, nb2 = rem >> 6; kt = rem & 63;
    n = nb2*256 + threadIdx.x;                       // 0..1023
    W = W2 + (size_t)e * DFN * DN; Nd = DN;
    pan = w2p + (((size_t)e*8 + (n >> 7))*64 + kt) * 16384;
  }
  const int r = n & 127;
  #pragma unroll
  for (int kk8 = 0; kk8 < 8; kk8++){
    union { unsigned short u[8]; uint4 v; } buf;
    #pragma unroll
    for (int j = 0; j < 8; j++)
      buf.u[j] = f2bf(W[(size_t)(kt*64 + kk8*8 + j)*Nd + n]);
    *(uint4*)(pan + r*128 + ((kk8 ^ (r & 7)) << 4)) = buf.v;
  }
}

// ---------------- gather tokens into A panels: apnl[pb][kt16][16KB image] ----------------
__global__ __launch_bounds__(256) void agather_kernel(
    const unsigned short* __restrict__ h2bf, const int* __restrict__ rows,
    unsigned char* __restrict__ apnl)
{
  const int pb = blockIdx.x, kt = blockIdx.y;
  const int t = threadIdx.x;
  const int r = t >> 1, c0 = (t & 1) * 4;
  const int tok = rows[pb*128 + r];
  const unsigned char* src = (const unsigned char*)h2bf + (size_t)tok*2048 + kt*128;
  unsigned char* dst = apnl + ((size_t)pb*16 + kt)*16384 + r*128;
  #pragma unroll
  for (int i = 0; i < 4; i++){
    int c = c0 + i;
    *(uint4*)(dst + ((c ^ (r & 7)) << 4)) = *(const uint4*)(src + c*16);
  }
}

// ---------------- MoE GEMM1: 512 blocks (2/CU), 64KB single-buffer, XCD-pinned window ---
// e = bid&7, slot c = bid>>3 in 0..63; chunks q = c, c+64, ...
// decode: grp = q/(4*nmb); within = q%(4*nmb); mb = within>>2; nb = grp*4 + (within&3).
__global__ __launch_bounds__(512, 1) void moe1_kernel(
    const unsigned char* __restrict__ apnl, const unsigned char* __restrict__ w1p,
    const float* __restrict__ b1,
    const int* __restrict__ counts, const int* __restrict__ offs,
    unsigned short* __restrict__ midP)
{
  __shared__ __align__(16) unsigned char As[32768], Bs[32768];
  const int bid = blockIdx.x;
  const int t = threadIdx.x;
  const int w = t >> 6, lane = t & 63, lg = lane >> 4, lr = lane & 15;
  const int wm = w >> 2, wn = w & 3;
  const int sp = (w >> 1) & 1, sh = (w & 1) * 8192;
  const int e = bid & 7;
  const int c = bid >> 3;                  // 0..63
  const int cnt = counts[e], off = offs[e];
  const int nmb = (cnt + 255) >> 8;
  const int nch = nmb * 16;
  for (int q = c; q < nch; q += 64){
    const int grp = q / (4*nmb);
    const int within = q - grp*4*nmb;
    const int mb = within >> 2;
    const int nb = grp*4 + (within & 3);
    const int m0 = mb * 256;
    const int pb0 = (off + m0) >> 7;
    const unsigned char* sbase;
    unsigned char* dbase;
    if (w < 4){
      sbase = apnl + ((size_t)(pb0 + sp) * 16) * 16384 + sh + lane*16;
      dbase = As + sp*16384 + sh;
    } else {
      sbase = w1p + ((size_t)(e*32 + nb*2 + sp) * 16) * 16384 + sh + lane*16;
      dbase = Bs + sp*16384 + sh;
    }
    f32x4 acc[8][4] = {};
    for (int kt = 0; kt < 16; kt++){
      const unsigned char* s2 = sbase + (size_t)kt * 16384;
      #pragma unroll
      for (int j = 0; j < 8; j++) gload16(s2 + j*1024, dbase + j*1024);
      __syncthreads();
      const unsigned char* pA = As + wm*16384;
      const unsigned char* pB = Bs + (wn>>1)*16384;
      #pragma unroll
      for (int ks = 0; ks < 2; ks++){
        s16x8 b[4], a[8];
        #pragma unroll
        for (int f = 0; f < 4; f++){
          int rb = (wn&1)*64 + f*16 + lr;
          b[f] = *(const s16x8*)(pB + rb*128 + ((ks*64 + lg*16) ^ ((rb&7)<<4)));
        }
        #pragma unroll
        for (int f = 0; f < 8; f++){
          int ra = f*16 + lr;
          a[f] = *(const s16x8*)(pA + ra*128 + ((ks*64 + lg*16) ^ ((ra&7)<<4)));
        }
        __builtin_amdgcn_s_setprio(1);
        #pragma unroll
        for (int fm = 0; fm < 8; fm++)
        #pragma unroll
        for (int fn = 0; fn < 4; fn++)
          acc[fm][fn] = MFMA_BF16(a[fm], b[fn], acc[fm][fn]);
        __builtin_amdgcn_s_setprio(0);
      }
      __syncthreads();
    }
    // epilogue: two row-half passes through 64KB LDS, then linear full-line stores
    #pragma unroll
    for (int p = 0; p < 2; p++){
      if (wm == p){
        unsigned char* Lp = (wn < 2) ? (As + wn*16384) : (Bs + (wn-2)*16384);
        const float* b1e = b1 + (size_t)e*DFN + nb*256 + wn*64;
        #pragma unroll
        for (int fn = 0; fn < 4; fn++){
          float bias = b1e[fn*16 + lr];
          int col = fn*16 + lr;
          #pragma unroll
          for (int fm = 0; fm < 8; fm++)
          #pragma unroll
          for (int rr = 0; rr < 4; rr++){
            int r = fm*16 + lg*4 + rr;
            float v = fmaxf(acc[fm][fn][rr] + bias, 0.0f);
            *(unsigned short*)(Lp + r*128 + ((col ^ ((r & 7) << 3)) * 2)) = f2bf(v);
          }
        }
      }
      __syncthreads();
      {
        int panel = w >> 1, half = w & 1;
        const uint4* src = (const uint4*)(((panel < 2) ? (As + panel*16384) : (Bs + (panel-2)*16384)) + half*8192);
        uint4* dst = (uint4*)((unsigned char*)midP + (((size_t)(pb0 + p)*64) + nb*4 + panel)*16384 + half*8192);
        #pragma unroll
        for (int i = 0; i < 8; i++) dst[lane + i*64] = src[lane + i*64];
      }
      __syncthreads();
    }
  }
}

// ---------------- MoE GEMM2: 512 blocks (2/CU), 64KB single-buffer, 2-way K-split -------
// decode: nb = q&3; kh = (q>>2)&1; mb = q>>3.  32 kt per chunk; bias added at kh==0.
__global__ __launch_bounds__(512, 1) void moe2_kernel(
    const unsigned char* __restrict__ midP, const unsigned char* __restrict__ w2p,
    const float* __restrict__ b2,
    const int* __restrict__ counts, const int* __restrict__ offs,
    const int* __restrict__ rows, const float* __restrict__ grow,
    float* __restrict__ out)
{
  __shared__ __align__(16) unsigned char As[32768], Bs[32768];
  const int bid = blockIdx.x;
  const int t = threadIdx.x;
  const int w = t >> 6, lane = t & 63, lg = lane >> 4, lr = lane & 15;
  const int wm = w >> 2, wn = w & 3;
  const int sp = (w >> 1) & 1, sh = (w & 1) * 8192;
  const int e = bid & 7;
  const int c = bid >> 3;                  // 0..63
  const int cnt = counts[e], off = offs[e];
  const int nmb = (cnt + 255) >> 8;
  const int nch = nmb * 8;
  for (int q = c; q < nch; q += 64){
    const int nb = q & 3;
    const int kh = (q >> 2) & 1;
    const int mb = q >> 3;
    const int m0 = mb * 256;
    const int pb0 = (off + m0) >> 7;
    const unsigned char* sbase;
    unsigned char* dbase;
    if (w < 4){
      sbase = midP + (((size_t)(pb0 + sp))*64 + kh*32)*16384 + sh + lane*16;
      dbase = As + sp*16384 + sh;
    } else {
      sbase = w2p + (((size_t)(e*8 + nb*2 + sp))*64 + kh*32)*16384 + sh + lane*16;
      dbase = Bs + sp*16384 + sh;
    }
    f32x4 acc[8][4] = {};
    for (int kt = 0; kt < 32; kt++){
      const unsigned char* s2 = sbase + (size_t)kt * 16384;
      #pragma unroll
      for (int j = 0; j < 8; j++) gload16(s2 + j*1024, dbase + j*1024);
      __syncthreads();
      const unsigned char* pA = As + wm*16384;
      const unsigned char* pB = Bs + (wn>>1)*16384;
      #pragma unroll
      for (int ks = 0; ks < 2; ks++){
        s16x8 b[4], a[8];
        #pragma unroll
        for (int f = 0; f < 4; f++){
          int rb = (wn&1)*64 + f*16 + lr;
          b[f] = *(const s16x8*)(pB + rb*128 + ((ks*64 + lg*16) ^ ((rb&7)<<4)));
        }
        #pragma unroll
        for (int f = 0; f < 8; f++){
          int ra = f*16 + lr;
          a[f] = *(const s16x8*)(pA + ra*128 + ((ks*64 + lg*16) ^ ((ra&7)<<4)));
        }
        __builtin_amdgcn_s_setprio(1);
        #pragma unroll
        for (int fm = 0; fm < 8; fm++)
        #pragma unroll
        for (int fn = 0; fn < 4; fn++)
          acc[fm][fn] = MFMA_BF16(a[fm], b[fn], acc[fm][fn]);
        __builtin_amdgcn_s_setprio(0);
      }
      __syncthreads();
    }
    const float* b2e = b2 + (size_t)e*DN + nb*256 + wn*64;
    #pragma unroll
    for (int fm = 0; fm < 8; fm++)
    #pragma unroll
    for (int rr = 0; rr < 4; rr++){
      int ml = wm*128 + fm*16 + lg*4 + rr;
      if (m0 + ml < cnt){
        int gi = off + m0 + ml;
        int tok = rows[gi];
        float gt = grow[gi];
        #pragma unroll
        for (int fn = 0; fn < 4; fn++){
          int n = nb*256 + wn*64 + fn*16 + lr;
          float bias = (kh == 0) ? b2e[fn*16 + lr] : 0.0f;
          atomicAdd(out + (size_t)tok*DN + n, gt*(acc[fm][fn][rr] + bias));
        }
      }
    }
    __syncthreads();   // outputs drained before next chunk's staging overwrites LDS
  }
}

// ---------------- launch ----------------
extern "C" void kernel_launch(void* const* d_in, const int* in_sizes, int n_in,
                              void* d_out, int out_size, void* d_ws, size_t ws_size,
                              hipStream_t stream) {
  (void)in_sizes; (void)n_in; (void)out_size; (void)ws_size;
  const float* x     = (const float*)d_in[0];
  const float* noise = (const float*)d_in[1];
  const float* Wq    = (const float*)d_in[2];
  const float* Wk    = (const float*)d_in[3];
  const float* Wv    = (const float*)d_in[4];
  const float* Wp    = (const float*)d_in[5];
  const float* bproj = (const float*)d_in[6];
  const float* ln1g  = (const float*)d_in[7];
  const float* ln1b  = (const float*)d_in[8];
  const float* ln2g  = (const float*)d_in[9];
  const float* ln2b  = (const float*)d_in[10];
  const float* Wr    = (const float*)d_in[11];
  const float* br    = (const float*)d_in[12];
  const float* Wn    = (const float*)d_in[13];
  const float* bn    = (const float*)d_in[14];
  const float* W1    = (const float*)d_in[15];
  const float* b1    = (const float*)d_in[16];
  const float* W2    = (const float*)d_in[17];
  const float* b2    = (const float*)d_in[18];
  float* out = (float*)d_out;

  char* w = (char*)d_ws;
  auto alloc = [&](size_t bytes) -> char* {
    char* p = w; w += (bytes + 255) & ~(size_t)255; return p;
  };
  // Region A: qkv split + o split during attention; reused as panelized `mid` during MoE.
  char* big = alloc((size_t)NPB * 64 * 16384);          // 151 MB >= 134.2 MB qkv need
  _Float16* qkvsplit = (_Float16*)big;
  _Float16* ohi = (_Float16*)(big + (size_t)6*NQ*2);
  _Float16* olo = ohi + NQ;
  unsigned short* midP = (unsigned short*)big;
  // Region B: attention temporaries (dead after proj); W1 panels overlay them afterwards.
  char* attn_tmp = w;
  unsigned char* aph = (unsigned char*)alloc((size_t)64*16*16384);   // h1 hi panels 16 MB
  unsigned char* apl = (unsigned char*)alloc((size_t)64*16*16384);   // h1 lo panels 16 MB
  unsigned char* bqh = (unsigned char*)alloc((size_t)24*16*16384);   // qkv W hi panels 6.3 MB
  unsigned char* bql = (unsigned char*)alloc((size_t)24*16*16384);
  unsigned char* bph = (unsigned char*)alloc((size_t)8*16*16384);    // proj W hi panels 2.1 MB
  unsigned char* bpl = (unsigned char*)alloc((size_t)8*16*16384);
  unsigned char* w1p = (unsigned char*)attn_tmp;        // 64 MiB panels overlay
  char* w1p_end = attn_tmp + (size_t)EN*DFN*DN*2;
  if (w < w1p_end) w = w1p_end;
  unsigned char* w2p = (unsigned char*)alloc((size_t)EN*DN*DFN*2);   // 64 MiB
  unsigned char* apnl = (unsigned char*)alloc((size_t)NPB*16*16384); // 37.7 MB
  unsigned short* h2bf = (unsigned short*)alloc((size_t)NTOK*DN*2);
  int*   topk_e = (int*)alloc(NTOK*2*sizeof(int));
  float* topk_g = (float*)alloc(NTOK*2*sizeof(float));
  int*   rowsA  = (int*)alloc((size_t)NPB*128*sizeof(int));
  float* growA  = (float*)alloc((size_t)NPB*128*sizeof(float));
  int*   cnts   = (int*)alloc(256);
  int*   fill   = cnts + 8;
  int*   offs   = cnts + 16;

  (void)hipMemsetAsync(cnts, 0, 64, stream);                  // counts + fill
  (void)hipMemsetAsync(rowsA, 0, (size_t)NPB*128*sizeof(int), stream);
  ln1_kernel<<<NTOK, 128, 0, stream>>>(x, ln1g, ln1b, aph, apl);
  wsplit_kernel<<<512, 256, 0, stream>>>(Wq, Wk, Wv, Wp, bqh, bql, bph, bpl);
  qkv_gemm_kernel<<<dim3(64, 24), 256, 0, stream>>>(aph, apl, bqh, bql, qkvsplit);
  attn_kernel<<<dim3(16, 128), 256, 0, stream>>>(qkvsplit, ohi, olo);
  proj_gemm_kernel<<<dim3(64, 8), 256, 0, stream>>>(ohi, olo, bph, bpl, x, bproj, out);
  // attn temporaries now dead -> overlay weight panels
  wconv_kernel<<<4096, 256, 0, stream>>>(W1, W2, w1p, w2p);
  router_kernel<<<NTOK, 256, 0, stream>>>(out, ln2g, ln2b, Wr, br, Wn, bn, noise,
                                          h2bf, topk_e, topk_g, cnts);
  scan_kernel<<<1, 64, 0, stream>>>(cnts, offs);
  scatter_kernel<<<NTOK/256, 256, 0, stream>>>(topk_e, topk_g, offs, fill, rowsA, growA);
  agather_kernel<<<dim3(NPB, 16), 256, 0, stream>>>(h2bf, rowsA, apnl);
  moe1_kernel<<<512, 512, 0, stream>>>(apnl, w1p, b1, cnts, offs, midP);
  moe2_kernel<<<512, 512, 0, stream>>>((const unsigned char*)midP, w2p, b2,
                                       cnts, offs, rowsA, growA, out);
}

// Round 16
// 1494.183 us; speedup vs baseline: 1.0923x; 1.0923x over previous
//
#include <hip/hip_runtime.h>
#include <hip/hip_bf16.h>
#include <math.h>

#define NTOK 8192
#define DN   1024
#define HN   16
#define HSN  64
#define EN   8
#define DFN  4096
#define TN   1024
#define NQ   8388608u   // B*H*T*HS elements per q/k/v buffer
#define NPB  144        // max 128-row panels (16384 + 8*255 pad, 256-aligned segments)

typedef _Float16 f16x8 __attribute__((ext_vector_type(8)));
typedef _Float16 f16x4 __attribute__((ext_vector_type(4)));
typedef float    f32x4 __attribute__((ext_vector_type(4)));
typedef short    s16x8 __attribute__((ext_vector_type(8)));

#define MFMA_F16(A,B,C)  __builtin_amdgcn_mfma_f32_16x16x32_f16((A),(B),(C),0,0,0)
#define MFMA_BF16(A,B,C) __builtin_amdgcn_mfma_f32_16x16x32_bf16((A),(B),(C),0,0,0)

__device__ __forceinline__ unsigned short f2bf(float f){
  union { float f; unsigned u; } v; v.f = f;
  unsigned r = v.u + 0x7fffu + ((v.u >> 16) & 1u);
  return (unsigned short)(r >> 16);
}
__device__ __forceinline__ void fsplit(float v, _Float16& hi, _Float16& lo){
  hi = (_Float16)v; lo = (_Float16)(v - (float)hi);
}
// async global->LDS, 16B per lane; LDS dest is wave-uniform base (+lane*16 implicit)
__device__ __forceinline__ void gload16(const void* g, void* l){
  __builtin_amdgcn_global_load_lds((const __attribute__((address_space(1))) unsigned int*)g,
                                   (__attribute__((address_space(3))) unsigned int*)l, 16, 0, 0);
}
#define BAR() __builtin_amdgcn_s_barrier()
#define VMW_BAR(N) do { \
  asm volatile("s_waitcnt vmcnt(" #N ")" ::: "memory"); \
  __builtin_amdgcn_s_barrier(); \
} while (0)

// ---------------- LN1: x -> h1 panel images (x64, hi/lo) ----------------
__global__ __launch_bounds__(128) void ln1_kernel(
    const float* __restrict__ x, const float* __restrict__ g, const float* __restrict__ be,
    unsigned char* __restrict__ aph, unsigned char* __restrict__ apl)
{
  const int row = blockIdx.x;
  const int t = threadIdx.x;             // 0..127, handles 8 cols
  __shared__ float red[2];
  float4 va = ((const float4*)(x + (size_t)row*DN))[t*2];
  float4 vb = ((const float4*)(x + (size_t)row*DN))[t*2+1];
  float s = va.x+va.y+va.z+va.w + vb.x+vb.y+vb.z+vb.w;
  #pragma unroll
  for (int m = 32; m >= 1; m >>= 1) s += __shfl_xor(s, m);
  if ((t & 63) == 0) red[t >> 6] = s;
  __syncthreads();
  const float mu = (red[0] + red[1]) * (1.0f / DN);
  float e[8] = { va.x-mu, va.y-mu, va.z-mu, va.w-mu, vb.x-mu, vb.y-mu, vb.z-mu, vb.w-mu };
  float s2 = 0.0f;
  #pragma unroll
  for (int i = 0; i < 8; i++) s2 += e[i]*e[i];
  #pragma unroll
  for (int m = 32; m >= 1; m >>= 1) s2 += __shfl_xor(s2, m);
  __syncthreads();
  if ((t & 63) == 0) red[t >> 6] = s2;
  __syncthreads();
  const float var = (red[0] + red[1]) * (1.0f / DN);
  const float rs = 1.0f / sqrtf(var + 1e-5f);
  float4 ga = ((const float4*)g)[t*2], gb = ((const float4*)g)[t*2+1];
  float4 ba = ((const float4*)be)[t*2], bb = ((const float4*)be)[t*2+1];
  float gg[8] = { ga.x,ga.y,ga.z,ga.w, gb.x,gb.y,gb.z,gb.w };
  float bbv[8] = { ba.x,ba.y,ba.z,ba.w, bb.x,bb.y,bb.z,bb.w };
  f16x8 hi8, lo8;
  #pragma unroll
  for (int i = 0; i < 8; i++){
    _Float16 hi, lo; fsplit((e[i]*rs*gg[i] + bbv[i]) * 64.0f, hi, lo);
    hi8[i] = hi; lo8[i] = lo;
  }
  const int pb = row >> 7, r = row & 127, kt = t >> 3, kk8 = t & 7;
  size_t po = ((size_t)(pb*16 + kt))*16384 + r*128 + (size_t)((kk8 ^ (r & 7)) << 4);
  *(f16x8*)(aph + po) = hi8;
  *(f16x8*)(apl + po) = lo8;
}

// ---------------- attention weights -> B panel images (x1024, hi/lo) ----------------
__global__ __launch_bounds__(256) void wsplit_kernel(
    const float* __restrict__ Wq, const float* __restrict__ Wk, const float* __restrict__ Wv,
    const float* __restrict__ Wp,
    unsigned char* __restrict__ bqh, unsigned char* __restrict__ bql,
    unsigned char* __restrict__ bph, unsigned char* __restrict__ bpl)
{
  int b = blockIdx.x;
  const int t = threadIdx.x;
  const int r = t & 127;
  const int c0 = (t >> 7) * 4;     // physical slots c0..c0+3
  if (b < 384){
    int nb = b >> 4, kt = b & 15;
    int n = nb*128 + r;
    int mat = n >> 10, h = (n >> 6) & 15, hs = n & 63;
    const float* W = (mat == 0) ? Wq : ((mat == 1) ? Wk : Wv);
    const float* src = W + (size_t)h*65536 + hs;     // + k*64
    unsigned char* ph = bqh + ((size_t)(nb*16 + kt))*16384 + r*128;
    unsigned char* pl = bql + ((size_t)(nb*16 + kt))*16384 + r*128;
    #pragma unroll
    for (int c = c0; c < c0 + 4; c++){
      int kk8 = c ^ (r & 7);
      f16x8 hi8, lo8;
      #pragma unroll
      for (int j = 0; j < 8; j++){
        _Float16 hi, lo; fsplit(src[(size_t)(kt*64 + kk8*8 + j)*64] * 1024.0f, hi, lo);
        hi8[j] = hi; lo8[j] = lo;
      }
      *(f16x8*)(ph + c*16) = hi8;
      *(f16x8*)(pl + c*16) = lo8;
    }
  } else {
    b -= 384;
    int nb = b >> 4, kt = b & 15;
    int n = nb*128 + r;
    unsigned char* ph = bph + ((size_t)(nb*16 + kt))*16384 + r*128;
    unsigned char* pl = bpl + ((size_t)(nb*16 + kt))*16384 + r*128;
    #pragma unroll
    for (int c = c0; c < c0 + 4; c++){
      int kk8 = c ^ (r & 7);
      f16x8 hi8, lo8;
      #pragma unroll
      for (int j = 0; j < 8; j++){
        _Float16 hi, lo; fsplit(Wp[(size_t)(kt*64 + kk8*8 + j)*DN + n] * 1024.0f, hi, lo);
        hi8[j] = hi; lo8[j] = lo;
      }
      *(f16x8*)(ph + c*16) = hi8;
      *(f16x8*)(pl + c*16) = lo8;
    }
  }
}

// ---------------- QKV GEMM: 128x128, fused 3-product split (one K pass) ----------------
// V (mat==2) is written TRANSPOSED: [b,h,hs,t] so attention can stage V^T vectorized.
__global__ __launch_bounds__(256) void qkv_gemm_kernel(
    const unsigned char* __restrict__ aph, const unsigned char* __restrict__ apl,
    const unsigned char* __restrict__ bqh, const unsigned char* __restrict__ bql,
    _Float16* __restrict__ qkvout)
{
  const int mb = blockIdx.x;    // 0..63
  const int nb = blockIdx.y;    // 0..23
  __shared__ __align__(16) unsigned char Ah[16384], Al[16384], Bh[16384], Bl[16384];
  const int t = threadIdx.x, w = t >> 6, lane = t & 63, lg = lane >> 4, lr = lane & 15;
  const int wr = w >> 1, wc = w & 1;
  const unsigned char* sb;
  unsigned char* dp;
  if (w == 0){ sb = aph + ((size_t)(mb*16))*16384; dp = Ah; }
  else if (w == 1){ sb = apl + ((size_t)(mb*16))*16384; dp = Al; }
  else if (w == 2){ sb = bqh + ((size_t)(nb*16))*16384; dp = Bh; }
  else { sb = bql + ((size_t)(nb*16))*16384; dp = Bl; }
  sb += lane*16;
  f32x4 acc[4][4] = {};
  for (int kt = 0; kt < 16; kt++){
    const unsigned char* s2 = sb + (size_t)kt*16384;
    #pragma unroll
    for (int j = 0; j < 16; j++) gload16(s2 + j*1024, dp + j*1024);
    __syncthreads();
    #pragma unroll
    for (int ks = 0; ks < 2; ks++){
      f16x8 ah[4], al[4], bh[4], bl[4];
      #pragma unroll
      for (int f = 0; f < 4; f++){
        int ra = wr*64 + f*16 + lr;
        int off = (ks*64 + lg*16) ^ ((ra & 7) << 4);
        ah[f] = *(const f16x8*)(Ah + ra*128 + off);
        al[f] = *(const f16x8*)(Al + ra*128 + off);
      }
      #pragma unroll
      for (int f = 0; f < 4; f++){
        int rb = wc*64 + f*16 + lr;
        int off = (ks*64 + lg*16) ^ ((rb & 7) << 4);
        bh[f] = *(const f16x8*)(Bh + rb*128 + off);
        bl[f] = *(const f16x8*)(Bl + rb*128 + off);
      }
      #pragma unroll
      for (int fm = 0; fm < 4; fm++)
      #pragma unroll
      for (int fn = 0; fn < 4; fn++){
        acc[fm][fn] = MFMA_F16(ah[fm], bh[fn], acc[fm][fn]);
        acc[fm][fn] = MFMA_F16(al[fm], bh[fn], acc[fm][fn]);
        acc[fm][fn] = MFMA_F16(ah[fm], bl[fn], acc[fm][fn]);
      }
    }
    __syncthreads();
  }
  #pragma unroll
  for (int fm = 0; fm < 4; fm++)
  #pragma unroll
  for (int fn = 0; fn < 4; fn++)
  #pragma unroll
  for (int rr = 0; rr < 4; rr++){
    int m = mb*128 + wr*64 + fm*16 + lg*4 + rr;
    int n = nb*128 + wc*64 + fn*16 + lr;
    int mat = n >> 10, h = (n >> 6) & 15, hs = n & 63;
    int bb = m >> 10, tt = m & 1023;
    _Float16* dsthi = qkvout + (size_t)mat * 2u * NQ;
    _Float16* dstlo = dsthi + NQ;
    size_t oi;
    if (mat == 2)  // V transposed: [b][h][hs][t]
      oi = (((size_t)(bb*HN + h))*HSN + hs)*TN + tt;
    else
      oi = (((size_t)(bb*HN + h))*TN + tt)*HSN + hs;
    _Float16 hi, lo; fsplit(acc[fm][fn][rr] * (1.0f/1024.0f), hi, lo);  // = 64*q
    dsthi[oi] = hi; dstlo[oi] = lo;
  }
}

// ---------------- flash attention (split f16, V^T input) ----------------
__global__ __launch_bounds__(256) void attn_kernel(
    const _Float16* __restrict__ qkv,
    _Float16* __restrict__ ohi_, _Float16* __restrict__ olo_)
{
  const _Float16* qhi = qkv;
  const _Float16* qlo = qkv + NQ;
  const _Float16* khi = qkv + 2u*NQ;
  const _Float16* klo = qkv + 3u*NQ;
  const _Float16* vhi = qkv + 4u*NQ;   // layout [b,h,hs,t]
  const _Float16* vlo = qkv + 5u*NQ;
  const int qt = blockIdx.x;     // 0..15
  const int bh = blockIdx.y;     // 0..127
  const size_t base = (size_t)bh * TN * HSN;   // same element count for V^T
  const int t = threadIdx.x, wid = t >> 6, lane = t & 63, lg = lane >> 4, lr = lane & 15;
  __shared__ _Float16 Khi[64][72], Klo[64][72], Vthi[64][72], Vtlo[64][72], Phi[64][72], Plo[64][72];
  f16x8 qh[2], ql[2];
  {
    const int qrow = qt*64 + wid*16 + lr;
    const _Float16* qp  = qhi + base + (size_t)qrow*HSN;
    const _Float16* qpl = qlo + base + (size_t)qrow*HSN;
    #pragma unroll
    for (int c = 0; c < 2; c++){
      qh[c] = *(const f16x8*)(qp  + c*32 + lg*8);
      ql[c] = *(const f16x8*)(qpl + c*32 + lg*8);
    }
  }
  f32x4 oacc[4] = {};
  float mrow[4], lsum[4];
  #pragma unroll
  for (int r = 0; r < 4; r++){ mrow[r] = -INFINITY; lsum[r] = 0.0f; }
  const int sr = t >> 2, sc = (t & 3) * 16;
  const float sscale = 1.0f / (4096.0f * 32.0f);
  for (int kvt = 0; kvt <= qt; kvt++){
    {
      const size_t gr = base + (size_t)(kvt*64 + sr)*HSN + sc;
      *(f16x8*)&Khi[sr][sc]     = *(const f16x8*)(khi + gr);
      *(f16x8*)&Khi[sr][sc + 8] = *(const f16x8*)(khi + gr + 8);
      *(f16x8*)&Klo[sr][sc]     = *(const f16x8*)(klo + gr);
      *(f16x8*)&Klo[sr][sc + 8] = *(const f16x8*)(klo + gr + 8);
      // V^T: row sr = hs, cols = t within tile (vectorized, no transpose)
      const size_t gv = base + (size_t)sr*TN + kvt*64 + sc;
      *(f16x8*)&Vthi[sr][sc]     = *(const f16x8*)(vhi + gv);
      *(f16x8*)&Vthi[sr][sc + 8] = *(const f16x8*)(vhi + gv + 8);
      *(f16x8*)&Vtlo[sr][sc]     = *(const f16x8*)(vlo + gv);
      *(f16x8*)&Vtlo[sr][sc + 8] = *(const f16x8*)(vlo + gv + 8);
    }
    __syncthreads();
    f32x4 sacc[4] = {};
    #pragma unroll
    for (int c = 0; c < 2; c++)
    #pragma unroll
    for (int fn = 0; fn < 4; fn++){
      f16x8 kh = *(const f16x8*)&Khi[fn*16 + lr][c*32 + lg*8];
      f16x8 kl = *(const f16x8*)&Klo[fn*16 + lr][c*32 + lg*8];
      sacc[fn] = MFMA_F16(qh[c], kh, sacc[fn]);
      sacc[fn] = MFMA_F16(qh[c], kl, sacc[fn]);
      sacc[fn] = MFMA_F16(ql[c], kh, sacc[fn]);
    }
    float sv[4][4], pmax[4];
    #pragma unroll
    for (int r = 0; r < 4; r++) pmax[r] = -INFINITY;
    const int qg0 = qt*64 + wid*16 + lg*4;
    #pragma unroll
    for (int fn = 0; fn < 4; fn++)
    #pragma unroll
    for (int r = 0; r < 4; r++){
      float xv = sacc[fn][r] * sscale;
      int kvg = kvt*64 + fn*16 + lr;
      xv = (kvg <= qg0 + r) ? xv : -INFINITY;
      sv[fn][r] = xv;
      pmax[r] = fmaxf(pmax[r], xv);
    }
    #pragma unroll
    for (int r = 0; r < 4; r++){
      #pragma unroll
      for (int m = 1; m < 16; m <<= 1) pmax[r] = fmaxf(pmax[r], __shfl_xor(pmax[r], m));
    }
    float alpha[4], mnew[4], psum[4];
    #pragma unroll
    for (int r = 0; r < 4; r++){
      mnew[r] = fmaxf(mrow[r], pmax[r]);
      alpha[r] = __expf(mrow[r] - mnew[r]);
      psum[r] = 0.0f;
    }
    #pragma unroll
    for (int fn = 0; fn < 4; fn++)
    #pragma unroll
    for (int r = 0; r < 4; r++){
      float p = __expf(sv[fn][r] - mnew[r]);
      psum[r] += p;
      _Float16 hi, lo; fsplit(p * 512.0f, hi, lo);
      Phi[wid*16 + lg*4 + r][fn*16 + lr] = hi;
      Plo[wid*16 + lg*4 + r][fn*16 + lr] = lo;
    }
    #pragma unroll
    for (int r = 0; r < 4; r++){
      #pragma unroll
      for (int m = 1; m < 16; m <<= 1) psum[r] += __shfl_xor(psum[r], m);
      lsum[r] = lsum[r]*alpha[r] + psum[r];
      mrow[r] = mnew[r];
    }
    #pragma unroll
    for (int fn = 0; fn < 4; fn++)
    #pragma unroll
    for (int r = 0; r < 4; r++) oacc[fn][r] *= alpha[r];
    #pragma unroll
    for (int c2 = 0; c2 < 2; c2++){
      f16x8 ph = *(const f16x8*)&Phi[wid*16 + lr][c2*32 + lg*8];
      f16x8 pl = *(const f16x8*)&Plo[wid*16 + lr][c2*32 + lg*8];
      #pragma unroll
      for (int fn = 0; fn < 4; fn++){
        f16x8 vh = *(const f16x8*)&Vthi[fn*16 + lr][c2*32 + lg*8];
        f16x8 vl = *(const f16x8*)&Vtlo[fn*16 + lr][c2*32 + lg*8];
        oacc[fn] = MFMA_F16(ph, vh, oacc[fn]);
        oacc[fn] = MFMA_F16(ph, vl, oacc[fn]);
        oacc[fn] = MFMA_F16(pl, vh, oacc[fn]);
      }
    }
    __syncthreads();
  }
  const int bb = bh >> 4, hh = bh & 15;
  #pragma unroll
  for (int fn = 0; fn < 4; fn++)
  #pragma unroll
  for (int r = 0; r < 4; r++){
    float ov = oacc[fn][r] / (32768.0f * lsum[r]);   // 512*64 scale
    int m = qt*64 + wid*16 + lg*4 + r;
    size_t oi = ((size_t)(bb*TN + m))*DN + hh*HSN + fn*16 + lr;
    _Float16 hi, lo; fsplit(ov * 64.0f, hi, lo);
    ohi_[oi] = hi; olo_[oi] = lo;
  }
}

// ---------------- proj GEMM + residual: 128x128, fused 3-product split -----------------
__global__ __launch_bounds__(256) void proj_gemm_kernel(
    const _Float16* __restrict__ ohi, const _Float16* __restrict__ olo,
    const unsigned char* __restrict__ bph, const unsigned char* __restrict__ bpl,
    const float* __restrict__ x, const float* __restrict__ bproj,
    float* __restrict__ out)
{
  const int mb = blockIdx.x;    // 0..63
  const int nb = blockIdx.y;    // 0..7
  __shared__ __align__(16) unsigned char Ah[16384], Al[16384], Bh[16384], Bl[16384];
  const int t = threadIdx.x, w = t >> 6, lane = t & 63, lg = lane >> 4, lr = lane & 15;
  const int wr = w >> 1, wc = w & 1;
  f32x4 acc[4][4] = {};
  const unsigned char* sbB = ((w == 2) ? bph : bpl) + ((size_t)(nb*16))*16384 + lane*16;
  unsigned char* dpB = (w == 2) ? Bh : Bl;
  const _Float16* aSrc = (w == 0) ? ohi : olo;
  unsigned char* dpA = (w == 0) ? Ah : Al;
  const int rA = lane >> 3;          // + j*8
  const int cA = lane & 7;
  for (int kt = 0; kt < 16; kt++){
    if (w < 2){
      #pragma unroll
      for (int j = 0; j < 16; j++){
        int r = rA + j*8;
        const unsigned char* s2 = (const unsigned char*)(aSrc + (size_t)(mb*128 + r)*DN)
                                  + kt*128 + ((cA ^ (r & 7)) << 4);
        gload16(s2, dpA + j*1024);
      }
    } else {
      const unsigned char* s2 = sbB + (size_t)kt*16384;
      #pragma unroll
      for (int j = 0; j < 16; j++) gload16(s2 + j*1024, dpB + j*1024);
    }
    __syncthreads();
    #pragma unroll
    for (int ks = 0; ks < 2; ks++){
      f16x8 ah[4], al[4], bh[4], bl[4];
      #pragma unroll
      for (int f = 0; f < 4; f++){
        int ra = wr*64 + f*16 + lr;
        int off = (ks*64 + lg*16) ^ ((ra & 7) << 4);
        ah[f] = *(const f16x8*)(Ah + ra*128 + off);
        al[f] = *(const f16x8*)(Al + ra*128 + off);
      }
      #pragma unroll
      for (int f = 0; f < 4; f++){
        int rb = wc*64 + f*16 + lr;
        int off = (ks*64 + lg*16) ^ ((rb & 7) << 4);
        bh[f] = *(const f16x8*)(Bh + rb*128 + off);
        bl[f] = *(const f16x8*)(Bl + rb*128 + off);
      }
      #pragma unroll
      for (int fm = 0; fm < 4; fm++)
      #pragma unroll
      for (int fn = 0; fn < 4; fn++){
        acc[fm][fn] = MFMA_F16(ah[fm], bh[fn], acc[fm][fn]);
        acc[fm][fn] = MFMA_F16(al[fm], bh[fn], acc[fm][fn]);
        acc[fm][fn] = MFMA_F16(ah[fm], bl[fn], acc[fm][fn]);
      }
    }
    __syncthreads();
  }
  #pragma unroll
  for (int fm = 0; fm < 4; fm++)
  #pragma unroll
  for (int fn = 0; fn < 4; fn++)
  #pragma unroll
  for (int rr = 0; rr < 4; rr++){
    int m = mb*128 + wr*64 + fm*16 + lg*4 + rr;
    int n = nb*128 + wc*64 + fn*16 + lr;
    size_t oi = (size_t)m*DN + n;
    out[oi] = x[oi] + acc[fm][fn][rr] * (1.0f/65536.0f) + bproj[n];
  }
}

// ---------------- router: LN2 (fp32) + logits + noisy top-2 + h2(bf16) ----------------
__global__ __launch_bounds__(256) void router_kernel(
    const float* __restrict__ x1, const float* __restrict__ g, const float* __restrict__ be,
    const float* __restrict__ Wr, const float* __restrict__ br,
    const float* __restrict__ Wn, const float* __restrict__ bn,
    const float* __restrict__ noise, unsigned short* __restrict__ h2bf,
    int* __restrict__ topk_e, float* __restrict__ topk_g, int* __restrict__ counts)
{
  const int token = blockIdx.x;
  const int t = threadIdx.x;
  __shared__ float redsum[4];
  __shared__ float red[64];
  float4 v = ((const float4*)(x1 + (size_t)token * DN))[t];
  float s = v.x + v.y + v.z + v.w;
  #pragma unroll
  for (int m = 32; m >= 1; m >>= 1) s += __shfl_xor(s, m);
  if ((t & 63) == 0) redsum[t >> 6] = s;
  __syncthreads();
  const float mu = (redsum[0] + redsum[1] + redsum[2] + redsum[3]) * (1.0f / DN);
  const float d0 = v.x - mu, d1 = v.y - mu, d2 = v.z - mu, d3 = v.w - mu;
  float s2 = d0*d0 + d1*d1 + d2*d2 + d3*d3;
  #pragma unroll
  for (int m = 32; m >= 1; m >>= 1) s2 += __shfl_xor(s2, m);
  __syncthreads();
  if ((t & 63) == 0) redsum[t >> 6] = s2;
  __syncthreads();
  const float var = (redsum[0] + redsum[1] + redsum[2] + redsum[3]) * (1.0f / DN);
  const float rs = 1.0f / sqrtf(var + 1e-5f);
  float4 gv = ((const float4*)g)[t];
  float4 bv = ((const float4*)be)[t];
  float h0 = d0*rs*gv.x + bv.x, h1v = d1*rs*gv.y + bv.y, h2v = d2*rs*gv.z + bv.z, h3 = d3*rs*gv.w + bv.w;
  ushort4 hb;
  hb.x = f2bf(h0); hb.y = f2bf(h1v); hb.z = f2bf(h2v); hb.w = f2bf(h3);
  *(ushort4*)(h2bf + (size_t)token*DN + t*4) = hb;
  float acc[16];
  const int j = t * 4;
  #pragma unroll
  for (int e = 0; e < 8; e++){
    acc[e]     = h0*Wr[(j+0)*8+e] + h1v*Wr[(j+1)*8+e] + h2v*Wr[(j+2)*8+e] + h3*Wr[(j+3)*8+e];
    acc[8 + e] = h0*Wn[(j+0)*8+e] + h1v*Wn[(j+1)*8+e] + h2v*Wn[(j+2)*8+e] + h3*Wn[(j+3)*8+e];
  }
  #pragma unroll
  for (int q = 0; q < 16; q++){
    #pragma unroll
    for (int m = 32; m >= 1; m >>= 1) acc[q] += __shfl_xor(acc[q], m);
  }
  if ((t & 63) == 0){
    #pragma unroll
    for (int q = 0; q < 16; q++) red[(t >> 6)*16 + q] = acc[q];
  }
  __syncthreads();
  if (t < 16) red[t] = red[t] + red[16 + t] + red[32 + t] + red[48 + t];
  __syncthreads();
  if (t == 0){
    float nz[8];
    #pragma unroll
    for (int e = 0; e < 8; e++){
      float logit = red[e] + br[e];
      float a = red[8 + e] + bn[e];
      float sp = (a > 20.0f) ? a : log1pf(expf(a));
      nz[e] = logit + noise[(size_t)token*EN + e] * sp;
    }
    float v1 = -INFINITY, v2 = -INFINITY; int i1 = 0, i2 = 0;
    #pragma unroll
    for (int e = 0; e < 8; e++){
      float z = nz[e];
      if (z > v1){ v2 = v1; i2 = i1; v1 = z; i1 = e; }
      else if (z > v2){ v2 = z; i2 = e; }
    }
    float e2 = expf(v2 - v1);
    float den = 1.0f + e2;
    topk_e[token*2]     = i1; topk_e[token*2 + 1] = i2;
    topk_g[token*2]     = 1.0f/den; topk_g[token*2 + 1] = e2/den;
    atomicAdd(&counts[i1], 1); atomicAdd(&counts[i2], 1);
  }
}

// 256-aligned expert segment offsets (moe tiles are 256 rows)
__global__ void scan_kernel(const int* __restrict__ counts, int* __restrict__ offs)
{
  if (threadIdx.x == 0 && blockIdx.x == 0){
    int a = 0;
    for (int e = 0; e < EN; e++){ offs[e] = a; a += (counts[e] + 255) & ~255; }
  }
}

__global__ __launch_bounds__(256) void scatter_kernel(
    const int* __restrict__ topk_e, const float* __restrict__ topk_g,
    const int* __restrict__ offs, int* __restrict__ fill,
    int* __restrict__ rows, float* __restrict__ grow)
{
  const int token = blockIdx.x*256 + threadIdx.x;
  #pragma unroll
  for (int i = 0; i < 2; i++){
    int e = topk_e[token*2 + i];
    int pos = offs[e] + atomicAdd(&fill[e], 1);
    rows[pos] = token;
    grow[pos] = topk_g[token*2 + i];
  }
}

// ---------------- expert weights -> 16KB LDS-image panels (bf16, swizzle baked) --------
__global__ __launch_bounds__(256) void wconv_kernel(
    const float* __restrict__ W1, const float* __restrict__ W2,
    unsigned char* __restrict__ w1p, unsigned char* __restrict__ w2p)
{
  int b = blockIdx.x;
  const float* W; unsigned char* pan; int Nd, kt, n;
  if (b < 2048){
    int e = b >> 8, rem = b & 255, nb2 = rem >> 4; kt = rem & 15;
    n = nb2*256 + threadIdx.x;                       // 0..4095
    W = W1 + (size_t)e * DN * DFN; Nd = DFN;
    pan = w1p + (((size_t)e*32 + (n >> 7))*16 + kt) * 16384;
  } else {
    b -= 2048;
    int e = b >> 8, rem = b & 255, nb2 = rem >> 6; kt = rem & 63;
    n = nb2*256 + threadIdx.x;                       // 0..1023
    W = W2 + (size_t)e * DFN * DN; Nd = DN;
    pan = w2p + (((size_t)e*8 + (n >> 7))*64 + kt) * 16384;
  }
  const int r = n & 127;
  #pragma unroll
  for (int kk8 = 0; kk8 < 8; kk8++){
    union { unsigned short u[8]; uint4 v; } buf;
    #pragma unroll
    for (int j = 0; j < 8; j++)
      buf.u[j] = f2bf(W[(size_t)(kt*64 + kk8*8 + j)*Nd + n]);
    *(uint4*)(pan + r*128 + ((kk8 ^ (r & 7)) << 4)) = buf.v;
  }
}

// ---------------- gather tokens into A panels: apnl[pb][kt16][16KB image] ----------------
__global__ __launch_bounds__(256) void agather_kernel(
    const unsigned short* __restrict__ h2bf, const int* __restrict__ rows,
    unsigned char* __restrict__ apnl)
{
  const int pb = blockIdx.x, kt = blockIdx.y;
  const int t = threadIdx.x;
  const int r = t >> 1, c0 = (t & 1) * 4;
  const int tok = rows[pb*128 + r];
  const unsigned char* src = (const unsigned char*)h2bf + (size_t)tok*2048 + kt*128;
  unsigned char* dst = apnl + ((size_t)pb*16 + kt)*16384 + r*128;
  #pragma unroll
  for (int i = 0; i < 4; i++){
    int c = c0 + i;
    *(uint4*)(dst + ((c ^ (r & 7)) << 4)) = *(const uint4*)(src + c*16);
  }
}

// ---------------- MoE GEMM1 (persistent, 2D-window) — R9 exact ----------------
__global__ __launch_bounds__(512, 1) void moe1_kernel(
    const unsigned char* __restrict__ apnl, const unsigned char* __restrict__ w1p,
    const float* __restrict__ b1,
    const int* __restrict__ counts, const int* __restrict__ offs,
    unsigned short* __restrict__ midP)
{
  __shared__ __align__(16) unsigned char As[2][32768], Bs[2][32768];
  const int bid = blockIdx.x;
  const int t = threadIdx.x;
  const int w = t >> 6, lane = t & 63, lg = lane >> 4, lr = lane & 15;
  const int wm = w >> 2, wn = w & 3;
  const int sp = (w >> 1) & 1, sh = (w & 1) * 8192;
  const int e  = bid & 7;
  const int c  = bid >> 3;                 // CU slot within XCD, 0..31
  const int cnt = counts[e];
  const int off = offs[e];
  const int nmb = (cnt + 255) >> 8;
  const int nch = nmb * 16;
  for (int q = c; q < nch; q += 32){
    const int grp = q / (4*nmb);
    const int within = q - grp*4*nmb;
    const int mb = within >> 2;
    const int nb = grp*4 + (within & 3);   // 0..15 (256-col group)
    const int m0 = mb * 256;
    const int pb0 = (off + m0) >> 7;
    const unsigned char* sbase;
    unsigned char* dbase;
    if (w < 4){
      sbase = apnl + ((size_t)(pb0 + sp) * 16) * 16384 + sh + lane*16;
      dbase = &As[0][sp*16384 + sh];
    } else {
      sbase = w1p + ((size_t)(e*32 + nb*2 + sp) * 16) * 16384 + sh + lane*16;
      dbase = &Bs[0][sp*16384 + sh];
    }
    f32x4 acc[8][4] = {};
    auto stage = [&](int buf, int kt){
      const unsigned char* s2 = sbase + (size_t)kt * 16384;
      unsigned char* d = dbase + buf * 32768;
      #pragma unroll
      for (int j = 0; j < 8; j++) gload16(s2 + j*1024, d + j*1024);
    };
    auto compute = [&](int buf){
      const unsigned char* pA = &As[buf][wm*16384];
      const unsigned char* pB = &Bs[buf][(wn>>1)*16384];
      #pragma unroll
      for (int ks = 0; ks < 2; ks++){
        s16x8 b[4], a[8];
        #pragma unroll
        for (int f = 0; f < 4; f++){
          int rb = (wn&1)*64 + f*16 + lr;
          b[f] = *(const s16x8*)(pB + rb*128 + ((ks*64 + lg*16) ^ ((rb&7)<<4)));
        }
        #pragma unroll
        for (int f = 0; f < 8; f++){
          int ra = f*16 + lr;
          a[f] = *(const s16x8*)(pA + ra*128 + ((ks*64 + lg*16) ^ ((ra&7)<<4)));
        }
        __builtin_amdgcn_s_setprio(1);
        #pragma unroll
        for (int fm = 0; fm < 8; fm++)
        #pragma unroll
        for (int fn = 0; fn < 4; fn++)
          acc[fm][fn] = MFMA_BF16(a[fm], b[fn], acc[fm][fn]);
        __builtin_amdgcn_s_setprio(0);
      }
    };
    stage(0, 0);
    stage(1, 1);
    for (int kt = 0; kt + 2 < 16; kt += 2){
      VMW_BAR(8); compute(0); BAR(); stage(0, kt + 2);
      VMW_BAR(8); compute(1); BAR(); stage(1, kt + 3);
    }
    VMW_BAR(8); compute(0);
    VMW_BAR(0); compute(1);
    BAR();
    {
      unsigned char* Lp = ((wm == 0) ? (unsigned char*)As : (unsigned char*)Bs) + wn*16384;
      const float* b1e = b1 + (size_t)e*DFN + nb*256 + wn*64;
      #pragma unroll
      for (int fn = 0; fn < 4; fn++){
        float bias = b1e[fn*16 + lr];
        int col = fn*16 + lr;
        #pragma unroll
        for (int fm = 0; fm < 8; fm++)
        #pragma unroll
        for (int rr = 0; rr < 4; rr++){
          int r = fm*16 + lg*4 + rr;
          float v = fmaxf(acc[fm][fn][rr] + bias, 0.0f);
          *(unsigned short*)(Lp + r*128 + ((col ^ ((r & 7) << 3)) * 2)) = f2bf(v);
        }
      }
    }
    BAR();
    {
      int p = w >> 2, jj = w & 3;
      const uint4* src = (const uint4*)(((p == 0) ? (unsigned char*)As : (unsigned char*)Bs) + jj*16384);
      uint4* dst = (uint4*)((unsigned char*)midP + (((size_t)(pb0 + p)*64) + nb*4 + jj) * 16384);
      #pragma unroll
      for (int i = 0; i < 16; i++) dst[lane + i*64] = src[lane + i*64];
    }
    BAR();
  }
}

// ---------------- MoE GEMM2 (persistent, 2D-window) — R9 exact ----------------
__global__ __launch_bounds__(512, 1) void moe2_kernel(
    const unsigned char* __restrict__ midP, const unsigned char* __restrict__ w2p,
    const float* __restrict__ b2,
    const int* __restrict__ counts, const int* __restrict__ offs,
    const int* __restrict__ rows, const float* __restrict__ grow,
    float* __restrict__ out)
{
  __shared__ __align__(16) unsigned char As[2][32768], Bs[2][32768];
  const int bid = blockIdx.x;
  const int t = threadIdx.x;
  const int w = t >> 6, lane = t & 63, lg = lane >> 4, lr = lane & 15;
  const int wm = w >> 2, wn = w & 3;
  const int sp = (w >> 1) & 1, sh = (w & 1) * 8192;
  const int e  = bid & 7;
  const int c  = bid >> 3;
  const int cnt = counts[e];
  const int off = offs[e];
  const int nmb = (cnt + 255) >> 8;
  const int nch = nmb * 4;
  for (int q = c; q < nch; q += 32){
    const int mb = q >> 2;
    const int nb = q & 3;
    const int m0 = mb * 256;
    const int pb0 = (off + m0) >> 7;
    const unsigned char* sbase;
    unsigned char* dbase;
    if (w < 4){
      sbase = midP + ((size_t)(pb0 + sp) * 64) * 16384 + sh + lane*16;
      dbase = &As[0][sp*16384 + sh];
    } else {
      sbase = w2p + ((size_t)(e*8 + nb*2 + sp) * 64) * 16384 + sh + lane*16;
      dbase = &Bs[0][sp*16384 + sh];
    }
    f32x4 acc[8][4] = {};
    auto stage = [&](int buf, int kt){
      const unsigned char* s2 = sbase + (size_t)kt * 16384;
      unsigned char* d = dbase + buf * 32768;
      #pragma unroll
      for (int j = 0; j < 8; j++) gload16(s2 + j*1024, d + j*1024);
    };
    auto compute = [&](int buf){
      const unsigned char* pA = &As[buf][wm*16384];
      const unsigned char* pB = &Bs[buf][(wn>>1)*16384];
      #pragma unroll
      for (int ks = 0; ks < 2; ks++){
        s16x8 b[4], a[8];
        #pragma unroll
        for (int f = 0; f < 4; f++){
          int rb = (wn&1)*64 + f*16 + lr;
          b[f] = *(const s16x8*)(pB + rb*128 + ((ks*64 + lg*16) ^ ((rb&7)<<4)));
        }
        #pragma unroll
        for (int f = 0; f < 8; f++){
          int ra = f*16 + lr;
          a[f] = *(const s16x8*)(pA + ra*128 + ((ks*64 + lg*16) ^ ((ra&7)<<4)));
        }
        __builtin_amdgcn_s_setprio(1);
        #pragma unroll
        for (int fm = 0; fm < 8; fm++)
        #pragma unroll
        for (int fn = 0; fn < 4; fn++)
          acc[fm][fn] = MFMA_BF16(a[fm], b[fn], acc[fm][fn]);
        __builtin_amdgcn_s_setprio(0);
      }
    };
    stage(0, 0);
    stage(1, 1);
    for (int kt = 0; kt + 2 < 64; kt += 2){
      VMW_BAR(8); compute(0); BAR(); stage(0, kt + 2);
      VMW_BAR(8); compute(1); BAR(); stage(1, kt + 3);
    }
    VMW_BAR(8); compute(0);
    VMW_BAR(0); compute(1);
    BAR();
    const float* b2e = b2 + (size_t)e*DN + nb*256 + wn*64;
    #pragma unroll
    for (int fm = 0; fm < 8; fm++)
    #pragma unroll
    for (int rr = 0; rr < 4; rr++){
      int ml = wm*128 + fm*16 + lg*4 + rr;
      if (m0 + ml < cnt){
        int gi = off + m0 + ml;
        int tok = rows[gi];
        float gt = grow[gi];
        #pragma unroll
        for (int fn = 0; fn < 4; fn++){
          int n = nb*256 + wn*64 + fn*16 + lr;
          atomicAdd(out + (size_t)tok*DN + n, gt*(acc[fm][fn][rr] + b2e[fn*16 + lr]));
        }
      }
    }
  }
}

// ---------------- launch ----------------
extern "C" void kernel_launch(void* const* d_in, const int* in_sizes, int n_in,
                              void* d_out, int out_size, void* d_ws, size_t ws_size,
                              hipStream_t stream) {
  (void)in_sizes; (void)n_in; (void)out_size; (void)ws_size;
  const float* x     = (const float*)d_in[0];
  const float* noise = (const float*)d_in[1];
  const float* Wq    = (const float*)d_in[2];
  const float* Wk    = (const float*)d_in[3];
  const float* Wv    = (const float*)d_in[4];
  const float* Wp    = (const float*)d_in[5];
  const float* bproj = (const float*)d_in[6];
  const float* ln1g  = (const float*)d_in[7];
  const float* ln1b  = (const float*)d_in[8];
  const float* ln2g  = (const float*)d_in[9];
  const float* ln2b  = (const float*)d_in[10];
  const float* Wr    = (const float*)d_in[11];
  const float* br    = (const float*)d_in[12];
  const float* Wn    = (const float*)d_in[13];
  const float* bn    = (const float*)d_in[14];
  const float* W1    = (const float*)d_in[15];
  const float* b1    = (const float*)d_in[16];
  const float* W2    = (const float*)d_in[17];
  const float* b2    = (const float*)d_in[18];
  float* out = (float*)d_out;

  char* w = (char*)d_ws;
  auto alloc = [&](size_t bytes) -> char* {
    char* p = w; w += (bytes + 255) & ~(size_t)255; return p;
  };
  // Region A: qkv split + o split during attention; reused as panelized `mid` during MoE.
  char* big = alloc((size_t)NPB * 64 * 16384);          // 151 MB >= 134.2 MB qkv need
  _Float16* qkvsplit = (_Float16*)big;
  _Float16* ohi = (_Float16*)(big + (size_t)6*NQ*2);
  _Float16* olo = ohi + NQ;
  unsigned short* midP = (unsigned short*)big;
  // Region B: attention temporaries (dead after proj); W1 panels overlay them afterwards.
  char* attn_tmp = w;
  unsigned char* aph = (unsigned char*)alloc((size_t)64*16*16384);   // h1 hi panels 16 MB
  unsigned char* apl = (unsigned char*)alloc((size_t)64*16*16384);   // h1 lo panels 16 MB
  unsigned char* bqh = (unsigned char*)alloc((size_t)24*16*16384);   // qkv W hi panels 6.3 MB
  unsigned char* bql = (unsigned char*)alloc((size_t)24*16*16384);
  unsigned char* bph = (unsigned char*)alloc((size_t)8*16*16384);    // proj W hi panels 2.1 MB
  unsigned char* bpl = (unsigned char*)alloc((size_t)8*16*16384);
  unsigned char* w1p = (unsigned char*)attn_tmp;        // 64 MiB panels overlay
  char* w1p_end = attn_tmp + (size_t)EN*DFN*DN*2;
  if (w < w1p_end) w = w1p_end;
  unsigned char* w2p = (unsigned char*)alloc((size_t)EN*DN*DFN*2);   // 64 MiB
  unsigned char* apnl = (unsigned char*)alloc((size_t)NPB*16*16384); // 37.7 MB
  unsigned short* h2bf = (unsigned short*)alloc((size_t)NTOK*DN*2);
  int*   topk_e = (int*)alloc(NTOK*2*sizeof(int));
  float* topk_g = (float*)alloc(NTOK*2*sizeof(float));
  int*   rowsA  = (int*)alloc((size_t)NPB*128*sizeof(int));
  float* growA  = (float*)alloc((size_t)NPB*128*sizeof(float));
  int*   cnts   = (int*)alloc(256);
  int*   fill   = cnts + 8;
  int*   offs   = cnts + 16;

  (void)hipMemsetAsync(cnts, 0, 64, stream);                  // counts + fill
  (void)hipMemsetAsync(rowsA, 0, (size_t)NPB*128*sizeof(int), stream);
  ln1_kernel<<<NTOK, 128, 0, stream>>>(x, ln1g, ln1b, aph, apl);
  wsplit_kernel<<<512, 256, 0, stream>>>(Wq, Wk, Wv, Wp, bqh, bql, bph, bpl);
  qkv_gemm_kernel<<<dim3(64, 24), 256, 0, stream>>>(aph, apl, bqh, bql, qkvsplit);
  attn_kernel<<<dim3(16, 128), 256, 0, stream>>>(qkvsplit, ohi, olo);
  proj_gemm_kernel<<<dim3(64, 8), 256, 0, stream>>>(ohi, olo, bph, bpl, x, bproj, out);
  // attn temporaries now dead -> overlay weight panels
  wconv_kernel<<<4096, 256, 0, stream>>>(W1, W2, w1p, w2p);
  router_kernel<<<NTOK, 256, 0, stream>>>(out, ln2g, ln2b, Wr, br, Wn, bn, noise,
                                          h2bf, topk_e, topk_g, cnts);
  scan_kernel<<<1, 64, 0, stream>>>(cnts, offs);
  scatter_kernel<<<NTOK/256, 256, 0, stream>>>(topk_e, topk_g, offs, fill, rowsA, growA);
  agather_kernel<<<dim3(NPB, 16), 256, 0, stream>>>(h2bf, rowsA, apnl);
  moe1_kernel<<<256, 512, 0, stream>>>(apnl, w1p, b1, cnts, offs, midP);
  moe2_kernel<<<256, 512, 0, stream>>>((const unsigned char*)midP, w2p, b2,
                                       cnts, offs, rowsA, growA, out);
}

// Round 17
// 1478.520 us; speedup vs baseline: 1.1038x; 1.0106x over previous
//
#include <hip/hip_runtime.h>
#include <hip/hip_bf16.h>
#include <math.h>

#define NTOK 8192
#define DN   1024
#define HN   16
#define HSN  64
#define EN   8
#define DFN  4096
#define TN   1024
#define NQ   8388608u   // B*H*T*HS elements per q/k/v buffer
#define NPB  144        // max 128-row panels (16384 + 8*255 pad, 256-aligned segments)

typedef _Float16 f16x8 __attribute__((ext_vector_type(8)));
typedef _Float16 f16x4 __attribute__((ext_vector_type(4)));
typedef float    f32x4 __attribute__((ext_vector_type(4)));
typedef short    s16x8 __attribute__((ext_vector_type(8)));

#define MFMA_F16(A,B,C)  __builtin_amdgcn_mfma_f32_16x16x32_f16((A),(B),(C),0,0,0)
#define MFMA_BF16(A,B,C) __builtin_amdgcn_mfma_f32_16x16x32_bf16((A),(B),(C),0,0,0)

__device__ __forceinline__ unsigned short f2bf(float f){
  union { float f; unsigned u; } v; v.f = f;
  unsigned r = v.u + 0x7fffu + ((v.u >> 16) & 1u);
  return (unsigned short)(r >> 16);
}
__device__ __forceinline__ void fsplit(float v, _Float16& hi, _Float16& lo){
  hi = (_Float16)v; lo = (_Float16)(v - (float)hi);
}
// async global->LDS, 16B per lane; LDS dest is wave-uniform base (+lane*16 implicit)
__device__ __forceinline__ void gload16(const void* g, void* l){
  __builtin_amdgcn_global_load_lds((const __attribute__((address_space(1))) unsigned int*)g,
                                   (__attribute__((address_space(3))) unsigned int*)l, 16, 0, 0);
}
#define BAR() __builtin_amdgcn_s_barrier()
#define VMW_BAR(N) do { \
  asm volatile("s_waitcnt vmcnt(" #N ")" ::: "memory"); \
  __builtin_amdgcn_s_barrier(); \
} while (0)

// ---------------- LN1: x -> h1 panel images (x64, hi/lo) ----------------
__global__ __launch_bounds__(128) void ln1_kernel(
    const float* __restrict__ x, const float* __restrict__ g, const float* __restrict__ be,
    unsigned char* __restrict__ aph, unsigned char* __restrict__ apl)
{
  const int row = blockIdx.x;
  const int t = threadIdx.x;             // 0..127, handles 8 cols
  __shared__ float red[2];
  float4 va = ((const float4*)(x + (size_t)row*DN))[t*2];
  float4 vb = ((const float4*)(x + (size_t)row*DN))[t*2+1];
  float s = va.x+va.y+va.z+va.w + vb.x+vb.y+vb.z+vb.w;
  #pragma unroll
  for (int m = 32; m >= 1; m >>= 1) s += __shfl_xor(s, m);
  if ((t & 63) == 0) red[t >> 6] = s;
  __syncthreads();
  const float mu = (red[0] + red[1]) * (1.0f / DN);
  float e[8] = { va.x-mu, va.y-mu, va.z-mu, va.w-mu, vb.x-mu, vb.y-mu, vb.z-mu, vb.w-mu };
  float s2 = 0.0f;
  #pragma unroll
  for (int i = 0; i < 8; i++) s2 += e[i]*e[i];
  #pragma unroll
  for (int m = 32; m >= 1; m >>= 1) s2 += __shfl_xor(s2, m);
  __syncthreads();
  if ((t & 63) == 0) red[t >> 6] = s2;
  __syncthreads();
  const float var = (red[0] + red[1]) * (1.0f / DN);
  const float rs = 1.0f / sqrtf(var + 1e-5f);
  float4 ga = ((const float4*)g)[t*2], gb = ((const float4*)g)[t*2+1];
  float4 ba = ((const float4*)be)[t*2], bb = ((const float4*)be)[t*2+1];
  float gg[8] = { ga.x,ga.y,ga.z,ga.w, gb.x,gb.y,gb.z,gb.w };
  float bbv[8] = { ba.x,ba.y,ba.z,ba.w, bb.x,bb.y,bb.z,bb.w };
  f16x8 hi8, lo8;
  #pragma unroll
  for (int i = 0; i < 8; i++){
    _Float16 hi, lo; fsplit((e[i]*rs*gg[i] + bbv[i]) * 64.0f, hi, lo);
    hi8[i] = hi; lo8[i] = lo;
  }
  const int pb = row >> 7, r = row & 127, kt = t >> 3, kk8 = t & 7;
  size_t po = ((size_t)(pb*16 + kt))*16384 + r*128 + (size_t)((kk8 ^ (r & 7)) << 4);
  *(f16x8*)(aph + po) = hi8;
  *(f16x8*)(apl + po) = lo8;
}

// ---------------- attention weights -> B panel images (x1024, hi/lo) ----------------
__global__ __launch_bounds__(256) void wsplit_kernel(
    const float* __restrict__ Wq, const float* __restrict__ Wk, const float* __restrict__ Wv,
    const float* __restrict__ Wp,
    unsigned char* __restrict__ bqh, unsigned char* __restrict__ bql,
    unsigned char* __restrict__ bph, unsigned char* __restrict__ bpl)
{
  int b = blockIdx.x;
  const int t = threadIdx.x;
  const int r = t & 127;
  const int c0 = (t >> 7) * 4;     // physical slots c0..c0+3
  if (b < 384){
    int nb = b >> 4, kt = b & 15;
    int n = nb*128 + r;
    int mat = n >> 10, h = (n >> 6) & 15, hs = n & 63;
    const float* W = (mat == 0) ? Wq : ((mat == 1) ? Wk : Wv);
    const float* src = W + (size_t)h*65536 + hs;     // + k*64
    unsigned char* ph = bqh + ((size_t)(nb*16 + kt))*16384 + r*128;
    unsigned char* pl = bql + ((size_t)(nb*16 + kt))*16384 + r*128;
    #pragma unroll
    for (int c = c0; c < c0 + 4; c++){
      int kk8 = c ^ (r & 7);
      f16x8 hi8, lo8;
      #pragma unroll
      for (int j = 0; j < 8; j++){
        _Float16 hi, lo; fsplit(src[(size_t)(kt*64 + kk8*8 + j)*64] * 1024.0f, hi, lo);
        hi8[j] = hi; lo8[j] = lo;
      }
      *(f16x8*)(ph + c*16) = hi8;
      *(f16x8*)(pl + c*16) = lo8;
    }
  } else {
    b -= 384;
    int nb = b >> 4, kt = b & 15;
    int n = nb*128 + r;
    unsigned char* ph = bph + ((size_t)(nb*16 + kt))*16384 + r*128;
    unsigned char* pl = bpl + ((size_t)(nb*16 + kt))*16384 + r*128;
    #pragma unroll
    for (int c = c0; c < c0 + 4; c++){
      int kk8 = c ^ (r & 7);
      f16x8 hi8, lo8;
      #pragma unroll
      for (int j = 0; j < 8; j++){
        _Float16 hi, lo; fsplit(Wp[(size_t)(kt*64 + kk8*8 + j)*DN + n] * 1024.0f, hi, lo);
        hi8[j] = hi; lo8[j] = lo;
      }
      *(f16x8*)(ph + c*16) = hi8;
      *(f16x8*)(pl + c*16) = lo8;
    }
  }
}

// ---------------- QKV GEMM: 128x128, fused 3-product split (one K pass) ----------------
// V (mat==2) is written TRANSPOSED: [b,h,hs,t] so attention can stage V^T vectorized.
__global__ __launch_bounds__(256) void qkv_gemm_kernel(
    const unsigned char* __restrict__ aph, const unsigned char* __restrict__ apl,
    const unsigned char* __restrict__ bqh, const unsigned char* __restrict__ bql,
    _Float16* __restrict__ qkvout)
{
  const int mb = blockIdx.x;    // 0..63
  const int nb = blockIdx.y;    // 0..23
  __shared__ __align__(16) unsigned char Ah[16384], Al[16384], Bh[16384], Bl[16384];
  const int t = threadIdx.x, w = t >> 6, lane = t & 63, lg = lane >> 4, lr = lane & 15;
  const int wr = w >> 1, wc = w & 1;
  const unsigned char* sb;
  unsigned char* dp;
  if (w == 0){ sb = aph + ((size_t)(mb*16))*16384; dp = Ah; }
  else if (w == 1){ sb = apl + ((size_t)(mb*16))*16384; dp = Al; }
  else if (w == 2){ sb = bqh + ((size_t)(nb*16))*16384; dp = Bh; }
  else { sb = bql + ((size_t)(nb*16))*16384; dp = Bl; }
  sb += lane*16;
  f32x4 acc[4][4] = {};
  for (int kt = 0; kt < 16; kt++){
    const unsigned char* s2 = sb + (size_t)kt*16384;
    #pragma unroll
    for (int j = 0; j < 16; j++) gload16(s2 + j*1024, dp + j*1024);
    __syncthreads();
    #pragma unroll
    for (int ks = 0; ks < 2; ks++){
      f16x8 ah[4], al[4], bh[4], bl[4];
      #pragma unroll
      for (int f = 0; f < 4; f++){
        int ra = wr*64 + f*16 + lr;
        int off = (ks*64 + lg*16) ^ ((ra & 7) << 4);
        ah[f] = *(const f16x8*)(Ah + ra*128 + off);
        al[f] = *(const f16x8*)(Al + ra*128 + off);
      }
      #pragma unroll
      for (int f = 0; f < 4; f++){
        int rb = wc*64 + f*16 + lr;
        int off = (ks*64 + lg*16) ^ ((rb & 7) << 4);
        bh[f] = *(const f16x8*)(Bh + rb*128 + off);
        bl[f] = *(const f16x8*)(Bl + rb*128 + off);
      }
      #pragma unroll
      for (int fm = 0; fm < 4; fm++)
      #pragma unroll
      for (int fn = 0; fn < 4; fn++){
        acc[fm][fn] = MFMA_F16(ah[fm], bh[fn], acc[fm][fn]);
        acc[fm][fn] = MFMA_F16(al[fm], bh[fn], acc[fm][fn]);
        acc[fm][fn] = MFMA_F16(ah[fm], bl[fn], acc[fm][fn]);
      }
    }
    __syncthreads();
  }
  #pragma unroll
  for (int fm = 0; fm < 4; fm++)
  #pragma unroll
  for (int fn = 0; fn < 4; fn++)
  #pragma unroll
  for (int rr = 0; rr < 4; rr++){
    int m = mb*128 + wr*64 + fm*16 + lg*4 + rr;
    int n = nb*128 + wc*64 + fn*16 + lr;
    int mat = n >> 10, h = (n >> 6) & 15, hs = n & 63;
    int bb = m >> 10, tt = m & 1023;
    _Float16* dsthi = qkvout + (size_t)mat * 2u * NQ;
    _Float16* dstlo = dsthi + NQ;
    size_t oi;
    if (mat == 2)  // V transposed: [b][h][hs][t]
      oi = (((size_t)(bb*HN + h))*HSN + hs)*TN + tt;
    else
      oi = (((size_t)(bb*HN + h))*TN + tt)*HSN + hs;
    _Float16 hi, lo; fsplit(acc[fm][fn][rr] * (1.0f/1024.0f), hi, lo);  // = 64*q
    dsthi[oi] = hi; dstlo[oi] = lo;
  }
}

// ---------------- flash attention (split f16, V^T input) ----------------
__global__ __launch_bounds__(256) void attn_kernel(
    const _Float16* __restrict__ qkv,
    _Float16* __restrict__ ohi_, _Float16* __restrict__ olo_)
{
  const _Float16* qhi = qkv;
  const _Float16* qlo = qkv + NQ;
  const _Float16* khi = qkv + 2u*NQ;
  const _Float16* klo = qkv + 3u*NQ;
  const _Float16* vhi = qkv + 4u*NQ;   // layout [b,h,hs,t]
  const _Float16* vlo = qkv + 5u*NQ;
  const int qt = blockIdx.x;     // 0..15
  const int bh = blockIdx.y;     // 0..127
  const size_t base = (size_t)bh * TN * HSN;   // same element count for V^T
  const int t = threadIdx.x, wid = t >> 6, lane = t & 63, lg = lane >> 4, lr = lane & 15;
  __shared__ _Float16 Khi[64][72], Klo[64][72], Vthi[64][72], Vtlo[64][72], Phi[64][72], Plo[64][72];
  f16x8 qh[2], ql[2];
  {
    const int qrow = qt*64 + wid*16 + lr;
    const _Float16* qp  = qhi + base + (size_t)qrow*HSN;
    const _Float16* qpl = qlo + base + (size_t)qrow*HSN;
    #pragma unroll
    for (int c = 0; c < 2; c++){
      qh[c] = *(const f16x8*)(qp  + c*32 + lg*8);
      ql[c] = *(const f16x8*)(qpl + c*32 + lg*8);
    }
  }
  f32x4 oacc[4] = {};
  float mrow[4], lsum[4];
  #pragma unroll
  for (int r = 0; r < 4; r++){ mrow[r] = -INFINITY; lsum[r] = 0.0f; }
  const int sr = t >> 2, sc = (t & 3) * 16;
  const float sscale = 1.0f / (4096.0f * 32.0f);
  for (int kvt = 0; kvt <= qt; kvt++){
    {
      const size_t gr = base + (size_t)(kvt*64 + sr)*HSN + sc;
      *(f16x8*)&Khi[sr][sc]     = *(const f16x8*)(khi + gr);
      *(f16x8*)&Khi[sr][sc + 8] = *(const f16x8*)(khi + gr + 8);
      *(f16x8*)&Klo[sr][sc]     = *(const f16x8*)(klo + gr);
      *(f16x8*)&Klo[sr][sc + 8] = *(const f16x8*)(klo + gr + 8);
      // V^T: row sr = hs, cols = t within tile (vectorized, no transpose)
      const size_t gv = base + (size_t)sr*TN + kvt*64 + sc;
      *(f16x8*)&Vthi[sr][sc]     = *(const f16x8*)(vhi + gv);
      *(f16x8*)&Vthi[sr][sc + 8] = *(const f16x8*)(vhi + gv + 8);
      *(f16x8*)&Vtlo[sr][sc]     = *(const f16x8*)(vlo + gv);
      *(f16x8*)&Vtlo[sr][sc + 8] = *(const f16x8*)(vlo + gv + 8);
    }
    __syncthreads();
    f32x4 sacc[4] = {};
    #pragma unroll
    for (int c = 0; c < 2; c++)
    #pragma unroll
    for (int fn = 0; fn < 4; fn++){
      f16x8 kh = *(const f16x8*)&Khi[fn*16 + lr][c*32 + lg*8];
      f16x8 kl = *(const f16x8*)&Klo[fn*16 + lr][c*32 + lg*8];
      sacc[fn] = MFMA_F16(qh[c], kh, sacc[fn]);
      sacc[fn] = MFMA_F16(qh[c], kl, sacc[fn]);
      sacc[fn] = MFMA_F16(ql[c], kh, sacc[fn]);
    }
    float sv[4][4], pmax[4];
    #pragma unroll
    for (int r = 0; r < 4; r++) pmax[r] = -INFINITY;
    const int qg0 = qt*64 + wid*16 + lg*4;
    #pragma unroll
    for (int fn = 0; fn < 4; fn++)
    #pragma unroll
    for (int r = 0; r < 4; r++){
      float xv = sacc[fn][r] * sscale;
      int kvg = kvt*64 + fn*16 + lr;
      xv = (kvg <= qg0 + r) ? xv : -INFINITY;
      sv[fn][r] = xv;
      pmax[r] = fmaxf(pmax[r], xv);
    }
    #pragma unroll
    for (int r = 0; r < 4; r++){
      #pragma unroll
      for (int m = 1; m < 16; m <<= 1) pmax[r] = fmaxf(pmax[r], __shfl_xor(pmax[r], m));
    }
    float alpha[4], mnew[4], psum[4];
    #pragma unroll
    for (int r = 0; r < 4; r++){
      mnew[r] = fmaxf(mrow[r], pmax[r]);
      alpha[r] = __expf(mrow[r] - mnew[r]);
      psum[r] = 0.0f;
    }
    #pragma unroll
    for (int fn = 0; fn < 4; fn++)
    #pragma unroll
    for (int r = 0; r < 4; r++){
      float p = __expf(sv[fn][r] - mnew[r]);
      psum[r] += p;
      _Float16 hi, lo; fsplit(p * 512.0f, hi, lo);
      Phi[wid*16 + lg*4 + r][fn*16 + lr] = hi;
      Plo[wid*16 + lg*4 + r][fn*16 + lr] = lo;
    }
    #pragma unroll
    for (int r = 0; r < 4; r++){
      #pragma unroll
      for (int m = 1; m < 16; m <<= 1) psum[r] += __shfl_xor(psum[r], m);
      lsum[r] = lsum[r]*alpha[r] + psum[r];
      mrow[r] = mnew[r];
    }
    #pragma unroll
    for (int fn = 0; fn < 4; fn++)
    #pragma unroll
    for (int r = 0; r < 4; r++) oacc[fn][r] *= alpha[r];
    #pragma unroll
    for (int c2 = 0; c2 < 2; c2++){
      f16x8 ph = *(const f16x8*)&Phi[wid*16 + lr][c2*32 + lg*8];
      f16x8 pl = *(const f16x8*)&Plo[wid*16 + lr][c2*32 + lg*8];
      #pragma unroll
      for (int fn = 0; fn < 4; fn++){
        f16x8 vh = *(const f16x8*)&Vthi[fn*16 + lr][c2*32 + lg*8];
        f16x8 vl = *(const f16x8*)&Vtlo[fn*16 + lr][c2*32 + lg*8];
        oacc[fn] = MFMA_F16(ph, vh, oacc[fn]);
        oacc[fn] = MFMA_F16(ph, vl, oacc[fn]);
        oacc[fn] = MFMA_F16(pl, vh, oacc[fn]);
      }
    }
    __syncthreads();
  }
  const int bb = bh >> 4, hh = bh & 15;
  #pragma unroll
  for (int fn = 0; fn < 4; fn++)
  #pragma unroll
  for (int r = 0; r < 4; r++){
    float ov = oacc[fn][r] / (32768.0f * lsum[r]);   // 512*64 scale
    int m = qt*64 + wid*16 + lg*4 + r;
    size_t oi = ((size_t)(bb*TN + m))*DN + hh*HSN + fn*16 + lr;
    _Float16 hi, lo; fsplit(ov * 64.0f, hi, lo);
    ohi_[oi] = hi; olo_[oi] = lo;
  }
}

// ---------------- proj GEMM + residual: 128x128, fused 3-product split -----------------
__global__ __launch_bounds__(256) void proj_gemm_kernel(
    const _Float16* __restrict__ ohi, const _Float16* __restrict__ olo,
    const unsigned char* __restrict__ bph, const unsigned char* __restrict__ bpl,
    const float* __restrict__ x, const float* __restrict__ bproj,
    float* __restrict__ out)
{
  const int mb = blockIdx.x;    // 0..63
  const int nb = blockIdx.y;    // 0..7
  __shared__ __align__(16) unsigned char Ah[16384], Al[16384], Bh[16384], Bl[16384];
  const int t = threadIdx.x, w = t >> 6, lane = t & 63, lg = lane >> 4, lr = lane & 15;
  const int wr = w >> 1, wc = w & 1;
  f32x4 acc[4][4] = {};
  const unsigned char* sbB = ((w == 2) ? bph : bpl) + ((size_t)(nb*16))*16384 + lane*16;
  unsigned char* dpB = (w == 2) ? Bh : Bl;
  const _Float16* aSrc = (w == 0) ? ohi : olo;
  unsigned char* dpA = (w == 0) ? Ah : Al;
  const int rA = lane >> 3;          // + j*8
  const int cA = lane & 7;
  for (int kt = 0; kt < 16; kt++){
    if (w < 2){
      #pragma unroll
      for (int j = 0; j < 16; j++){
        int r = rA + j*8;
        const unsigned char* s2 = (const unsigned char*)(aSrc + (size_t)(mb*128 + r)*DN)
                                  + kt*128 + ((cA ^ (r & 7)) << 4);
        gload16(s2, dpA + j*1024);
      }
    } else {
      const unsigned char* s2 = sbB + (size_t)kt*16384;
      #pragma unroll
      for (int j = 0; j < 16; j++) gload16(s2 + j*1024, dpB + j*1024);
    }
    __syncthreads();
    #pragma unroll
    for (int ks = 0; ks < 2; ks++){
      f16x8 ah[4], al[4], bh[4], bl[4];
      #pragma unroll
      for (int f = 0; f < 4; f++){
        int ra = wr*64 + f*16 + lr;
        int off = (ks*64 + lg*16) ^ ((ra & 7) << 4);
        ah[f] = *(const f16x8*)(Ah + ra*128 + off);
        al[f] = *(const f16x8*)(Al + ra*128 + off);
      }
      #pragma unroll
      for (int f = 0; f < 4; f++){
        int rb = wc*64 + f*16 + lr;
        int off = (ks*64 + lg*16) ^ ((rb & 7) << 4);
        bh[f] = *(const f16x8*)(Bh + rb*128 + off);
        bl[f] = *(const f16x8*)(Bl + rb*128 + off);
      }
      #pragma unroll
      for (int fm = 0; fm < 4; fm++)
      #pragma unroll
      for (int fn = 0; fn < 4; fn++){
        acc[fm][fn] = MFMA_F16(ah[fm], bh[fn], acc[fm][fn]);
        acc[fm][fn] = MFMA_F16(al[fm], bh[fn], acc[fm][fn]);
        acc[fm][fn] = MFMA_F16(ah[fm], bl[fn], acc[fm][fn]);
      }
    }
    __syncthreads();
  }
  #pragma unroll
  for (int fm = 0; fm < 4; fm++)
  #pragma unroll
  for (int fn = 0; fn < 4; fn++)
  #pragma unroll
  for (int rr = 0; rr < 4; rr++){
    int m = mb*128 + wr*64 + fm*16 + lg*4 + rr;
    int n = nb*128 + wc*64 + fn*16 + lr;
    size_t oi = (size_t)m*DN + n;
    out[oi] = x[oi] + acc[fm][fn][rr] * (1.0f/65536.0f) + bproj[n];
  }
}

// ---------------- router: LN2 (fp32) + logits + noisy top-2 + h2(bf16) ----------------
__global__ __launch_bounds__(256) void router_kernel(
    const float* __restrict__ x1, const float* __restrict__ g, const float* __restrict__ be,
    const float* __restrict__ Wr, const float* __restrict__ br,
    const float* __restrict__ Wn, const float* __restrict__ bn,
    const float* __restrict__ noise, unsigned short* __restrict__ h2bf,
    int* __restrict__ topk_e, float* __restrict__ topk_g, int* __restrict__ counts)
{
  const int token = blockIdx.x;
  const int t = threadIdx.x;
  __shared__ float redsum[4];
  __shared__ float red[64];
  float4 v = ((const float4*)(x1 + (size_t)token * DN))[t];
  float s = v.x + v.y + v.z + v.w;
  #pragma unroll
  for (int m = 32; m >= 1; m >>= 1) s += __shfl_xor(s, m);
  if ((t & 63) == 0) redsum[t >> 6] = s;
  __syncthreads();
  const float mu = (redsum[0] + redsum[1] + redsum[2] + redsum[3]) * (1.0f / DN);
  const float d0 = v.x - mu, d1 = v.y - mu, d2 = v.z - mu, d3 = v.w - mu;
  float s2 = d0*d0 + d1*d1 + d2*d2 + d3*d3;
  #pragma unroll
  for (int m = 32; m >= 1; m >>= 1) s2 += __shfl_xor(s2, m);
  __syncthreads();
  if ((t & 63) == 0) redsum[t >> 6] = s2;
  __syncthreads();
  const float var = (redsum[0] + redsum[1] + redsum[2] + redsum[3]) * (1.0f / DN);
  const float rs = 1.0f / sqrtf(var + 1e-5f);
  float4 gv = ((const float4*)g)[t];
  float4 bv = ((const float4*)be)[t];
  float h0 = d0*rs*gv.x + bv.x, h1v = d1*rs*gv.y + bv.y, h2v = d2*rs*gv.z + bv.z, h3 = d3*rs*gv.w + bv.w;
  ushort4 hb;
  hb.x = f2bf(h0); hb.y = f2bf(h1v); hb.z = f2bf(h2v); hb.w = f2bf(h3);
  *(ushort4*)(h2bf + (size_t)token*DN + t*4) = hb;
  float acc[16];
  const int j = t * 4;
  #pragma unroll
  for (int e = 0; e < 8; e++){
    acc[e]     = h0*Wr[(j+0)*8+e] + h1v*Wr[(j+1)*8+e] + h2v*Wr[(j+2)*8+e] + h3*Wr[(j+3)*8+e];
    acc[8 + e] = h0*Wn[(j+0)*8+e] + h1v*Wn[(j+1)*8+e] + h2v*Wn[(j+2)*8+e] + h3*Wn[(j+3)*8+e];
  }
  #pragma unroll
  for (int q = 0; q < 16; q++){
    #pragma unroll
    for (int m = 32; m >= 1; m >>= 1) acc[q] += __shfl_xor(acc[q], m);
  }
  if ((t & 63) == 0){
    #pragma unroll
    for (int q = 0; q < 16; q++) red[(t >> 6)*16 + q] = acc[q];
  }
  __syncthreads();
  if (t < 16) red[t] = red[t] + red[16 + t] + red[32 + t] + red[48 + t];
  __syncthreads();
  if (t == 0){
    float nz[8];
    #pragma unroll
    for (int e = 0; e < 8; e++){
      float logit = red[e] + br[e];
      float a = red[8 + e] + bn[e];
      float sp = (a > 20.0f) ? a : log1pf(expf(a));
      nz[e] = logit + noise[(size_t)token*EN + e] * sp;
    }
    float v1 = -INFINITY, v2 = -INFINITY; int i1 = 0, i2 = 0;
    #pragma unroll
    for (int e = 0; e < 8; e++){
      float z = nz[e];
      if (z > v1){ v2 = v1; i2 = i1; v1 = z; i1 = e; }
      else if (z > v2){ v2 = z; i2 = e; }
    }
    float e2 = expf(v2 - v1);
    float den = 1.0f + e2;
    topk_e[token*2]     = i1; topk_e[token*2 + 1] = i2;
    topk_g[token*2]     = 1.0f/den; topk_g[token*2 + 1] = e2/den;
    atomicAdd(&counts[i1], 1); atomicAdd(&counts[i2], 1);
  }
}

// 256-aligned expert segment offsets (moe tiles are 256 rows)
__global__ void scan_kernel(const int* __restrict__ counts, int* __restrict__ offs)
{
  if (threadIdx.x == 0 && blockIdx.x == 0){
    int a = 0;
    for (int e = 0; e < EN; e++){ offs[e] = a; a += (counts[e] + 255) & ~255; }
  }
}

__global__ __launch_bounds__(256) void scatter_kernel(
    const int* __restrict__ topk_e, const float* __restrict__ topk_g,
    const int* __restrict__ offs, int* __restrict__ fill,
    int* __restrict__ rows, float* __restrict__ grow)
{
  const int token = blockIdx.x*256 + threadIdx.x;
  #pragma unroll
  for (int i = 0; i < 2; i++){
    int e = topk_e[token*2 + i];
    int pos = offs[e] + atomicAdd(&fill[e], 1);
    rows[pos] = token;
    grow[pos] = topk_g[token*2 + i];
  }
}

// ---------------- expert weights -> 16KB LDS-image panels (bf16, swizzle baked) --------
__global__ __launch_bounds__(256) void wconv_kernel(
    const float* __restrict__ W1, const float* __restrict__ W2,
    unsigned char* __restrict__ w1p, unsigned char* __restrict__ w2p)
{
  int b = blockIdx.x;
  const float* W; unsigned char* pan; int Nd, kt, n;
  if (b < 2048){
    int e = b >> 8, rem = b & 255, nb2 = rem >> 4; kt = rem & 15;
    n = nb2*256 + threadIdx.x;                       // 0..4095
    W = W1 + (size_t)e * DN * DFN; Nd = DFN;
    pan = w1p + (((size_t)e*32 + (n >> 7))*16 + kt) * 16384;
  } else {
    b -= 2048;
    int e = b >> 8, rem = b & 255, nb2 = rem >> 6; kt = rem & 63;
    n = nb2*256 + threadIdx.x;                       // 0..1023
    W = W2 + (size_t)e * DFN * DN; Nd = DN;
    pan = w2p + (((size_t)e*8 + (n >> 7))*64 + kt) * 16384;
  }
  const int r = n & 127;
  #pragma unroll
  for (int kk8 = 0; kk8 < 8; kk8++){
    union { unsigned short u[8]; uint4 v; } buf;
    #pragma unroll
    for (int j = 0; j < 8; j++)
      buf.u[j] = f2bf(W[(size_t)(kt*64 + kk8*8 + j)*Nd + n]);
    *(uint4*)(pan + r*128 + ((kk8 ^ (r & 7)) << 4)) = buf.v;
  }
}

// ---------------- gather tokens into A panels: apnl[pb][kt16][16KB image] ----------------
__global__ __launch_bounds__(256) void agather_kernel(
    const unsigned short* __restrict__ h2bf, const int* __restrict__ rows,
    unsigned char* __restrict__ apnl)
{
  const int pb = blockIdx.x, kt = blockIdx.y;
  const int t = threadIdx.x;
  const int r = t >> 1, c0 = (t & 1) * 4;
  const int tok = rows[pb*128 + r];
  const unsigned char* src = (const unsigned char*)h2bf + (size_t)tok*2048 + kt*128;
  unsigned char* dst = apnl + ((size_t)pb*16 + kt)*16384 + r*128;
  #pragma unroll
  for (int i = 0; i < 4; i++){
    int c = c0 + i;
    *(uint4*)(dst + ((c ^ (r & 7)) << 4)) = *(const uint4*)(src + c*16);
  }
}

// ---------------- MoE GEMM1 (persistent, 2D-window, single-barrier T3-min loop) --------
__global__ __launch_bounds__(512, 1) void moe1_kernel(
    const unsigned char* __restrict__ apnl, const unsigned char* __restrict__ w1p,
    const float* __restrict__ b1,
    const int* __restrict__ counts, const int* __restrict__ offs,
    unsigned short* __restrict__ midP)
{
  __shared__ __align__(16) unsigned char As[2][32768], Bs[2][32768];
  const int bid = blockIdx.x;
  const int t = threadIdx.x;
  const int w = t >> 6, lane = t & 63, lg = lane >> 4, lr = lane & 15;
  const int wm = w >> 2, wn = w & 3;
  const int sp = (w >> 1) & 1, sh = (w & 1) * 8192;
  const int e  = bid & 7;
  const int c  = bid >> 3;                 // CU slot within XCD, 0..31
  const int cnt = counts[e];
  const int off = offs[e];
  const int nmb = (cnt + 255) >> 8;
  const int nch = nmb * 16;
  for (int q = c; q < nch; q += 32){
    const int grp = q / (4*nmb);
    const int within = q - grp*4*nmb;
    const int mb = within >> 2;
    const int nb = grp*4 + (within & 3);   // 0..15 (256-col group)
    const int m0 = mb * 256;
    const int pb0 = (off + m0) >> 7;
    const unsigned char* sbase;
    unsigned char* dbase;
    if (w < 4){
      sbase = apnl + ((size_t)(pb0 + sp) * 16) * 16384 + sh + lane*16;
      dbase = &As[0][sp*16384 + sh];
    } else {
      sbase = w1p + ((size_t)(e*32 + nb*2 + sp) * 16) * 16384 + sh + lane*16;
      dbase = &Bs[0][sp*16384 + sh];
    }
    f32x4 acc[8][4] = {};
    auto stage = [&](int buf, int kt){
      const unsigned char* s2 = sbase + (size_t)kt * 16384;
      unsigned char* d = dbase + buf * 32768;
      #pragma unroll
      for (int j = 0; j < 8; j++) gload16(s2 + j*1024, d + j*1024);
    };
    auto compute = [&](int buf){
      const unsigned char* pA = &As[buf][wm*16384];
      const unsigned char* pB = &Bs[buf][(wn>>1)*16384];
      #pragma unroll
      for (int ks = 0; ks < 2; ks++){
        s16x8 b[4], a[8];
        #pragma unroll
        for (int f = 0; f < 4; f++){
          int rb = (wn&1)*64 + f*16 + lr;
          b[f] = *(const s16x8*)(pB + rb*128 + ((ks*64 + lg*16) ^ ((rb&7)<<4)));
        }
        #pragma unroll
        for (int f = 0; f < 8; f++){
          int ra = f*16 + lr;
          a[f] = *(const s16x8*)(pA + ra*128 + ((ks*64 + lg*16) ^ ((ra&7)<<4)));
        }
        __builtin_amdgcn_s_setprio(1);
        #pragma unroll
        for (int fm = 0; fm < 8; fm++)
        #pragma unroll
        for (int fn = 0; fn < 4; fn++)
          acc[fm][fn] = MFMA_BF16(a[fm], b[fn], acc[fm][fn]);
        __builtin_amdgcn_s_setprio(0);
      }
    };
    // T3-minimum single-barrier loop: stage(next) -> compute(cur) -> vmcnt(0)+barrier
    stage(0, 0);
    VMW_BAR(0);
    for (int kt = 0; kt < 16; kt += 2){
      stage(1, kt + 1);
      compute(0);
      VMW_BAR(0);
      if (kt + 2 < 16) stage(0, kt + 2);
      compute(1);
      VMW_BAR(0);
    }
    {
      unsigned char* Lp = ((wm == 0) ? (unsigned char*)As : (unsigned char*)Bs) + wn*16384;
      const float* b1e = b1 + (size_t)e*DFN + nb*256 + wn*64;
      #pragma unroll
      for (int fn = 0; fn < 4; fn++){
        float bias = b1e[fn*16 + lr];
        int col = fn*16 + lr;
        #pragma unroll
        for (int fm = 0; fm < 8; fm++)
        #pragma unroll
        for (int rr = 0; rr < 4; rr++){
          int r = fm*16 + lg*4 + rr;
          float v = fmaxf(acc[fm][fn][rr] + bias, 0.0f);
          *(unsigned short*)(Lp + r*128 + ((col ^ ((r & 7) << 3)) * 2)) = f2bf(v);
        }
      }
    }
    BAR();
    {
      int p = w >> 2, jj = w & 3;
      const uint4* src = (const uint4*)(((p == 0) ? (unsigned char*)As : (unsigned char*)Bs) + jj*16384);
      uint4* dst = (uint4*)((unsigned char*)midP + (((size_t)(pb0 + p)*64) + nb*4 + jj) * 16384);
      #pragma unroll
      for (int i = 0; i < 16; i++) dst[lane + i*64] = src[lane + i*64];
    }
    BAR();
  }
}

// ---------------- MoE GEMM2 (persistent, 2D-window, single-barrier T3-min loop) --------
__global__ __launch_bounds__(512, 1) void moe2_kernel(
    const unsigned char* __restrict__ midP, const unsigned char* __restrict__ w2p,
    const float* __restrict__ b2,
    const int* __restrict__ counts, const int* __restrict__ offs,
    const int* __restrict__ rows, const float* __restrict__ grow,
    float* __restrict__ out)
{
  __shared__ __align__(16) unsigned char As[2][32768], Bs[2][32768];
  const int bid = blockIdx.x;
  const int t = threadIdx.x;
  const int w = t >> 6, lane = t & 63, lg = lane >> 4, lr = lane & 15;
  const int wm = w >> 2, wn = w & 3;
  const int sp = (w >> 1) & 1, sh = (w & 1) * 8192;
  const int e  = bid & 7;
  const int c  = bid >> 3;
  const int cnt = counts[e];
  const int off = offs[e];
  const int nmb = (cnt + 255) >> 8;
  const int nch = nmb * 4;
  for (int q = c; q < nch; q += 32){
    const int mb = q >> 2;
    const int nb = q & 3;
    const int m0 = mb * 256;
    const int pb0 = (off + m0) >> 7;
    const unsigned char* sbase;
    unsigned char* dbase;
    if (w < 4){
      sbase = midP + ((size_t)(pb0 + sp) * 64) * 16384 + sh + lane*16;
      dbase = &As[0][sp*16384 + sh];
    } else {
      sbase = w2p + ((size_t)(e*8 + nb*2 + sp) * 64) * 16384 + sh + lane*16;
      dbase = &Bs[0][sp*16384 + sh];
    }
    f32x4 acc[8][4] = {};
    auto stage = [&](int buf, int kt){
      const unsigned char* s2 = sbase + (size_t)kt * 16384;
      unsigned char* d = dbase + buf * 32768;
      #pragma unroll
      for (int j = 0; j < 8; j++) gload16(s2 + j*1024, d + j*1024);
    };
    auto compute = [&](int buf){
      const unsigned char* pA = &As[buf][wm*16384];
      const unsigned char* pB = &Bs[buf][(wn>>1)*16384];
      #pragma unroll
      for (int ks = 0; ks < 2; ks++){
        s16x8 b[4], a[8];
        #pragma unroll
        for (int f = 0; f < 4; f++){
          int rb = (wn&1)*64 + f*16 + lr;
          b[f] = *(const s16x8*)(pB + rb*128 + ((ks*64 + lg*16) ^ ((rb&7)<<4)));
        }
        #pragma unroll
        for (int f = 0; f < 8; f++){
          int ra = f*16 + lr;
          a[f] = *(const s16x8*)(pA + ra*128 + ((ks*64 + lg*16) ^ ((ra&7)<<4)));
        }
        __builtin_amdgcn_s_setprio(1);
        #pragma unroll
        for (int fm = 0; fm < 8; fm++)
        #pragma unroll
        for (int fn = 0; fn < 4; fn++)
          acc[fm][fn] = MFMA_BF16(a[fm], b[fn], acc[fm][fn]);
        __builtin_amdgcn_s_setprio(0);
      }
    };
    // T3-minimum single-barrier loop
    stage(0, 0);
    VMW_BAR(0);
    for (int kt = 0; kt < 64; kt += 2){
      stage(1, kt + 1);
      compute(0);
      VMW_BAR(0);
      if (kt + 2 < 64) stage(0, kt + 2);
      compute(1);
      VMW_BAR(0);
    }
    const float* b2e = b2 + (size_t)e*DN + nb*256 + wn*64;
    #pragma unroll
    for (int fm = 0; fm < 8; fm++)
    #pragma unroll
    for (int rr = 0; rr < 4; rr++){
      int ml = wm*128 + fm*16 + lg*4 + rr;
      if (m0 + ml < cnt){
        int gi = off + m0 + ml;
        int tok = rows[gi];
        float gt = grow[gi];
        #pragma unroll
        for (int fn = 0; fn < 4; fn++){
          int n = nb*256 + wn*64 + fn*16 + lr;
          atomicAdd(out + (size_t)tok*DN + n, gt*(acc[fm][fn][rr] + b2e[fn*16 + lr]));
        }
      }
    }
  }
}

// ---------------- launch ----------------
extern "C" void kernel_launch(void* const* d_in, const int* in_sizes, int n_in,
                              void* d_out, int out_size, void* d_ws, size_t ws_size,
                              hipStream_t stream) {
  (void)in_sizes; (void)n_in; (void)out_size; (void)ws_size;
  const float* x     = (const float*)d_in[0];
  const float* noise = (const float*)d_in[1];
  const float* Wq    = (const float*)d_in[2];
  const float* Wk    = (const float*)d_in[3];
  const float* Wv    = (const float*)d_in[4];
  const float* Wp    = (const float*)d_in[5];
  const float* bproj = (const float*)d_in[6];
  const float* ln1g  = (const float*)d_in[7];
  const float* ln1b  = (const float*)d_in[8];
  const float* ln2g  = (const float*)d_in[9];
  const float* ln2b  = (const float*)d_in[10];
  const float* Wr    = (const float*)d_in[11];
  const float* br    = (const float*)d_in[12];
  const float* Wn    = (const float*)d_in[13];
  const float* bn    = (const float*)d_in[14];
  const float* W1    = (const float*)d_in[15];
  const float* b1    = (const float*)d_in[16];
  const float* W2    = (const float*)d_in[17];
  const float* b2    = (const float*)d_in[18];
  float* out = (float*)d_out;

  char* w = (char*)d_ws;
  auto alloc = [&](size_t bytes) -> char* {
    char* p = w; w += (bytes + 255) & ~(size_t)255; return p;
  };
  // Region A: qkv split + o split during attention; reused as panelized `mid` during MoE.
  char* big = alloc((size_t)NPB * 64 * 16384);          // 151 MB >= 134.2 MB qkv need
  _Float16* qkvsplit = (_Float16*)big;
  _Float16* ohi = (_Float16*)(big + (size_t)6*NQ*2);
  _Float16* olo = ohi + NQ;
  unsigned short* midP = (unsigned short*)big;
  // Region B: attention temporaries (dead after proj); W1 panels overlay them afterwards.
  char* attn_tmp = w;
  unsigned char* aph = (unsigned char*)alloc((size_t)64*16*16384);   // h1 hi panels 16 MB
  unsigned char* apl = (unsigned char*)alloc((size_t)64*16*16384);   // h1 lo panels 16 MB
  unsigned char* bqh = (unsigned char*)alloc((size_t)24*16*16384);   // qkv W hi panels 6.3 MB
  unsigned char* bql = (unsigned char*)alloc((size_t)24*16*16384);
  unsigned char* bph = (unsigned char*)alloc((size_t)8*16*16384);    // proj W hi panels 2.1 MB
  unsigned char* bpl = (unsigned char*)alloc((size_t)8*16*16384);
  unsigned char* w1p = (unsigned char*)attn_tmp;        // 64 MiB panels overlay
  char* w1p_end = attn_tmp + (size_t)EN*DFN*DN*2;
  if (w < w1p_end) w = w1p_end;
  unsigned char* w2p = (unsigned char*)alloc((size_t)EN*DN*DFN*2);   // 64 MiB
  unsigned char* apnl = (unsigned char*)alloc((size_t)NPB*16*16384); // 37.7 MB
  unsigned short* h2bf = (unsigned short*)alloc((size_t)NTOK*DN*2);
  int*   topk_e = (int*)alloc(NTOK*2*sizeof(int));
  float* topk_g = (float*)alloc(NTOK*2*sizeof(float));
  int*   rowsA  = (int*)alloc((size_t)NPB*128*sizeof(int));
  float* growA  = (float*)alloc((size_t)NPB*128*sizeof(float));
  int*   cnts   = (int*)alloc(256);
  int*   fill   = cnts + 8;
  int*   offs   = cnts + 16;

  (void)hipMemsetAsync(cnts, 0, 64, stream);                  // counts + fill
  (void)hipMemsetAsync(rowsA, 0, (size_t)NPB*128*sizeof(int), stream);
  ln1_kernel<<<NTOK, 128, 0, stream>>>(x, ln1g, ln1b, aph, apl);
  wsplit_kernel<<<512, 256, 0, stream>>>(Wq, Wk, Wv, Wp, bqh, bql, bph, bpl);
  qkv_gemm_kernel<<<dim3(64, 24), 256, 0, stream>>>(aph, apl, bqh, bql, qkvsplit);
  attn_kernel<<<dim3(16, 128), 256, 0, stream>>>(qkvsplit, ohi, olo);
  proj_gemm_kernel<<<dim3(64, 8), 256, 0, stream>>>(ohi, olo, bph, bpl, x, bproj, out);
  // attn temporaries now dead -> overlay weight panels
  wconv_kernel<<<4096, 256, 0, stream>>>(W1, W2, w1p, w2p);
  router_kernel<<<NTOK, 256, 0, stream>>>(out, ln2g, ln2b, Wr, br, Wn, bn, noise,
                                          h2bf, topk_e, topk_g, cnts);
  scan_kernel<<<1, 64, 0, stream>>>(cnts, offs);
  scatter_kernel<<<NTOK/256, 256, 0, stream>>>(topk_e, topk_g, offs, fill, rowsA, growA);
  agather_kernel<<<dim3(NPB, 16), 256, 0, stream>>>(h2bf, rowsA, apnl);
  moe1_kernel<<<256, 512, 0, stream>>>(apnl, w1p, b1, cnts, offs, midP);
  moe2_kernel<<<256, 512, 0, stream>>>((const unsigned char*)midP, w2p, b2,
                                       cnts, offs, rowsA, growA, out);
}

// Round 18
// 1441.771 us; speedup vs baseline: 1.1320x; 1.0255x over previous
//
#include <hip/hip_runtime.h>
#include <hip/hip_bf16.h>
#include <math.h>

#define NTOK 8192
#define DN   1024
#define HN   16
#define HSN  64
#define EN   8
#define DFN  4096
#define TN   1024
#define NQ   8388608u   // B*H*T*HS elements per q/k/v buffer
#define NPB  144        // max 128-row panels (16384 + 8*255 pad, 256-aligned segments)

typedef _Float16 f16x8 __attribute__((ext_vector_type(8)));
typedef _Float16 f16x4 __attribute__((ext_vector_type(4)));
typedef float    f32x4 __attribute__((ext_vector_type(4)));
typedef short    s16x8 __attribute__((ext_vector_type(8)));

#define MFMA_F16(A,B,C)  __builtin_amdgcn_mfma_f32_16x16x32_f16((A),(B),(C),0,0,0)
#define MFMA_BF16(A,B,C) __builtin_amdgcn_mfma_f32_16x16x32_bf16((A),(B),(C),0,0,0)

__device__ __forceinline__ unsigned short f2bf(float f){
  union { float f; unsigned u; } v; v.f = f;
  unsigned r = v.u + 0x7fffu + ((v.u >> 16) & 1u);
  return (unsigned short)(r >> 16);
}
__device__ __forceinline__ void fsplit(float v, _Float16& hi, _Float16& lo){
  hi = (_Float16)v; lo = (_Float16)(v - (float)hi);
}
// async global->LDS, 16B per lane; LDS dest is wave-uniform base (+lane*16 implicit)
__device__ __forceinline__ void gload16(const void* g, void* l){
  __builtin_amdgcn_global_load_lds((const __attribute__((address_space(1))) unsigned int*)g,
                                   (__attribute__((address_space(3))) unsigned int*)l, 16, 0, 0);
}
#define BAR() __builtin_amdgcn_s_barrier()
#define VMW_BAR(N) do { \
  asm volatile("s_waitcnt vmcnt(" #N ")" ::: "memory"); \
  __builtin_amdgcn_s_barrier(); \
} while (0)

// ---------------- LN1: x -> h1 panel images (x64, hi/lo) ----------------
__global__ __launch_bounds__(128) void ln1_kernel(
    const float* __restrict__ x, const float* __restrict__ g, const float* __restrict__ be,
    unsigned char* __restrict__ aph, unsigned char* __restrict__ apl)
{
  const int row = blockIdx.x;
  const int t = threadIdx.x;             // 0..127, handles 8 cols
  __shared__ float red[2];
  float4 va = ((const float4*)(x + (size_t)row*DN))[t*2];
  float4 vb = ((const float4*)(x + (size_t)row*DN))[t*2+1];
  float s = va.x+va.y+va.z+va.w + vb.x+vb.y+vb.z+vb.w;
  #pragma unroll
  for (int m = 32; m >= 1; m >>= 1) s += __shfl_xor(s, m);
  if ((t & 63) == 0) red[t >> 6] = s;
  __syncthreads();
  const float mu = (red[0] + red[1]) * (1.0f / DN);
  float e[8] = { va.x-mu, va.y-mu, va.z-mu, va.w-mu, vb.x-mu, vb.y-mu, vb.z-mu, vb.w-mu };
  float s2 = 0.0f;
  #pragma unroll
  for (int i = 0; i < 8; i++) s2 += e[i]*e[i];
  #pragma unroll
  for (int m = 32; m >= 1; m >>= 1) s2 += __shfl_xor(s2, m);
  __syncthreads();
  if ((t & 63) == 0) red[t >> 6] = s2;
  __syncthreads();
  const float var = (red[0] + red[1]) * (1.0f / DN);
  const float rs = 1.0f / sqrtf(var + 1e-5f);
  float4 ga = ((const float4*)g)[t*2], gb = ((const float4*)g)[t*2+1];
  float4 ba = ((const float4*)be)[t*2], bb = ((const float4*)be)[t*2+1];
  float gg[8] = { ga.x,ga.y,ga.z,ga.w, gb.x,gb.y,gb.z,gb.w };
  float bbv[8] = { ba.x,ba.y,ba.z,ba.w, bb.x,bb.y,bb.z,bb.w };
  f16x8 hi8, lo8;
  #pragma unroll
  for (int i = 0; i < 8; i++){
    _Float16 hi, lo; fsplit((e[i]*rs*gg[i] + bbv[i]) * 64.0f, hi, lo);
    hi8[i] = hi; lo8[i] = lo;
  }
  const int pb = row >> 7, r = row & 127, kt = t >> 3, kk8 = t & 7;
  size_t po = ((size_t)(pb*16 + kt))*16384 + r*128 + (size_t)((kk8 ^ (r & 7)) << 4);
  *(f16x8*)(aph + po) = hi8;
  *(f16x8*)(apl + po) = lo8;
}

// ---------------- attention weights -> B panel images (x1024, hi/lo) ----------------
__global__ __launch_bounds__(256) void wsplit_kernel(
    const float* __restrict__ Wq, const float* __restrict__ Wk, const float* __restrict__ Wv,
    const float* __restrict__ Wp,
    unsigned char* __restrict__ bqh, unsigned char* __restrict__ bql,
    unsigned char* __restrict__ bph, unsigned char* __restrict__ bpl)
{
  int b = blockIdx.x;
  const int t = threadIdx.x;
  const int r = t & 127;
  const int c0 = (t >> 7) * 4;     // physical slots c0..c0+3
  if (b < 384){
    int nb = b >> 4, kt = b & 15;
    int n = nb*128 + r;
    int mat = n >> 10, h = (n >> 6) & 15, hs = n & 63;
    const float* W = (mat == 0) ? Wq : ((mat == 1) ? Wk : Wv);
    const float* src = W + (size_t)h*65536 + hs;     // + k*64
    unsigned char* ph = bqh + ((size_t)(nb*16 + kt))*16384 + r*128;
    unsigned char* pl = bql + ((size_t)(nb*16 + kt))*16384 + r*128;
    #pragma unroll
    for (int c = c0; c < c0 + 4; c++){
      int kk8 = c ^ (r & 7);
      f16x8 hi8, lo8;
      #pragma unroll
      for (int j = 0; j < 8; j++){
        _Float16 hi, lo; fsplit(src[(size_t)(kt*64 + kk8*8 + j)*64] * 1024.0f, hi, lo);
        hi8[j] = hi; lo8[j] = lo;
      }
      *(f16x8*)(ph + c*16) = hi8;
      *(f16x8*)(pl + c*16) = lo8;
    }
  } else {
    b -= 384;
    int nb = b >> 4, kt = b & 15;
    int n = nb*128 + r;
    unsigned char* ph = bph + ((size_t)(nb*16 + kt))*16384 + r*128;
    unsigned char* pl = bpl + ((size_t)(nb*16 + kt))*16384 + r*128;
    #pragma unroll
    for (int c = c0; c < c0 + 4; c++){
      int kk8 = c ^ (r & 7);
      f16x8 hi8, lo8;
      #pragma unroll
      for (int j = 0; j < 8; j++){
        _Float16 hi, lo; fsplit(Wp[(size_t)(kt*64 + kk8*8 + j)*DN + n] * 1024.0f, hi, lo);
        hi8[j] = hi; lo8[j] = lo;
      }
      *(f16x8*)(ph + c*16) = hi8;
      *(f16x8*)(pl + c*16) = lo8;
    }
  }
}

// ---------------- QKV GEMM: 128x128, fused 3-product split (one K pass) ----------------
// V (mat==2) is written TRANSPOSED: [b,h,hs,t] so attention can stage V^T vectorized.
__global__ __launch_bounds__(256) void qkv_gemm_kernel(
    const unsigned char* __restrict__ aph, const unsigned char* __restrict__ apl,
    const unsigned char* __restrict__ bqh, const unsigned char* __restrict__ bql,
    _Float16* __restrict__ qkvout)
{
  const int mb = blockIdx.x;    // 0..63
  const int nb = blockIdx.y;    // 0..23
  __shared__ __align__(16) unsigned char Ah[16384], Al[16384], Bh[16384], Bl[16384];
  const int t = threadIdx.x, w = t >> 6, lane = t & 63, lg = lane >> 4, lr = lane & 15;
  const int wr = w >> 1, wc = w & 1;
  const unsigned char* sb;
  unsigned char* dp;
  if (w == 0){ sb = aph + ((size_t)(mb*16))*16384; dp = Ah; }
  else if (w == 1){ sb = apl + ((size_t)(mb*16))*16384; dp = Al; }
  else if (w == 2){ sb = bqh + ((size_t)(nb*16))*16384; dp = Bh; }
  else { sb = bql + ((size_t)(nb*16))*16384; dp = Bl; }
  sb += lane*16;
  f32x4 acc[4][4] = {};
  for (int kt = 0; kt < 16; kt++){
    const unsigned char* s2 = sb + (size_t)kt*16384;
    #pragma unroll
    for (int j = 0; j < 16; j++) gload16(s2 + j*1024, dp + j*1024);
    __syncthreads();
    #pragma unroll
    for (int ks = 0; ks < 2; ks++){
      f16x8 ah[4], al[4], bh[4], bl[4];
      #pragma unroll
      for (int f = 0; f < 4; f++){
        int ra = wr*64 + f*16 + lr;
        int off = (ks*64 + lg*16) ^ ((ra & 7) << 4);
        ah[f] = *(const f16x8*)(Ah + ra*128 + off);
        al[f] = *(const f16x8*)(Al + ra*128 + off);
      }
      #pragma unroll
      for (int f = 0; f < 4; f++){
        int rb = wc*64 + f*16 + lr;
        int off = (ks*64 + lg*16) ^ ((rb & 7) << 4);
        bh[f] = *(const f16x8*)(Bh + rb*128 + off);
        bl[f] = *(const f16x8*)(Bl + rb*128 + off);
      }
      #pragma unroll
      for (int fm = 0; fm < 4; fm++)
      #pragma unroll
      for (int fn = 0; fn < 4; fn++){
        acc[fm][fn] = MFMA_F16(ah[fm], bh[fn], acc[fm][fn]);
        acc[fm][fn] = MFMA_F16(al[fm], bh[fn], acc[fm][fn]);
        acc[fm][fn] = MFMA_F16(ah[fm], bl[fn], acc[fm][fn]);
      }
    }
    __syncthreads();
  }
  #pragma unroll
  for (int fm = 0; fm < 4; fm++)
  #pragma unroll
  for (int fn = 0; fn < 4; fn++)
  #pragma unroll
  for (int rr = 0; rr < 4; rr++){
    int m = mb*128 + wr*64 + fm*16 + lg*4 + rr;
    int n = nb*128 + wc*64 + fn*16 + lr;
    int mat = n >> 10, h = (n >> 6) & 15, hs = n & 63;
    int bb = m >> 10, tt = m & 1023;
    _Float16* dsthi = qkvout + (size_t)mat * 2u * NQ;
    _Float16* dstlo = dsthi + NQ;
    size_t oi;
    if (mat == 2)  // V transposed: [b][h][hs][t]
      oi = (((size_t)(bb*HN + h))*HSN + hs)*TN + tt;
    else
      oi = (((size_t)(bb*HN + h))*TN + tt)*HSN + hs;
    _Float16 hi, lo; fsplit(acc[fm][fn][rr] * (1.0f/1024.0f), hi, lo);  // = 64*q
    dsthi[oi] = hi; dstlo[oi] = lo;
  }
}

// ---------------- flash attention (split f16, V^T input) ----------------
__global__ __launch_bounds__(256) void attn_kernel(
    const _Float16* __restrict__ qkv,
    _Float16* __restrict__ ohi_, _Float16* __restrict__ olo_)
{
  const _Float16* qhi = qkv;
  const _Float16* qlo = qkv + NQ;
  const _Float16* khi = qkv + 2u*NQ;
  const _Float16* klo = qkv + 3u*NQ;
  const _Float16* vhi = qkv + 4u*NQ;   // layout [b,h,hs,t]
  const _Float16* vlo = qkv + 5u*NQ;
  const int qt = blockIdx.x;     // 0..15
  const int bh = blockIdx.y;     // 0..127
  const size_t base = (size_t)bh * TN * HSN;   // same element count for V^T
  const int t = threadIdx.x, wid = t >> 6, lane = t & 63, lg = lane >> 4, lr = lane & 15;
  __shared__ _Float16 Khi[64][72], Klo[64][72], Vthi[64][72], Vtlo[64][72], Phi[64][72], Plo[64][72];
  f16x8 qh[2], ql[2];
  {
    const int qrow = qt*64 + wid*16 + lr;
    const _Float16* qp  = qhi + base + (size_t)qrow*HSN;
    const _Float16* qpl = qlo + base + (size_t)qrow*HSN;
    #pragma unroll
    for (int c = 0; c < 2; c++){
      qh[c] = *(const f16x8*)(qp  + c*32 + lg*8);
      ql[c] = *(const f16x8*)(qpl + c*32 + lg*8);
    }
  }
  f32x4 oacc[4] = {};
  float mrow[4], lsum[4];
  #pragma unroll
  for (int r = 0; r < 4; r++){ mrow[r] = -INFINITY; lsum[r] = 0.0f; }
  const int sr = t >> 2, sc = (t & 3) * 16;
  const float sscale = 1.0f / (4096.0f * 32.0f);
  for (int kvt = 0; kvt <= qt; kvt++){
    {
      const size_t gr = base + (size_t)(kvt*64 + sr)*HSN + sc;
      *(f16x8*)&Khi[sr][sc]     = *(const f16x8*)(khi + gr);
      *(f16x8*)&Khi[sr][sc + 8] = *(const f16x8*)(khi + gr + 8);
      *(f16x8*)&Klo[sr][sc]     = *(const f16x8*)(klo + gr);
      *(f16x8*)&Klo[sr][sc + 8] = *(const f16x8*)(klo + gr + 8);
      // V^T: row sr = hs, cols = t within tile (vectorized, no transpose)
      const size_t gv = base + (size_t)sr*TN + kvt*64 + sc;
      *(f16x8*)&Vthi[sr][sc]     = *(const f16x8*)(vhi + gv);
      *(f16x8*)&Vthi[sr][sc + 8] = *(const f16x8*)(vhi + gv + 8);
      *(f16x8*)&Vtlo[sr][sc]     = *(const f16x8*)(vlo + gv);
      *(f16x8*)&Vtlo[sr][sc + 8] = *(const f16x8*)(vlo + gv + 8);
    }
    __syncthreads();
    f32x4 sacc[4] = {};
    #pragma unroll
    for (int c = 0; c < 2; c++)
    #pragma unroll
    for (int fn = 0; fn < 4; fn++){
      f16x8 kh = *(const f16x8*)&Khi[fn*16 + lr][c*32 + lg*8];
      f16x8 kl = *(const f16x8*)&Klo[fn*16 + lr][c*32 + lg*8];
      sacc[fn] = MFMA_F16(qh[c], kh, sacc[fn]);
      sacc[fn] = MFMA_F16(qh[c], kl, sacc[fn]);
      sacc[fn] = MFMA_F16(ql[c], kh, sacc[fn]);
    }
    float sv[4][4], pmax[4];
    #pragma unroll
    for (int r = 0; r < 4; r++) pmax[r] = -INFINITY;
    const int qg0 = qt*64 + wid*16 + lg*4;
    #pragma unroll
    for (int fn = 0; fn < 4; fn++)
    #pragma unroll
    for (int r = 0; r < 4; r++){
      float xv = sacc[fn][r] * sscale;
      int kvg = kvt*64 + fn*16 + lr;
      xv = (kvg <= qg0 + r) ? xv : -INFINITY;
      sv[fn][r] = xv;
      pmax[r] = fmaxf(pmax[r], xv);
    }
    #pragma unroll
    for (int r = 0; r < 4; r++){
      #pragma unroll
      for (int m = 1; m < 16; m <<= 1) pmax[r] = fmaxf(pmax[r], __shfl_xor(pmax[r], m));
    }
    float alpha[4], mnew[4], psum[4];
    #pragma unroll
    for (int r = 0; r < 4; r++){
      mnew[r] = fmaxf(mrow[r], pmax[r]);
      alpha[r] = __expf(mrow[r] - mnew[r]);
      psum[r] = 0.0f;
    }
    #pragma unroll
    for (int fn = 0; fn < 4; fn++)
    #pragma unroll
    for (int r = 0; r < 4; r++){
      float p = __expf(sv[fn][r] - mnew[r]);
      psum[r] += p;
      _Float16 hi, lo; fsplit(p * 512.0f, hi, lo);
      Phi[wid*16 + lg*4 + r][fn*16 + lr] = hi;
      Plo[wid*16 + lg*4 + r][fn*16 + lr] = lo;
    }
    #pragma unroll
    for (int r = 0; r < 4; r++){
      #pragma unroll
      for (int m = 1; m < 16; m <<= 1) psum[r] += __shfl_xor(psum[r], m);
      lsum[r] = lsum[r]*alpha[r] + psum[r];
      mrow[r] = mnew[r];
    }
    #pragma unroll
    for (int fn = 0; fn < 4; fn++)
    #pragma unroll
    for (int r = 0; r < 4; r++) oacc[fn][r] *= alpha[r];
    #pragma unroll
    for (int c2 = 0; c2 < 2; c2++){
      f16x8 ph = *(const f16x8*)&Phi[wid*16 + lr][c2*32 + lg*8];
      f16x8 pl = *(const f16x8*)&Plo[wid*16 + lr][c2*32 + lg*8];
      #pragma unroll
      for (int fn = 0; fn < 4; fn++){
        f16x8 vh = *(const f16x8*)&Vthi[fn*16 + lr][c2*32 + lg*8];
        f16x8 vl = *(const f16x8*)&Vtlo[fn*16 + lr][c2*32 + lg*8];
        oacc[fn] = MFMA_F16(ph, vh, oacc[fn]);
        oacc[fn] = MFMA_F16(ph, vl, oacc[fn]);
        oacc[fn] = MFMA_F16(pl, vh, oacc[fn]);
      }
    }
    __syncthreads();
  }
  const int bb = bh >> 4, hh = bh & 15;
  #pragma unroll
  for (int fn = 0; fn < 4; fn++)
  #pragma unroll
  for (int r = 0; r < 4; r++){
    float ov = oacc[fn][r] / (32768.0f * lsum[r]);   // 512*64 scale
    int m = qt*64 + wid*16 + lg*4 + r;
    size_t oi = ((size_t)(bb*TN + m))*DN + hh*HSN + fn*16 + lr;
    _Float16 hi, lo; fsplit(ov * 64.0f, hi, lo);
    ohi_[oi] = hi; olo_[oi] = lo;
  }
}

// ---------------- proj GEMM + residual: 128x128, fused 3-product split -----------------
__global__ __launch_bounds__(256) void proj_gemm_kernel(
    const _Float16* __restrict__ ohi, const _Float16* __restrict__ olo,
    const unsigned char* __restrict__ bph, const unsigned char* __restrict__ bpl,
    const float* __restrict__ x, const float* __restrict__ bproj,
    float* __restrict__ out)
{
  const int mb = blockIdx.x;    // 0..63
  const int nb = blockIdx.y;    // 0..7
  __shared__ __align__(16) unsigned char Ah[16384], Al[16384], Bh[16384], Bl[16384];
  const int t = threadIdx.x, w = t >> 6, lane = t & 63, lg = lane >> 4, lr = lane & 15;
  const int wr = w >> 1, wc = w & 1;
  f32x4 acc[4][4] = {};
  const unsigned char* sbB = ((w == 2) ? bph : bpl) + ((size_t)(nb*16))*16384 + lane*16;
  unsigned char* dpB = (w == 2) ? Bh : Bl;
  const _Float16* aSrc = (w == 0) ? ohi : olo;
  unsigned char* dpA = (w == 0) ? Ah : Al;
  const int rA = lane >> 3;          // + j*8
  const int cA = lane & 7;
  for (int kt = 0; kt < 16; kt++){
    if (w < 2){
      #pragma unroll
      for (int j = 0; j < 16; j++){
        int r = rA + j*8;
        const unsigned char* s2 = (const unsigned char*)(aSrc + (size_t)(mb*128 + r)*DN)
                                  + kt*128 + ((cA ^ (r & 7)) << 4);
        gload16(s2, dpA + j*1024);
      }
    } else {
      const unsigned char* s2 = sbB + (size_t)kt*16384;
      #pragma unroll
      for (int j = 0; j < 16; j++) gload16(s2 + j*1024, dpB + j*1024);
    }
    __syncthreads();
    #pragma unroll
    for (int ks = 0; ks < 2; ks++){
      f16x8 ah[4], al[4], bh[4], bl[4];
      #pragma unroll
      for (int f = 0; f < 4; f++){
        int ra = wr*64 + f*16 + lr;
        int off = (ks*64 + lg*16) ^ ((ra & 7) << 4);
        ah[f] = *(const f16x8*)(Ah + ra*128 + off);
        al[f] = *(const f16x8*)(Al + ra*128 + off);
      }
      #pragma unroll
      for (int f = 0; f < 4; f++){
        int rb = wc*64 + f*16 + lr;
        int off = (ks*64 + lg*16) ^ ((rb & 7) << 4);
        bh[f] = *(const f16x8*)(Bh + rb*128 + off);
        bl[f] = *(const f16x8*)(Bl + rb*128 + off);
      }
      #pragma unroll
      for (int fm = 0; fm < 4; fm++)
      #pragma unroll
      for (int fn = 0; fn < 4; fn++){
        acc[fm][fn] = MFMA_F16(ah[fm], bh[fn], acc[fm][fn]);
        acc[fm][fn] = MFMA_F16(al[fm], bh[fn], acc[fm][fn]);
        acc[fm][fn] = MFMA_F16(ah[fm], bl[fn], acc[fm][fn]);
      }
    }
    __syncthreads();
  }
  #pragma unroll
  for (int fm = 0; fm < 4; fm++)
  #pragma unroll
  for (int fn = 0; fn < 4; fn++)
  #pragma unroll
  for (int rr = 0; rr < 4; rr++){
    int m = mb*128 + wr*64 + fm*16 + lg*4 + rr;
    int n = nb*128 + wc*64 + fn*16 + lr;
    size_t oi = (size_t)m*DN + n;
    out[oi] = x[oi] + acc[fm][fn][rr] * (1.0f/65536.0f) + bproj[n];
  }
}

// ---------------- router: LN2 (fp32) + logits + noisy top-2 + h2(bf16) ----------------
__global__ __launch_bounds__(256) void router_kernel(
    const float* __restrict__ x1, const float* __restrict__ g, const float* __restrict__ be,
    const float* __restrict__ Wr, const float* __restrict__ br,
    const float* __restrict__ Wn, const float* __restrict__ bn,
    const float* __restrict__ noise, unsigned short* __restrict__ h2bf,
    int* __restrict__ topk_e, float* __restrict__ topk_g, int* __restrict__ counts)
{
  const int token = blockIdx.x;
  const int t = threadIdx.x;
  __shared__ float redsum[4];
  __shared__ float red[64];
  float4 v = ((const float4*)(x1 + (size_t)token * DN))[t];
  float s = v.x + v.y + v.z + v.w;
  #pragma unroll
  for (int m = 32; m >= 1; m >>= 1) s += __shfl_xor(s, m);
  if ((t & 63) == 0) redsum[t >> 6] = s;
  __syncthreads();
  const float mu = (redsum[0] + redsum[1] + redsum[2] + redsum[3]) * (1.0f / DN);
  const float d0 = v.x - mu, d1 = v.y - mu, d2 = v.z - mu, d3 = v.w - mu;
  float s2 = d0*d0 + d1*d1 + d2*d2 + d3*d3;
  #pragma unroll
  for (int m = 32; m >= 1; m >>= 1) s2 += __shfl_xor(s2, m);
  __syncthreads();
  if ((t & 63) == 0) redsum[t >> 6] = s2;
  __syncthreads();
  const float var = (redsum[0] + redsum[1] + redsum[2] + redsum[3]) * (1.0f / DN);
  const float rs = 1.0f / sqrtf(var + 1e-5f);
  float4 gv = ((const float4*)g)[t];
  float4 bv = ((const float4*)be)[t];
  float h0 = d0*rs*gv.x + bv.x, h1v = d1*rs*gv.y + bv.y, h2v = d2*rs*gv.z + bv.z, h3 = d3*rs*gv.w + bv.w;
  ushort4 hb;
  hb.x = f2bf(h0); hb.y = f2bf(h1v); hb.z = f2bf(h2v); hb.w = f2bf(h3);
  *(ushort4*)(h2bf + (size_t)token*DN + t*4) = hb;
  float acc[16];
  const int j = t * 4;
  #pragma unroll
  for (int e = 0; e < 8; e++){
    acc[e]     = h0*Wr[(j+0)*8+e] + h1v*Wr[(j+1)*8+e] + h2v*Wr[(j+2)*8+e] + h3*Wr[(j+3)*8+e];
    acc[8 + e] = h0*Wn[(j+0)*8+e] + h1v*Wn[(j+1)*8+e] + h2v*Wn[(j+2)*8+e] + h3*Wn[(j+3)*8+e];
  }
  #pragma unroll
  for (int q = 0; q < 16; q++){
    #pragma unroll
    for (int m = 32; m >= 1; m >>= 1) acc[q] += __shfl_xor(acc[q], m);
  }
  if ((t & 63) == 0){
    #pragma unroll
    for (int q = 0; q < 16; q++) red[(t >> 6)*16 + q] = acc[q];
  }
  __syncthreads();
  if (t < 16) red[t] = red[t] + red[16 + t] + red[32 + t] + red[48 + t];
  __syncthreads();
  if (t == 0){
    float nz[8];
    #pragma unroll
    for (int e = 0; e < 8; e++){
      float logit = red[e] + br[e];
      float a = red[8 + e] + bn[e];
      float sp = (a > 20.0f) ? a : log1pf(expf(a));
      nz[e] = logit + noise[(size_t)token*EN + e] * sp;
    }
    float v1 = -INFINITY, v2 = -INFINITY; int i1 = 0, i2 = 0;
    #pragma unroll
    for (int e = 0; e < 8; e++){
      float z = nz[e];
      if (z > v1){ v2 = v1; i2 = i1; v1 = z; i1 = e; }
      else if (z > v2){ v2 = z; i2 = e; }
    }
    float e2 = expf(v2 - v1);
    float den = 1.0f + e2;
    topk_e[token*2]     = i1; topk_e[token*2 + 1] = i2;
    topk_g[token*2]     = 1.0f/den; topk_g[token*2 + 1] = e2/den;
    atomicAdd(&counts[i1], 1); atomicAdd(&counts[i2], 1);
  }
}

// 256-aligned expert segment offsets (moe tiles are 256 rows)
__global__ void scan_kernel(const int* __restrict__ counts, int* __restrict__ offs)
{
  if (threadIdx.x == 0 && blockIdx.x == 0){
    int a = 0;
    for (int e = 0; e < EN; e++){ offs[e] = a; a += (counts[e] + 255) & ~255; }
  }
}

__global__ __launch_bounds__(256) void scatter_kernel(
    const int* __restrict__ topk_e, const float* __restrict__ topk_g,
    const int* __restrict__ offs, int* __restrict__ fill,
    int* __restrict__ rows, float* __restrict__ grow)
{
  const int token = blockIdx.x*256 + threadIdx.x;
  #pragma unroll
  for (int i = 0; i < 2; i++){
    int e = topk_e[token*2 + i];
    int pos = offs[e] + atomicAdd(&fill[e], 1);
    rows[pos] = token;
    grow[pos] = topk_g[token*2 + i];
  }
}

// ---------------- expert weights -> 16KB LDS-image panels (bf16, swizzle baked) --------
__global__ __launch_bounds__(256) void wconv_kernel(
    const float* __restrict__ W1, const float* __restrict__ W2,
    unsigned char* __restrict__ w1p, unsigned char* __restrict__ w2p)
{
  int b = blockIdx.x;
  const float* W; unsigned char* pan; int Nd, kt, n;
  if (b < 2048){
    int e = b >> 8, rem = b & 255, nb2 = rem >> 4; kt = rem & 15;
    n = nb2*256 + threadIdx.x;                       // 0..4095
    W = W1 + (size_t)e * DN * DFN; Nd = DFN;
    pan = w1p + (((size_t)e*32 + (n >> 7))*16 + kt) * 16384;
  } else {
    b -= 2048;
    int e = b >> 8, rem = b & 255, nb2 = rem >> 6; kt = rem & 63;
    n = nb2*256 + threadIdx.x;                       // 0..1023
    W = W2 + (size_t)e * DFN * DN; Nd = DN;
    pan = w2p + (((size_t)e*8 + (n >> 7))*64 + kt) * 16384;
  }
  const int r = n & 127;
  #pragma unroll
  for (int kk8 = 0; kk8 < 8; kk8++){
    union { unsigned short u[8]; uint4 v; } buf;
    #pragma unroll
    for (int j = 0; j < 8; j++)
      buf.u[j] = f2bf(W[(size_t)(kt*64 + kk8*8 + j)*Nd + n]);
    *(uint4*)(pan + r*128 + ((kk8 ^ (r & 7)) << 4)) = buf.v;
  }
}

// ---------------- gather tokens into A panels: apnl[pb][kt16][16KB image] ----------------
__global__ __launch_bounds__(256) void agather_kernel(
    const unsigned short* __restrict__ h2bf, const int* __restrict__ rows,
    unsigned char* __restrict__ apnl)
{
  const int pb = blockIdx.x, kt = blockIdx.y;
  const int t = threadIdx.x;
  const int r = t >> 1, c0 = (t & 1) * 4;
  const int tok = rows[pb*128 + r];
  const unsigned char* src = (const unsigned char*)h2bf + (size_t)tok*2048 + kt*128;
  unsigned char* dst = apnl + ((size_t)pb*16 + kt)*16384 + r*128;
  #pragma unroll
  for (int i = 0; i < 4; i++){
    int c = c0 + i;
    *(uint4*)(dst + ((c ^ (r & 7)) << 4)) = *(const uint4*)(src + c*16);
  }
}

// ---------------- MoE GEMM1 (persistent, 2D-window, single-barrier loop, no setprio) ---
__global__ __launch_bounds__(512, 1) void moe1_kernel(
    const unsigned char* __restrict__ apnl, const unsigned char* __restrict__ w1p,
    const float* __restrict__ b1,
    const int* __restrict__ counts, const int* __restrict__ offs,
    unsigned short* __restrict__ midP)
{
  __shared__ __align__(16) unsigned char As[2][32768], Bs[2][32768];
  const int bid = blockIdx.x;
  const int t = threadIdx.x;
  const int w = t >> 6, lane = t & 63, lg = lane >> 4, lr = lane & 15;
  const int wm = w >> 2, wn = w & 3;
  const int sp = (w >> 1) & 1, sh = (w & 1) * 8192;
  const int e  = bid & 7;
  const int c  = bid >> 3;                 // CU slot within XCD, 0..31
  const int cnt = counts[e];
  const int off = offs[e];
  const int nmb = (cnt + 255) >> 8;
  const int nch = nmb * 16;
  for (int q = c; q < nch; q += 32){
    const int grp = q / (4*nmb);
    const int within = q - grp*4*nmb;
    const int mb = within >> 2;
    const int nb = grp*4 + (within & 3);   // 0..15 (256-col group)
    const int m0 = mb * 256;
    const int pb0 = (off + m0) >> 7;
    const unsigned char* sbase;
    unsigned char* dbase;
    if (w < 4){
      sbase = apnl + ((size_t)(pb0 + sp) * 16) * 16384 + sh + lane*16;
      dbase = &As[0][sp*16384 + sh];
    } else {
      sbase = w1p + ((size_t)(e*32 + nb*2 + sp) * 16) * 16384 + sh + lane*16;
      dbase = &Bs[0][sp*16384 + sh];
    }
    f32x4 acc[8][4] = {};
    auto stage = [&](int buf, int kt){
      const unsigned char* s2 = sbase + (size_t)kt * 16384;
      unsigned char* d = dbase + buf * 32768;
      #pragma unroll
      for (int j = 0; j < 8; j++) gload16(s2 + j*1024, d + j*1024);
    };
    auto compute = [&](int buf){
      const unsigned char* pA = &As[buf][wm*16384];
      const unsigned char* pB = &Bs[buf][(wn>>1)*16384];
      #pragma unroll
      for (int ks = 0; ks < 2; ks++){
        s16x8 b[4], a[8];
        #pragma unroll
        for (int f = 0; f < 4; f++){
          int rb = (wn&1)*64 + f*16 + lr;
          b[f] = *(const s16x8*)(pB + rb*128 + ((ks*64 + lg*16) ^ ((rb&7)<<4)));
        }
        #pragma unroll
        for (int f = 0; f < 8; f++){
          int ra = f*16 + lr;
          a[f] = *(const s16x8*)(pA + ra*128 + ((ks*64 + lg*16) ^ ((ra&7)<<4)));
        }
        #pragma unroll
        for (int fm = 0; fm < 8; fm++)
        #pragma unroll
        for (int fn = 0; fn < 4; fn++)
          acc[fm][fn] = MFMA_BF16(a[fm], b[fn], acc[fm][fn]);
      }
    };
    // T3-minimum single-barrier loop: stage(next) -> compute(cur) -> vmcnt(0)+barrier
    stage(0, 0);
    VMW_BAR(0);
    for (int kt = 0; kt < 16; kt += 2){
      stage(1, kt + 1);
      compute(0);
      VMW_BAR(0);
      if (kt + 2 < 16) stage(0, kt + 2);
      compute(1);
      VMW_BAR(0);
    }
    {
      unsigned char* Lp = ((wm == 0) ? (unsigned char*)As : (unsigned char*)Bs) + wn*16384;
      const float* b1e = b1 + (size_t)e*DFN + nb*256 + wn*64;
      #pragma unroll
      for (int fn = 0; fn < 4; fn++){
        float bias = b1e[fn*16 + lr];
        int col = fn*16 + lr;
        #pragma unroll
        for (int fm = 0; fm < 8; fm++)
        #pragma unroll
        for (int rr = 0; rr < 4; rr++){
          int r = fm*16 + lg*4 + rr;
          float v = fmaxf(acc[fm][fn][rr] + bias, 0.0f);
          *(unsigned short*)(Lp + r*128 + ((col ^ ((r & 7) << 3)) * 2)) = f2bf(v);
        }
      }
    }
    BAR();
    {
      int p = w >> 2, jj = w & 3;
      const uint4* src = (const uint4*)(((p == 0) ? (unsigned char*)As : (unsigned char*)Bs) + jj*16384);
      uint4* dst = (uint4*)((unsigned char*)midP + (((size_t)(pb0 + p)*64) + nb*4 + jj) * 16384);
      #pragma unroll
      for (int i = 0; i < 16; i++) dst[lane + i*64] = src[lane + i*64];
    }
    BAR();
  }
}

// ---------------- MoE GEMM2 (persistent, 2D-window, single-barrier loop, no setprio) ---
__global__ __launch_bounds__(512, 1) void moe2_kernel(
    const unsigned char* __restrict__ midP, const unsigned char* __restrict__ w2p,
    const float* __restrict__ b2,
    const int* __restrict__ counts, const int* __restrict__ offs,
    const int* __restrict__ rows, const float* __restrict__ grow,
    float* __restrict__ out)
{
  __shared__ __align__(16) unsigned char As[2][32768], Bs[2][32768];
  const int bid = blockIdx.x;
  const int t = threadIdx.x;
  const int w = t >> 6, lane = t & 63, lg = lane >> 4, lr = lane & 15;
  const int wm = w >> 2, wn = w & 3;
  const int sp = (w >> 1) & 1, sh = (w & 1) * 8192;
  const int e  = bid & 7;
  const int c  = bid >> 3;
  const int cnt = counts[e];
  const int off = offs[e];
  const int nmb = (cnt + 255) >> 8;
  const int nch = nmb * 4;
  for (int q = c; q < nch; q += 32){
    const int mb = q >> 2;
    const int nb = q & 3;
    const int m0 = mb * 256;
    const int pb0 = (off + m0) >> 7;
    const unsigned char* sbase;
    unsigned char* dbase;
    if (w < 4){
      sbase = midP + ((size_t)(pb0 + sp) * 64) * 16384 + sh + lane*16;
      dbase = &As[0][sp*16384 + sh];
    } else {
      sbase = w2p + ((size_t)(e*8 + nb*2 + sp) * 64) * 16384 + sh + lane*16;
      dbase = &Bs[0][sp*16384 + sh];
    }
    f32x4 acc[8][4] = {};
    auto stage = [&](int buf, int kt){
      const unsigned char* s2 = sbase + (size_t)kt * 16384;
      unsigned char* d = dbase + buf * 32768;
      #pragma unroll
      for (int j = 0; j < 8; j++) gload16(s2 + j*1024, d + j*1024);
    };
    auto compute = [&](int buf){
      const unsigned char* pA = &As[buf][wm*16384];
      const unsigned char* pB = &Bs[buf][(wn>>1)*16384];
      #pragma unroll
      for (int ks = 0; ks < 2; ks++){
        s16x8 b[4], a[8];
        #pragma unroll
        for (int f = 0; f < 4; f++){
          int rb = (wn&1)*64 + f*16 + lr;
          b[f] = *(const s16x8*)(pB + rb*128 + ((ks*64 + lg*16) ^ ((rb&7)<<4)));
        }
        #pragma unroll
        for (int f = 0; f < 8; f++){
          int ra = f*16 + lr;
          a[f] = *(const s16x8*)(pA + ra*128 + ((ks*64 + lg*16) ^ ((ra&7)<<4)));
        }
        #pragma unroll
        for (int fm = 0; fm < 8; fm++)
        #pragma unroll
        for (int fn = 0; fn < 4; fn++)
          acc[fm][fn] = MFMA_BF16(a[fm], b[fn], acc[fm][fn]);
      }
    };
    // T3-minimum single-barrier loop
    stage(0, 0);
    VMW_BAR(0);
    for (int kt = 0; kt < 64; kt += 2){
      stage(1, kt + 1);
      compute(0);
      VMW_BAR(0);
      if (kt + 2 < 64) stage(0, kt + 2);
      compute(1);
      VMW_BAR(0);
    }
    const float* b2e = b2 + (size_t)e*DN + nb*256 + wn*64;
    #pragma unroll
    for (int fm = 0; fm < 8; fm++)
    #pragma unroll
    for (int rr = 0; rr < 4; rr++){
      int ml = wm*128 + fm*16 + lg*4 + rr;
      if (m0 + ml < cnt){
        int gi = off + m0 + ml;
        int tok = rows[gi];
        float gt = grow[gi];
        #pragma unroll
        for (int fn = 0; fn < 4; fn++){
          int n = nb*256 + wn*64 + fn*16 + lr;
          atomicAdd(out + (size_t)tok*DN + n, gt*(acc[fm][fn][rr] + b2e[fn*16 + lr]));
        }
      }
    }
  }
}

// ---------------- launch ----------------
extern "C" void kernel_launch(void* const* d_in, const int* in_sizes, int n_in,
                              void* d_out, int out_size, void* d_ws, size_t ws_size,
                              hipStream_t stream) {
  (void)in_sizes; (void)n_in; (void)out_size; (void)ws_size;
  const float* x     = (const float*)d_in[0];
  const float* noise = (const float*)d_in[1];
  const float* Wq    = (const float*)d_in[2];
  const float* Wk    = (const float*)d_in[3];
  const float* Wv    = (const float*)d_in[4];
  const float* Wp    = (const float*)d_in[5];
  const float* bproj = (const float*)d_in[6];
  const float* ln1g  = (const float*)d_in[7];
  const float* ln1b  = (const float*)d_in[8];
  const float* ln2g  = (const float*)d_in[9];
  const float* ln2b  = (const float*)d_in[10];
  const float* Wr    = (const float*)d_in[11];
  const float* br    = (const float*)d_in[12];
  const float* Wn    = (const float*)d_in[13];
  const float* bn    = (const float*)d_in[14];
  const float* W1    = (const float*)d_in[15];
  const float* b1    = (const float*)d_in[16];
  const float* W2    = (const float*)d_in[17];
  const float* b2    = (const float*)d_in[18];
  float* out = (float*)d_out;

  char* w = (char*)d_ws;
  auto alloc = [&](size_t bytes) -> char* {
    char* p = w; w += (bytes + 255) & ~(size_t)255; return p;
  };
  // Region A: qkv split + o split during attention; reused as panelized `mid` during MoE.
  char* big = alloc((size_t)NPB * 64 * 16384);          // 151 MB >= 134.2 MB qkv need
  _Float16* qkvsplit = (_Float16*)big;
  _Float16* ohi = (_Float16*)(big + (size_t)6*NQ*2);
  _Float16* olo = ohi + NQ;
  unsigned short* midP = (unsigned short*)big;
  // Region B: attention temporaries (dead after proj); W1 panels overlay them afterwards.
  char* attn_tmp = w;
  unsigned char* aph = (unsigned char*)alloc((size_t)64*16*16384);   // h1 hi panels 16 MB
  unsigned char* apl = (unsigned char*)alloc((size_t)64*16*16384);   // h1 lo panels 16 MB
  unsigned char* bqh = (unsigned char*)alloc((size_t)24*16*16384);   // qkv W hi panels 6.3 MB
  unsigned char* bql = (unsigned char*)alloc((size_t)24*16*16384);
  unsigned char* bph = (unsigned char*)alloc((size_t)8*16*16384);    // proj W hi panels 2.1 MB
  unsigned char* bpl = (unsigned char*)alloc((size_t)8*16*16384);
  unsigned char* w1p = (unsigned char*)attn_tmp;        // 64 MiB panels overlay
  char* w1p_end = attn_tmp + (size_t)EN*DFN*DN*2;
  if (w < w1p_end) w = w1p_end;
  unsigned char* w2p = (unsigned char*)alloc((size_t)EN*DN*DFN*2);   // 64 MiB
  unsigned char* apnl = (unsigned char*)alloc((size_t)NPB*16*16384); // 37.7 MB
  unsigned short* h2bf = (unsigned short*)alloc((size_t)NTOK*DN*2);
  int*   topk_e = (int*)alloc(NTOK*2*sizeof(int));
  float* topk_g = (float*)alloc(NTOK*2*sizeof(float));
  int*   rowsA  = (int*)alloc((size_t)NPB*128*sizeof(int));
  float* growA  = (float*)alloc((size_t)NPB*128*sizeof(float));
  int*   cnts   = (int*)alloc(256);
  int*   fill   = cnts + 8;
  int*   offs   = cnts + 16;

  (void)hipMemsetAsync(cnts, 0, 64, stream);                  // counts + fill
  (void)hipMemsetAsync(rowsA, 0, (size_t)NPB*128*sizeof(int), stream);
  ln1_kernel<<<NTOK, 128, 0, stream>>>(x, ln1g, ln1b, aph, apl);
  wsplit_kernel<<<512, 256, 0, stream>>>(Wq, Wk, Wv, Wp, bqh, bql, bph, bpl);
  qkv_gemm_kernel<<<dim3(64, 24), 256, 0, stream>>>(aph, apl, bqh, bql, qkvsplit);
  attn_kernel<<<dim3(16, 128), 256, 0, stream>>>(qkvsplit, ohi, olo);
  proj_gemm_kernel<<<dim3(64, 8), 256, 0, stream>>>(ohi, olo, bph, bpl, x, bproj, out);
  // attn temporaries now dead -> overlay weight panels
  wconv_kernel<<<4096, 256, 0, stream>>>(W1, W2, w1p, w2p);
  router_kernel<<<NTOK, 256, 0, stream>>>(out, ln2g, ln2b, Wr, br, Wn, bn, noise,
                                          h2bf, topk_e, topk_g, cnts);
  scan_kernel<<<1, 64, 0, stream>>>(cnts, offs);
  scatter_kernel<<<NTOK/256, 256, 0, stream>>>(topk_e, topk_g, offs, fill, rowsA, growA);
  agather_kernel<<<dim3(NPB, 16), 256, 0, stream>>>(h2bf, rowsA, apnl);
  moe1_kernel<<<256, 512, 0, stream>>>(apnl, w1p, b1, cnts, offs, midP);
  moe2_kernel<<<256, 512, 0, stream>>>((const unsigned char*)midP, w2p, b2,
                                       cnts, offs, rowsA, growA, out);
}

// Round 20
// 1435.754 us; speedup vs baseline: 1.1367x; 1.0042x over previous
//
#include <hip/hip_runtime.h>
#include <hip/hip_bf16.h>
#include <math.h>

#define NTOK 8192
#define DN   1024
#define HN   16
#define HSN  64
#define EN   8
#define DFN  4096
#define TN   1024
#define NQ   8388608u   // B*T*D elements per q/k/v buffer
#define NPB  144        // max 128-row panels (16384 + 8*255 pad, 256-aligned segments)

typedef _Float16 f16x8 __attribute__((ext_vector_type(8)));
typedef _Float16 f16x4 __attribute__((ext_vector_type(4)));
typedef float    f32x4 __attribute__((ext_vector_type(4)));
typedef short    s16x8 __attribute__((ext_vector_type(8)));
typedef unsigned int u32x4 __attribute__((ext_vector_type(4)));

#define MFMA_F16(A,B,C)  __builtin_amdgcn_mfma_f32_16x16x32_f16((A),(B),(C),0,0,0)
#define MFMA_BF16(A,B,C) __builtin_amdgcn_mfma_f32_16x16x32_bf16((A),(B),(C),0,0,0)

__device__ __forceinline__ unsigned short f2bf(float f){
  union { float f; unsigned u; } v; v.f = f;
  unsigned r = v.u + 0x7fffu + ((v.u >> 16) & 1u);
  return (unsigned short)(r >> 16);
}
__device__ __forceinline__ void fsplit(float v, _Float16& hi, _Float16& lo){
  hi = (_Float16)v; lo = (_Float16)(v - (float)hi);
}
// async global->LDS, 16B per lane; LDS dest is wave-uniform base (+lane*16 implicit)
__device__ __forceinline__ void gload16(const void* g, void* l){
  __builtin_amdgcn_global_load_lds((const __attribute__((address_space(1))) unsigned int*)g,
                                   (__attribute__((address_space(3))) unsigned int*)l, 16, 0, 0);
}
#define BAR() __builtin_amdgcn_s_barrier()
#define VMW_BAR(N) do { \
  asm volatile("s_waitcnt vmcnt(" #N ")" ::: "memory"); \
  __builtin_amdgcn_s_barrier(); \
} while (0)

// ---------------- LN1: x -> h1 panel images (x64, hi/lo) ----------------
__global__ __launch_bounds__(128) void ln1_kernel(
    const float* __restrict__ x, const float* __restrict__ g, const float* __restrict__ be,
    unsigned char* __restrict__ aph, unsigned char* __restrict__ apl)
{
  const int row = blockIdx.x;
  const int t = threadIdx.x;             // 0..127, handles 8 cols
  __shared__ float red[2];
  float4 va = ((const float4*)(x + (size_t)row*DN))[t*2];
  float4 vb = ((const float4*)(x + (size_t)row*DN))[t*2+1];
  float s = va.x+va.y+va.z+va.w + vb.x+vb.y+vb.z+vb.w;
  #pragma unroll
  for (int m = 32; m >= 1; m >>= 1) s += __shfl_xor(s, m);
  if ((t & 63) == 0) red[t >> 6] = s;
  __syncthreads();
  const float mu = (red[0] + red[1]) * (1.0f / DN);
  float e[8] = { va.x-mu, va.y-mu, va.z-mu, va.w-mu, vb.x-mu, vb.y-mu, vb.z-mu, vb.w-mu };
  float s2 = 0.0f;
  #pragma unroll
  for (int i = 0; i < 8; i++) s2 += e[i]*e[i];
  #pragma unroll
  for (int m = 32; m >= 1; m >>= 1) s2 += __shfl_xor(s2, m);
  __syncthreads();
  if ((t & 63) == 0) red[t >> 6] = s2;
  __syncthreads();
  const float var = (red[0] + red[1]) * (1.0f / DN);
  const float rs = 1.0f / sqrtf(var + 1e-5f);
  float4 ga = ((const float4*)g)[t*2], gb = ((const float4*)g)[t*2+1];
  float4 ba = ((const float4*)be)[t*2], bb = ((const float4*)be)[t*2+1];
  float gg[8] = { ga.x,ga.y,ga.z,ga.w, gb.x,gb.y,gb.z,gb.w };
  float bbv[8] = { ba.x,ba.y,ba.z,ba.w, bb.x,bb.y,bb.z,bb.w };
  f16x8 hi8, lo8;
  #pragma unroll
  for (int i = 0; i < 8; i++){
    _Float16 hi, lo; fsplit((e[i]*rs*gg[i] + bbv[i]) * 64.0f, hi, lo);
    hi8[i] = hi; lo8[i] = lo;
  }
  const int pb = row >> 7, r = row & 127, kt = t >> 3, kk8 = t & 7;
  size_t po = ((size_t)(pb*16 + kt))*16384 + r*128 + (size_t)((kk8 ^ (r & 7)) << 4);
  *(f16x8*)(aph + po) = hi8;
  *(f16x8*)(apl + po) = lo8;
}

// ---------------- attention weights -> B panel images (x1024, hi/lo) ----------------
__global__ __launch_bounds__(256) void wsplit_kernel(
    const float* __restrict__ Wq, const float* __restrict__ Wk, const float* __restrict__ Wv,
    const float* __restrict__ Wp,
    unsigned char* __restrict__ bqh, unsigned char* __restrict__ bql,
    unsigned char* __restrict__ bph, unsigned char* __restrict__ bpl)
{
  int b = blockIdx.x;
  const int t = threadIdx.x;
  const int r = t & 127;
  const int c0 = (t >> 7) * 4;     // physical slots c0..c0+3
  if (b < 384){
    int nb = b >> 4, kt = b & 15;
    int n = nb*128 + r;
    int mat = n >> 10, h = (n >> 6) & 15, hs = n & 63;
    const float* W = (mat == 0) ? Wq : ((mat == 1) ? Wk : Wv);
    const float* src = W + (size_t)h*65536 + hs;     // + k*64
    unsigned char* ph = bqh + ((size_t)(nb*16 + kt))*16384 + r*128;
    unsigned char* pl = bql + ((size_t)(nb*16 + kt))*16384 + r*128;
    #pragma unroll
    for (int c = c0; c < c0 + 4; c++){
      int kk8 = c ^ (r & 7);
      f16x8 hi8, lo8;
      #pragma unroll
      for (int j = 0; j < 8; j++){
        _Float16 hi, lo; fsplit(src[(size_t)(kt*64 + kk8*8 + j)*64] * 1024.0f, hi, lo);
        hi8[j] = hi; lo8[j] = lo;
      }
      *(f16x8*)(ph + c*16) = hi8;
      *(f16x8*)(pl + c*16) = lo8;
    }
  } else {
    b -= 384;
    int nb = b >> 4, kt = b & 15;
    int n = nb*128 + r;
    unsigned char* ph = bph + ((size_t)(nb*16 + kt))*16384 + r*128;
    unsigned char* pl = bpl + ((size_t)(nb*16 + kt))*16384 + r*128;
    #pragma unroll
    for (int c = c0; c < c0 + 4; c++){
      int kk8 = c ^ (r & 7);
      f16x8 hi8, lo8;
      #pragma unroll
      for (int j = 0; j < 8; j++){
        _Float16 hi, lo; fsplit(Wp[(size_t)(kt*64 + kk8*8 + j)*DN + n] * 1024.0f, hi, lo);
        hi8[j] = hi; lo8[j] = lo;
      }
      *(f16x8*)(ph + c*16) = hi8;
      *(f16x8*)(pl + c*16) = lo8;
    }
  }
}

// ---------------- QKV GEMM: 128x128, fused 3-product split (one K pass) ----------------
// V (mat==2) is written TRANSPOSED: [b,h,hs,t] so attention can stage V^T vectorized.
__global__ __launch_bounds__(256) void qkv_gemm_kernel(
    const unsigned char* __restrict__ aph, const unsigned char* __restrict__ apl,
    const unsigned char* __restrict__ bqh, const unsigned char* __restrict__ bql,
    _Float16* __restrict__ qkvout)
{
  const int mb = blockIdx.x;    // 0..63
  const int nb = blockIdx.y;    // 0..23
  __shared__ __align__(16) unsigned char Ah[16384], Al[16384], Bh[16384], Bl[16384];
  const int t = threadIdx.x, w = t >> 6, lane = t & 63, lg = lane >> 4, lr = lane & 15;
  const int wr = w >> 1, wc = w & 1;
  const unsigned char* sb;
  unsigned char* dp;
  if (w == 0){ sb = aph + ((size_t)(mb*16))*16384; dp = Ah; }
  else if (w == 1){ sb = apl + ((size_t)(mb*16))*16384; dp = Al; }
  else if (w == 2){ sb = bqh + ((size_t)(nb*16))*16384; dp = Bh; }
  else { sb = bql + ((size_t)(nb*16))*16384; dp = Bl; }
  sb += lane*16;
  f32x4 acc[4][4] = {};
  for (int kt = 0; kt < 16; kt++){
    const unsigned char* s2 = sb + (size_t)kt*16384;
    #pragma unroll
    for (int j = 0; j < 16; j++) gload16(s2 + j*1024, dp + j*1024);
    __syncthreads();
    #pragma unroll
    for (int ks = 0; ks < 2; ks++){
      f16x8 ah[4], al[4], bh[4], bl[4];
      #pragma unroll
      for (int f = 0; f < 4; f++){
        int ra = wr*64 + f*16 + lr;
        int off = (ks*64 + lg*16) ^ ((ra & 7) << 4);
        ah[f] = *(const f16x8*)(Ah + ra*128 + off);
        al[f] = *(const f16x8*)(Al + ra*128 + off);
      }
      #pragma unroll
      for (int f = 0; f < 4; f++){
        int rb = wc*64 + f*16 + lr;
        int off = (ks*64 + lg*16) ^ ((rb & 7) << 4);
        bh[f] = *(const f16x8*)(Bh + rb*128 + off);
        bl[f] = *(const f16x8*)(Bl + rb*128 + off);
      }
      #pragma unroll
      for (int fm = 0; fm < 4; fm++)
      #pragma unroll
      for (int fn = 0; fn < 4; fn++){
        acc[fm][fn] = MFMA_F16(ah[fm], bh[fn], acc[fm][fn]);
        acc[fm][fn] = MFMA_F16(al[fm], bh[fn], acc[fm][fn]);
        acc[fm][fn] = MFMA_F16(ah[fm], bl[fn], acc[fm][fn]);
      }
    }
    __syncthreads();
  }
  #pragma unroll
  for (int fm = 0; fm < 4; fm++)
  #pragma unroll
  for (int fn = 0; fn < 4; fn++)
  #pragma unroll
  for (int rr = 0; rr < 4; rr++){
    int m = mb*128 + wr*64 + fm*16 + lg*4 + rr;
    int n = nb*128 + wc*64 + fn*16 + lr;
    int mat = n >> 10, h = (n >> 6) & 15, hs = n & 63;
    int bb = m >> 10, tt = m & 1023;
    _Float16* dsthi = qkvout + (size_t)mat * 2u * NQ;
    _Float16* dstlo = dsthi + NQ;
    size_t oi;
    if (mat == 2)  // V transposed: [b][h][hs][t]
      oi = (((size_t)(bb*HN + h))*HSN + hs)*TN + tt;
    else
      oi = (((size_t)(bb*HN + h))*TN + tt)*HSN + hs;
    _Float16 hi, lo; fsplit(acc[fm][fn][rr] * (1.0f/1024.0f), hi, lo);  // = 64*q
    dsthi[oi] = hi; dstlo[oi] = lo;
  }
}

// ---------------- flash attention (split f16, V^T input) ----------------
__global__ __launch_bounds__(256) void attn_kernel(
    const _Float16* __restrict__ qkv,
    _Float16* __restrict__ ohi_, _Float16* __restrict__ olo_)
{
  const _Float16* qhi = qkv;
  const _Float16* qlo = qkv + NQ;
  const _Float16* khi = qkv + 2u*NQ;
  const _Float16* klo = qkv + 3u*NQ;
  const _Float16* vhi = qkv + 4u*NQ;   // layout [b,h,hs,t]
  const _Float16* vlo = qkv + 5u*NQ;
  const int qt = blockIdx.x;     // 0..15
  const int bh = blockIdx.y;     // 0..127
  const size_t base = (size_t)bh * TN * HSN;   // same element count for V^T
  const int t = threadIdx.x, wid = t >> 6, lane = t & 63, lg = lane >> 4, lr = lane & 15;
  __shared__ _Float16 Khi[64][72], Klo[64][72], Vthi[64][72], Vtlo[64][72], Phi[64][72], Plo[64][72];
  f16x8 qh[2], ql[2];
  {
    const int qrow = qt*64 + wid*16 + lr;
    const _Float16* qp  = qhi + base + (size_t)qrow*HSN;
    const _Float16* qpl = qlo + base + (size_t)qrow*HSN;
    #pragma unroll
    for (int c = 0; c < 2; c++){
      qh[c] = *(const f16x8*)(qp  + c*32 + lg*8);
      ql[c] = *(const f16x8*)(qpl + c*32 + lg*8);
    }
  }
  f32x4 oacc[4] = {};
  float mrow[4], lsum[4];
  #pragma unroll
  for (int r = 0; r < 4; r++){ mrow[r] = -INFINITY; lsum[r] = 0.0f; }
  const int sr = t >> 2, sc = (t & 3) * 16;
  const float sscale = 1.0f / (4096.0f * 32.0f);
  for (int kvt = 0; kvt <= qt; kvt++){
    {
      const size_t gr = base + (size_t)(kvt*64 + sr)*HSN + sc;
      *(f16x8*)&Khi[sr][sc]     = *(const f16x8*)(khi + gr);
      *(f16x8*)&Khi[sr][sc + 8] = *(const f16x8*)(khi + gr + 8);
      *(f16x8*)&Klo[sr][sc]     = *(const f16x8*)(klo + gr);
      *(f16x8*)&Klo[sr][sc + 8] = *(const f16x8*)(klo + gr + 8);
      // V^T: row sr = hs, cols = t within tile (vectorized, no transpose)
      const size_t gv = base + (size_t)sr*TN + kvt*64 + sc;
      *(f16x8*)&Vthi[sr][sc]     = *(const f16x8*)(vhi + gv);
      *(f16x8*)&Vthi[sr][sc + 8] = *(const f16x8*)(vhi + gv + 8);
      *(f16x8*)&Vtlo[sr][sc]     = *(const f16x8*)(vlo + gv);
      *(f16x8*)&Vtlo[sr][sc + 8] = *(const f16x8*)(vlo + gv + 8);
    }
    __syncthreads();
    f32x4 sacc[4] = {};
    #pragma unroll
    for (int c = 0; c < 2; c++)
    #pragma unroll
    for (int fn = 0; fn < 4; fn++){
      f16x8 kh = *(const f16x8*)&Khi[fn*16 + lr][c*32 + lg*8];
      f16x8 kl = *(const f16x8*)&Klo[fn*16 + lr][c*32 + lg*8];
      sacc[fn] = MFMA_F16(qh[c], kh, sacc[fn]);
      sacc[fn] = MFMA_F16(qh[c], kl, sacc[fn]);
      sacc[fn] = MFMA_F16(ql[c], kh, sacc[fn]);
    }
    float sv[4][4], pmax[4];
    #pragma unroll
    for (int r = 0; r < 4; r++) pmax[r] = -INFINITY;
    const int qg0 = qt*64 + wid*16 + lg*4;
    #pragma unroll
    for (int fn = 0; fn < 4; fn++)
    #pragma unroll
    for (int r = 0; r < 4; r++){
      float xv = sacc[fn][r] * sscale;
      int kvg = kvt*64 + fn*16 + lr;
      xv = (kvg <= qg0 + r) ? xv : -INFINITY;
      sv[fn][r] = xv;
      pmax[r] = fmaxf(pmax[r], xv);
    }
    #pragma unroll
    for (int r = 0; r < 4; r++){
      #pragma unroll
      for (int m = 1; m < 16; m <<= 1) pmax[r] = fmaxf(pmax[r], __shfl_xor(pmax[r], m));
    }
    float alpha[4], mnew[4], psum[4];
    #pragma unroll
    for (int r = 0; r < 4; r++){
      mnew[r] = fmaxf(mrow[r], pmax[r]);
      alpha[r] = __expf(mrow[r] - mnew[r]);
      psum[r] = 0.0f;
    }
    #pragma unroll
    for (int fn = 0; fn < 4; fn++)
    #pragma unroll
    for (int r = 0; r < 4; r++){
      float p = __expf(sv[fn][r] - mnew[r]);
      psum[r] += p;
      _Float16 hi, lo; fsplit(p * 512.0f, hi, lo);
      Phi[wid*16 + lg*4 + r][fn*16 + lr] = hi;
      Plo[wid*16 + lg*4 + r][fn*16 + lr] = lo;
    }
    #pragma unroll
    for (int r = 0; r < 4; r++){
      #pragma unroll
      for (int m = 1; m < 16; m <<= 1) psum[r] += __shfl_xor(psum[r], m);
      lsum[r] = lsum[r]*alpha[r] + psum[r];
      mrow[r] = mnew[r];
    }
    #pragma unroll
    for (int fn = 0; fn < 4; fn++)
    #pragma unroll
    for (int r = 0; r < 4; r++) oacc[fn][r] *= alpha[r];
    #pragma unroll
    for (int c2 = 0; c2 < 2; c2++){
      f16x8 ph = *(const f16x8*)&Phi[wid*16 + lr][c2*32 + lg*8];
      f16x8 pl = *(const f16x8*)&Plo[wid*16 + lr][c2*32 + lg*8];
      #pragma unroll
      for (int fn = 0; fn < 4; fn++){
        f16x8 vh = *(const f16x8*)&Vthi[fn*16 + lr][c2*32 + lg*8];
        f16x8 vl = *(const f16x8*)&Vtlo[fn*16 + lr][c2*32 + lg*8];
        oacc[fn] = MFMA_F16(ph, vh, oacc[fn]);
        oacc[fn] = MFMA_F16(ph, vl, oacc[fn]);
        oacc[fn] = MFMA_F16(pl, vh, oacc[fn]);
      }
    }
    __syncthreads();
  }
  const int bb = bh >> 4, hh = bh & 15;
  #pragma unroll
  for (int fn = 0; fn < 4; fn++)
  #pragma unroll
  for (int r = 0; r < 4; r++){
    float ov = oacc[fn][r] / (32768.0f * lsum[r]);   // 512*64 scale
    int m = qt*64 + wid*16 + lg*4 + r;
    size_t oi = ((size_t)(bb*TN + m))*DN + hh*HSN + fn*16 + lr;
    _Float16 hi, lo; fsplit(ov * 64.0f, hi, lo);
    ohi_[oi] = hi; olo_[oi] = lo;
  }
}

// ---------------- proj GEMM + residual: 128x128, fused 3-product split -----------------
__global__ __launch_bounds__(256) void proj_gemm_kernel(
    const _Float16* __restrict__ ohi, const _Float16* __restrict__ olo,
    const unsigned char* __restrict__ bph, const unsigned char* __restrict__ bpl,
    const float* __restrict__ x, const float* __restrict__ bproj,
    float* __restrict__ out)
{
  const int mb = blockIdx.x;    // 0..63
  const int nb = blockIdx.y;    // 0..7
  __shared__ __align__(16) unsigned char Ah[16384], Al[16384], Bh[16384], Bl[16384];
  const int t = threadIdx.x, w = t >> 6, lane = t & 63, lg = lane >> 4, lr = lane & 15;
  const int wr = w >> 1, wc = w & 1;
  f32x4 acc[4][4] = {};
  const unsigned char* sbB = ((w == 2) ? bph : bpl) + ((size_t)(nb*16))*16384 + lane*16;
  unsigned char* dpB = (w == 2) ? Bh : Bl;
  const _Float16* aSrc = (w == 0) ? ohi : olo;
  unsigned char* dpA = (w == 0) ? Ah : Al;
  const int rA = lane >> 3;          // + j*8
  const int cA = lane & 7;
  for (int kt = 0; kt < 16; kt++){
    if (w < 2){
      #pragma unroll
      for (int j = 0; j < 16; j++){
        int r = rA + j*8;
        const unsigned char* s2 = (const unsigned char*)(aSrc + (size_t)(mb*128 + r)*DN)
                                  + kt*128 + ((cA ^ (r & 7)) << 4);
        gload16(s2, dpA + j*1024);
      }
    } else {
      const unsigned char* s2 = sbB + (size_t)kt*16384;
      #pragma unroll
      for (int j = 0; j < 16; j++) gload16(s2 + j*1024, dpB + j*1024);
    }
    __syncthreads();
    #pragma unroll
    for (int ks = 0; ks < 2; ks++){
      f16x8 ah[4], al[4], bh[4], bl[4];
      #pragma unroll
      for (int f = 0; f < 4; f++){
        int ra = wr*64 + f*16 + lr;
        int off = (ks*64 + lg*16) ^ ((ra & 7) << 4);
        ah[f] = *(const f16x8*)(Ah + ra*128 + off);
        al[f] = *(const f16x8*)(Al + ra*128 + off);
      }
      #pragma unroll
      for (int f = 0; f < 4; f++){
        int rb = wc*64 + f*16 + lr;
        int off = (ks*64 + lg*16) ^ ((rb & 7) << 4);
        bh[f] = *(const f16x8*)(Bh + rb*128 + off);
        bl[f] = *(const f16x8*)(Bl + rb*128 + off);
      }
      #pragma unroll
      for (int fm = 0; fm < 4; fm++)
      #pragma unroll
      for (int fn = 0; fn < 4; fn++){
        acc[fm][fn] = MFMA_F16(ah[fm], bh[fn], acc[fm][fn]);
        acc[fm][fn] = MFMA_F16(al[fm], bh[fn], acc[fm][fn]);
        acc[fm][fn] = MFMA_F16(ah[fm], bl[fn], acc[fm][fn]);
      }
    }
    __syncthreads();
  }
  #pragma unroll
  for (int fm = 0; fm < 4; fm++)
  #pragma unroll
  for (int fn = 0; fn < 4; fn++)
  #pragma unroll
  for (int rr = 0; rr < 4; rr++){
    int m = mb*128 + wr*64 + fm*16 + lg*4 + rr;
    int n = nb*128 + wc*64 + fn*16 + lr;
    size_t oi = (size_t)m*DN + n;
    out[oi] = x[oi] + acc[fm][fn][rr] * (1.0f/65536.0f) + bproj[n];
  }
}

// ---------------- router: LN2 (fp32) + logits + noisy top-2 + h2(bf16) ----------------
__global__ __launch_bounds__(256) void router_kernel(
    const float* __restrict__ x1, const float* __restrict__ g, const float* __restrict__ be,
    const float* __restrict__ Wr, const float* __restrict__ br,
    const float* __restrict__ Wn, const float* __restrict__ bn,
    const float* __restrict__ noise, unsigned short* __restrict__ h2bf,
    int* __restrict__ topk_e, float* __restrict__ topk_g, int* __restrict__ counts)
{
  const int token = blockIdx.x;
  const int t = threadIdx.x;
  __shared__ float redsum[4];
  __shared__ float red[64];
  float4 v = ((const float4*)(x1 + (size_t)token * DN))[t];
  float s = v.x + v.y + v.z + v.w;
  #pragma unroll
  for (int m = 32; m >= 1; m >>= 1) s += __shfl_xor(s, m);
  if ((t & 63) == 0) redsum[t >> 6] = s;
  __syncthreads();
  const float mu = (redsum[0] + redsum[1] + redsum[2] + redsum[3]) * (1.0f / DN);
  const float d0 = v.x - mu, d1 = v.y - mu, d2 = v.z - mu, d3 = v.w - mu;
  float s2 = d0*d0 + d1*d1 + d2*d2 + d3*d3;
  #pragma unroll
  for (int m = 32; m >= 1; m >>= 1) s2 += __shfl_xor(s2, m);
  __syncthreads();
  if ((t & 63) == 0) redsum[t >> 6] = s2;
  __syncthreads();
  const float var = (redsum[0] + redsum[1] + redsum[2] + redsum[3]) * (1.0f / DN);
  const float rs = 1.0f / sqrtf(var + 1e-5f);
  float4 gv = ((const float4*)g)[t];
  float4 bv = ((const float4*)be)[t];
  float h0 = d0*rs*gv.x + bv.x, h1v = d1*rs*gv.y + bv.y, h2v = d2*rs*gv.z + bv.z, h3 = d3*rs*gv.w + bv.w;
  ushort4 hb;
  hb.x = f2bf(h0); hb.y = f2bf(h1v); hb.z = f2bf(h2v); hb.w = f2bf(h3);
  *(ushort4*)(h2bf + (size_t)token*DN + t*4) = hb;
  float acc[16];
  const int j = t * 4;
  #pragma unroll
  for (int e = 0; e < 8; e++){
    acc[e]     = h0*Wr[(j+0)*8+e] + h1v*Wr[(j+1)*8+e] + h2v*Wr[(j+2)*8+e] + h3*Wr[(j+3)*8+e];
    acc[8 + e] = h0*Wn[(j+0)*8+e] + h1v*Wn[(j+1)*8+e] + h2v*Wn[(j+2)*8+e] + h3*Wn[(j+3)*8+e];
  }
  #pragma unroll
  for (int q = 0; q < 16; q++){
    #pragma unroll
    for (int m = 32; m >= 1; m >>= 1) acc[q] += __shfl_xor(acc[q], m);
  }
  if ((t & 63) == 0){
    #pragma unroll
    for (int q = 0; q < 16; q++) red[(t >> 6)*16 + q] = acc[q];
  }
  __syncthreads();
  if (t < 16) red[t] = red[t] + red[16 + t] + red[32 + t] + red[48 + t];
  __syncthreads();
  if (t == 0){
    float nz[8];
    #pragma unroll
    for (int e = 0; e < 8; e++){
      float logit = red[e] + br[e];
      float a = red[8 + e] + bn[e];
      float sp = (a > 20.0f) ? a : log1pf(expf(a));
      nz[e] = logit + noise[(size_t)token*EN + e] * sp;
    }
    float v1 = -INFINITY, v2 = -INFINITY; int i1 = 0, i2 = 0;
    #pragma unroll
    for (int e = 0; e < 8; e++){
      float z = nz[e];
      if (z > v1){ v2 = v1; i2 = i1; v1 = z; i1 = e; }
      else if (z > v2){ v2 = z; i2 = e; }
    }
    float e2 = expf(v2 - v1);
    float den = 1.0f + e2;
    topk_e[token*2]     = i1; topk_e[token*2 + 1] = i2;
    topk_g[token*2]     = 1.0f/den; topk_g[token*2 + 1] = e2/den;
    atomicAdd(&counts[i1], 1); atomicAdd(&counts[i2], 1);
  }
}

// 256-aligned expert segment offsets (moe tiles are 256 rows)
__global__ void scan_kernel(const int* __restrict__ counts, int* __restrict__ offs)
{
  if (threadIdx.x == 0 && blockIdx.x == 0){
    int a = 0;
    for (int e = 0; e < EN; e++){ offs[e] = a; a += (counts[e] + 255) & ~255; }
  }
}

__global__ __launch_bounds__(256) void scatter_kernel(
    const int* __restrict__ topk_e, const float* __restrict__ topk_g,
    const int* __restrict__ offs, int* __restrict__ fill,
    int* __restrict__ rows, float* __restrict__ grow)
{
  const int token = blockIdx.x*256 + threadIdx.x;
  #pragma unroll
  for (int i = 0; i < 2; i++){
    int e = topk_e[token*2 + i];
    int pos = offs[e] + atomicAdd(&fill[e], 1);
    rows[pos] = token;
    grow[pos] = topk_g[token*2 + i];
  }
}

// ---------------- expert weights -> 16KB LDS-image panels (bf16, swizzle baked) --------
__global__ __launch_bounds__(256) void wconv_kernel(
    const float* __restrict__ W1, const float* __restrict__ W2,
    unsigned char* __restrict__ w1p, unsigned char* __restrict__ w2p)
{
  int b = blockIdx.x;
  const float* W; unsigned char* pan; int Nd, kt, n;
  if (b < 2048){
    int e = b >> 8, rem = b & 255, nb2 = rem >> 4; kt = rem & 15;
    n = nb2*256 + threadIdx.x;                       // 0..4095
    W = W1 + (size_t)e * DN * DFN; Nd = DFN;
    pan = w1p + (((size_t)e*32 + (n >> 7))*16 + kt) * 16384;
  } else {
    b -= 2048;
    int e = b >> 8, rem = b & 255, nb2 = rem >> 6; kt = rem & 63;
    n = nb2*256 + threadIdx.x;                       // 0..1023
    W = W2 + (size_t)e * DFN * DN; Nd = DN;
    pan = w2p + (((size_t)e*8 + (n >> 7))*64 + kt) * 16384;
  }
  const int r = n & 127;
  #pragma unroll
  for (int kk8 = 0; kk8 < 8; kk8++){
    union { unsigned short u[8]; uint4 v; } buf;
    #pragma unroll
    for (int j = 0; j < 8; j++)
      buf.u[j] = f2bf(W[(size_t)(kt*64 + kk8*8 + j)*Nd + n]);
    *(uint4*)(pan + r*128 + ((kk8 ^ (r & 7)) << 4)) = buf.v;
  }
}

// ---------------- gather tokens into A panels: apnl[pb][kt16][16KB image] ----------------
__global__ __launch_bounds__(256) void agather_kernel(
    const unsigned short* __restrict__ h2bf, const int* __restrict__ rows,
    unsigned char* __restrict__ apnl)
{
  const int pb = blockIdx.x, kt = blockIdx.y;
  const int t = threadIdx.x;
  const int r = t >> 1, c0 = (t & 1) * 4;
  const int tok = rows[pb*128 + r];
  const unsigned char* src = (const unsigned char*)h2bf + (size_t)tok*2048 + kt*128;
  unsigned char* dst = apnl + ((size_t)pb*16 + kt)*16384 + r*128;
  #pragma unroll
  for (int i = 0; i < 4; i++){
    int c = c0 + i;
    *(uint4*)(dst + ((c ^ (r & 7)) << 4)) = *(const uint4*)(src + c*16);
  }
}

// ---------------- MoE GEMM1 (persistent, 2D-window, single-barrier, NT midP stores) ----
__global__ __launch_bounds__(512, 1) void moe1_kernel(
    const unsigned char* __restrict__ apnl, const unsigned char* __restrict__ w1p,
    const float* __restrict__ b1,
    const int* __restrict__ counts, const int* __restrict__ offs,
    unsigned short* __restrict__ midP)
{
  __shared__ __align__(16) unsigned char As[2][32768], Bs[2][32768];
  const int bid = blockIdx.x;
  const int t = threadIdx.x;
  const int w = t >> 6, lane = t & 63, lg = lane >> 4, lr = lane & 15;
  const int wm = w >> 2, wn = w & 3;
  const int sp = (w >> 1) & 1, sh = (w & 1) * 8192;
  const int e  = bid & 7;
  const int c  = bid >> 3;                 // CU slot within XCD, 0..31
  const int cnt = counts[e];
  const int off = offs[e];
  const int nmb = (cnt + 255) >> 8;
  const int nch = nmb * 16;
  for (int q = c; q < nch; q += 32){
    const int grp = q / (4*nmb);
    const int within = q - grp*4*nmb;
    const int mb = within >> 2;
    const int nb = grp*4 + (within & 3);   // 0..15 (256-col group)
    const int m0 = mb * 256;
    const int pb0 = (off + m0) >> 7;
    const unsigned char* sbase;
    unsigned char* dbase;
    if (w < 4){
      sbase = apnl + ((size_t)(pb0 + sp) * 16) * 16384 + sh + lane*16;
      dbase = &As[0][sp*16384 + sh];
    } else {
      sbase = w1p + ((size_t)(e*32 + nb*2 + sp) * 16) * 16384 + sh + lane*16;
      dbase = &Bs[0][sp*16384 + sh];
    }
    f32x4 acc[8][4] = {};
    auto stage = [&](int buf, int kt){
      const unsigned char* s2 = sbase + (size_t)kt * 16384;
      unsigned char* d = dbase + buf * 32768;
      #pragma unroll
      for (int j = 0; j < 8; j++) gload16(s2 + j*1024, d + j*1024);
    };
    auto compute = [&](int buf){
      const unsigned char* pA = &As[buf][wm*16384];
      const unsigned char* pB = &Bs[buf][(wn>>1)*16384];
      #pragma unroll
      for (int ks = 0; ks < 2; ks++){
        s16x8 b[4], a[8];
        #pragma unroll
        for (int f = 0; f < 4; f++){
          int rb = (wn&1)*64 + f*16 + lr;
          b[f] = *(const s16x8*)(pB + rb*128 + ((ks*64 + lg*16) ^ ((rb&7)<<4)));
        }
        #pragma unroll
        for (int f = 0; f < 8; f++){
          int ra = f*16 + lr;
          a[f] = *(const s16x8*)(pA + ra*128 + ((ks*64 + lg*16) ^ ((ra&7)<<4)));
        }
        #pragma unroll
        for (int fm = 0; fm < 8; fm++)
        #pragma unroll
        for (int fn = 0; fn < 4; fn++)
          acc[fm][fn] = MFMA_BF16(a[fm], b[fn], acc[fm][fn]);
      }
    };
    // T3-minimum single-barrier loop: stage(next) -> compute(cur) -> vmcnt(0)+barrier
    stage(0, 0);
    VMW_BAR(0);
    for (int kt = 0; kt < 16; kt += 2){
      stage(1, kt + 1);
      compute(0);
      VMW_BAR(0);
      if (kt + 2 < 16) stage(0, kt + 2);
      compute(1);
      VMW_BAR(0);
    }
    {
      unsigned char* Lp = ((wm == 0) ? (unsigned char*)As : (unsigned char*)Bs) + wn*16384;
      const float* b1e = b1 + (size_t)e*DFN + nb*256 + wn*64;
      #pragma unroll
      for (int fn = 0; fn < 4; fn++){
        float bias = b1e[fn*16 + lr];
        int col = fn*16 + lr;
        #pragma unroll
        for (int fm = 0; fm < 8; fm++)
        #pragma unroll
        for (int rr = 0; rr < 4; rr++){
          int r = fm*16 + lg*4 + rr;
          float v = fmaxf(acc[fm][fn][rr] + bias, 0.0f);
          *(unsigned short*)(Lp + r*128 + ((col ^ ((r & 7) << 3)) * 2)) = f2bf(v);
        }
      }
    }
    BAR();
    {
      int p = w >> 2, jj = w & 3;
      const u32x4* src = (const u32x4*)(((p == 0) ? (unsigned char*)As : (unsigned char*)Bs) + jj*16384);
      u32x4* dst = (u32x4*)((unsigned char*)midP + (((size_t)(pb0 + p)*64) + nb*4 + jj) * 16384);
      #pragma unroll
      for (int i = 0; i < 16; i++)
        __builtin_nontemporal_store(src[lane + i*64], &dst[lane + i*64]);
    }
    BAR();
  }
}

// ---------------- MoE GEMM2 (persistent, 2D-window, single-barrier, no setprio) --------
__global__ __launch_bounds__(512, 1) void moe2_kernel(
    const unsigned char* __restrict__ midP, const unsigned char* __restrict__ w2p,
    const float* __restrict__ b2,
    const int* __restrict__ counts, const int* __restrict__ offs,
    const int* __restrict__ rows, const float* __restrict__ grow,
    float* __restrict__ out)
{
  __shared__ __align__(16) unsigned char As[2][32768], Bs[2][32768];
  const int bid = blockIdx.x;
  const int t = threadIdx.x;
  const int w = t >> 6, lane = t & 63, lg = lane >> 4, lr = lane & 15;
  const int wm = w >> 2, wn = w & 3;
  const int sp = (w >> 1) & 1, sh = (w & 1) * 8192;
  const int e  = bid & 7;
  const int c  = bid >> 3;
  const int cnt = counts[e];
  const int off = offs[e];
  const int nmb = (cnt + 255) >> 8;
  const int nch = nmb * 4;
  for (int q = c; q < nch; q += 32){
    const int mb = q >> 2;
    const int nb = q & 3;
    const int m0 = mb * 256;
    const int pb0 = (off + m0) >> 7;
    const unsigned char* sbase;
    unsigned char* dbase;
    if (w < 4){
      sbase = midP + ((size_t)(pb0 + sp) * 64) * 16384 + sh + lane*16;
      dbase = &As[0][sp*16384 + sh];
    } else {
      sbase = w2p + ((size_t)(e*8 + nb*2 + sp) * 64) * 16384 + sh + lane*16;
      dbase = &Bs[0][sp*16384 + sh];
    }
    f32x4 acc[8][4] = {};
    auto stage = [&](int buf, int kt){
      const unsigned char* s2 = sbase + (size_t)kt * 16384;
      unsigned char* d = dbase + buf * 32768;
      #pragma unroll
      for (int j = 0; j < 8; j++) gload16(s2 + j*1024, d + j*1024);
    };
    auto compute = [&](int buf){
      const unsigned char* pA = &As[buf][wm*16384];
      const unsigned char* pB = &Bs[buf][(wn>>1)*16384];
      #pragma unroll
      for (int ks = 0; ks < 2; ks++){
        s16x8 b[4], a[8];
        #pragma unroll
        for (int f = 0; f < 4; f++){
          int rb = (wn&1)*64 + f*16 + lr;
          b[f] = *(const s16x8*)(pB + rb*128 + ((ks*64 + lg*16) ^ ((rb&7)<<4)));
        }
        #pragma unroll
        for (int f = 0; f < 8; f++){
          int ra = f*16 + lr;
          a[f] = *(const s16x8*)(pA + ra*128 + ((ks*64 + lg*16) ^ ((ra&7)<<4)));
        }
        #pragma unroll
        for (int fm = 0; fm < 8; fm++)
        #pragma unroll
        for (int fn = 0; fn < 4; fn++)
          acc[fm][fn] = MFMA_BF16(a[fm], b[fn], acc[fm][fn]);
      }
    };
    // T3-minimum single-barrier loop
    stage(0, 0);
    VMW_BAR(0);
    for (int kt = 0; kt < 64; kt += 2){
      stage(1, kt + 1);
      compute(0);
      VMW_BAR(0);
      if (kt + 2 < 64) stage(0, kt + 2);
      compute(1);
      VMW_BAR(0);
    }
    const float* b2e = b2 + (size_t)e*DN + nb*256 + wn*64;
    #pragma unroll
    for (int fm = 0; fm < 8; fm++)
    #pragma unroll
    for (int rr = 0; rr < 4; rr++){
      int ml = wm*128 + fm*16 + lg*4 + rr;
      if (m0 + ml < cnt){
        int gi = off + m0 + ml;
        int tok = rows[gi];
        float gt = grow[gi];
        #pragma unroll
        for (int fn = 0; fn < 4; fn++){
          int n = nb*256 + wn*64 + fn*16 + lr;
          atomicAdd(out + (size_t)tok*DN + n, gt*(acc[fm][fn][rr] + b2e[fn*16 + lr]));
        }
      }
    }
  }
}

// ---------------- launch ----------------
extern "C" void kernel_launch(void* const* d_in, const int* in_sizes, int n_in,
                              void* d_out, int out_size, void* d_ws, size_t ws_size,
                              hipStream_t stream) {
  (void)in_sizes; (void)n_in; (void)out_size; (void)ws_size;
  const float* x     = (const float*)d_in[0];
  const float* noise = (const float*)d_in[1];
  const float* Wq    = (const float*)d_in[2];
  const float* Wk    = (const float*)d_in[3];
  const float* Wv    = (const float*)d_in[4];
  const float* Wp    = (const float*)d_in[5];
  const float* bproj = (const float*)d_in[6];
  const float* ln1g  = (const float*)d_in[7];
  const float* ln1b  = (const float*)d_in[8];
  const float* ln2g  = (const float*)d_in[9];
  const float* ln2b  = (const float*)d_in[10];
  const float* Wr    = (const float*)d_in[11];
  const float* br    = (const float*)d_in[12];
  const float* Wn    = (const float*)d_in[13];
  const float* bn    = (const float*)d_in[14];
  const float* W1    = (const float*)d_in[15];
  const float* b1    = (const float*)d_in[16];
  const float* W2    = (const float*)d_in[17];
  const float* b2    = (const float*)d_in[18];
  float* out = (float*)d_out;

  char* w = (char*)d_ws;
  auto alloc = [&](size_t bytes) -> char* {
    char* p = w; w += (bytes + 255) & ~(size_t)255; return p;
  };
  // Region A: qkv split + o split during attention; reused as panelized `mid` during MoE.
  char* big = alloc((size_t)NPB * 64 * 16384);          // 151 MB >= 134.2 MB qkv need
  _Float16* qkvsplit = (_Float16*)big;
  _Float16* ohi = (_Float16*)(big + (size_t)6*NQ*2);
  _Float16* olo = ohi + NQ;
  unsigned short* midP = (unsigned short*)big;
  // Region B: attention temporaries (dead after proj); W1 panels overlay them afterwards.
  char* attn_tmp = w;
  unsigned char* aph = (unsigned char*)alloc((size_t)64*16*16384);   // h1 hi panels 16 MB
  unsigned char* apl = (unsigned char*)alloc((size_t)64*16*16384);   // h1 lo panels 16 MB
  unsigned char* bqh = (unsigned char*)alloc((size_t)24*16*16384);   // qkv W hi panels 6.3 MB
  unsigned char* bql = (unsigned char*)alloc((size_t)24*16*16384);
  unsigned char* bph = (unsigned char*)alloc((size_t)8*16*16384);    // proj W hi panels 2.1 MB
  unsigned char* bpl = (unsigned char*)alloc((size_t)8*16*16384);
  unsigned char* w1p = (unsigned char*)attn_tmp;        // 64 MiB panels overlay
  char* w1p_end = attn_tmp + (size_t)EN*DFN*DN*2;
  if (w < w1p_end) w = w1p_end;
  unsigned char* w2p = (unsigned char*)alloc((size_t)EN*DN*DFN*2);   // 64 MiB
  unsigned char* apnl = (unsigned char*)alloc((size_t)NPB*16*16384); // 37.7 MB
  unsigned short* h2bf = (unsigned short*)alloc((size_t)NTOK*DN*2);
  int*   topk_e = (int*)alloc(NTOK*2*sizeof(int));
  float* topk_g = (float*)alloc(NTOK*2*sizeof(float));
  int*   rowsA  = (int*)alloc((size_t)NPB*128*sizeof(int));
  float* growA  = (float*)alloc((size_t)NPB*128*sizeof(float));
  int*   cnts   = (int*)alloc(256);
  int*   fill   = cnts + 8;
  int*   offs   = cnts + 16;

  (void)hipMemsetAsync(cnts, 0, 64, stream);                  // counts + fill
  (void)hipMemsetAsync(rowsA, 0, (size_t)NPB*128*sizeof(int), stream);
  ln1_kernel<<<NTOK, 128, 0, stream>>>(x, ln1g, ln1b, aph, apl);
  wsplit_kernel<<<512, 256, 0, stream>>>(Wq, Wk, Wv, Wp, bqh, bql, bph, bpl);
  qkv_gemm_kernel<<<dim3(64, 24), 256, 0, stream>>>(aph, apl, bqh, bql, qkvsplit);
  attn_kernel<<<dim3(16, 128), 256, 0, stream>>>(qkvsplit, ohi, olo);
  proj_gemm_kernel<<<dim3(64, 8), 256, 0, stream>>>(ohi, olo, bph, bpl, x, bproj, out);
  // attn temporaries now dead -> overlay weight panels
  wconv_kernel<<<4096, 256, 0, stream>>>(W1, W2, w1p, w2p);
  router_kernel<<<NTOK, 256, 0, stream>>>(out, ln2g, ln2b, Wr, br, Wn, bn, noise,
                                          h2bf, topk_e, topk_g, cnts);
  scan_kernel<<<1, 64, 0, stream>>>(cnts, offs);
  scatter_kernel<<<NTOK/256, 256, 0, stream>>>(topk_e, topk_g, offs, fill, rowsA, growA);
  agather_kernel<<<dim3(NPB, 16), 256, 0, stream>>>(h2bf, rowsA, apnl);
  moe1_kernel<<<256, 512, 0, stream>>>(apnl, w1p, b1, cnts, offs, midP);
  moe2_kernel<<<256, 512, 0, stream>>>((const unsigned char*)midP, w2p, b2,
                                       cnts, offs, rowsA, growA, out);
}

// Round 21
// 1357.844 us; speedup vs baseline: 1.2019x; 1.0574x over previous
//
#include <hip/hip_runtime.h>
#include <hip/hip_bf16.h>
#include <math.h>

#define NTOK 8192
#define DN   1024
#define HN   16
#define HSN  64
#define EN   8
#define DFN  4096
#define TN   1024
#define NQ   8388608u   // B*T*D elements per q/k/v buffer
#define NPB  144        // max 128-row panels (16384 + 8*255 pad, 256-aligned segments)

typedef _Float16 f16x8 __attribute__((ext_vector_type(8)));
typedef _Float16 f16x4 __attribute__((ext_vector_type(4)));
typedef float    f32x4 __attribute__((ext_vector_type(4)));
typedef short    s16x8 __attribute__((ext_vector_type(8)));
typedef unsigned int u32x4 __attribute__((ext_vector_type(4)));

#define MFMA_F16(A,B,C)  __builtin_amdgcn_mfma_f32_16x16x32_f16((A),(B),(C),0,0,0)
#define MFMA_BF16(A,B,C) __builtin_amdgcn_mfma_f32_16x16x32_bf16((A),(B),(C),0,0,0)

__device__ __forceinline__ unsigned short f2bf(float f){
  union { float f; unsigned u; } v; v.f = f;
  unsigned r = v.u + 0x7fffu + ((v.u >> 16) & 1u);
  return (unsigned short)(r >> 16);
}
__device__ __forceinline__ void fsplit(float v, _Float16& hi, _Float16& lo){
  hi = (_Float16)v; lo = (_Float16)(v - (float)hi);
}
// async global->LDS, 16B per lane; LDS dest is wave-uniform base (+lane*16 implicit)
__device__ __forceinline__ void gload16(const void* g, void* l){
  __builtin_amdgcn_global_load_lds((const __attribute__((address_space(1))) unsigned int*)g,
                                   (__attribute__((address_space(3))) unsigned int*)l, 16, 0, 0);
}
#define BAR() __builtin_amdgcn_s_barrier()
#define VMW_BAR(N) do { \
  asm volatile("s_waitcnt vmcnt(" #N ")" ::: "memory"); \
  __builtin_amdgcn_s_barrier(); \
} while (0)

// ---------------- LN1: x -> h1 panel images (x64, hi/lo) ----------------
__global__ __launch_bounds__(128) void ln1_kernel(
    const float* __restrict__ x, const float* __restrict__ g, const float* __restrict__ be,
    unsigned char* __restrict__ aph, unsigned char* __restrict__ apl)
{
  const int row = blockIdx.x;
  const int t = threadIdx.x;             // 0..127, handles 8 cols
  __shared__ float red[2];
  float4 va = ((const float4*)(x + (size_t)row*DN))[t*2];
  float4 vb = ((const float4*)(x + (size_t)row*DN))[t*2+1];
  float s = va.x+va.y+va.z+va.w + vb.x+vb.y+vb.z+vb.w;
  #pragma unroll
  for (int m = 32; m >= 1; m >>= 1) s += __shfl_xor(s, m);
  if ((t & 63) == 0) red[t >> 6] = s;
  __syncthreads();
  const float mu = (red[0] + red[1]) * (1.0f / DN);
  float e[8] = { va.x-mu, va.y-mu, va.z-mu, va.w-mu, vb.x-mu, vb.y-mu, vb.z-mu, vb.w-mu };
  float s2 = 0.0f;
  #pragma unroll
  for (int i = 0; i < 8; i++) s2 += e[i]*e[i];
  #pragma unroll
  for (int m = 32; m >= 1; m >>= 1) s2 += __shfl_xor(s2, m);
  __syncthreads();
  if ((t & 63) == 0) red[t >> 6] = s2;
  __syncthreads();
  const float var = (red[0] + red[1]) * (1.0f / DN);
  const float rs = 1.0f / sqrtf(var + 1e-5f);
  float4 ga = ((const float4*)g)[t*2], gb = ((const float4*)g)[t*2+1];
  float4 ba = ((const float4*)be)[t*2], bb = ((const float4*)be)[t*2+1];
  float gg[8] = { ga.x,ga.y,ga.z,ga.w, gb.x,gb.y,gb.z,gb.w };
  float bbv[8] = { ba.x,ba.y,ba.z,ba.w, bb.x,bb.y,bb.z,bb.w };
  f16x8 hi8, lo8;
  #pragma unroll
  for (int i = 0; i < 8; i++){
    _Float16 hi, lo; fsplit((e[i]*rs*gg[i] + bbv[i]) * 64.0f, hi, lo);
    hi8[i] = hi; lo8[i] = lo;
  }
  const int pb = row >> 7, r = row & 127, kt = t >> 3, kk8 = t & 7;
  size_t po = ((size_t)(pb*16 + kt))*16384 + r*128 + (size_t)((kk8 ^ (r & 7)) << 4);
  *(f16x8*)(aph + po) = hi8;
  *(f16x8*)(apl + po) = lo8;
}

// ---------------- attention weights -> B panel images (x1024, hi/lo) ----------------
__global__ __launch_bounds__(256) void wsplit_kernel(
    const float* __restrict__ Wq, const float* __restrict__ Wk, const float* __restrict__ Wv,
    const float* __restrict__ Wp,
    unsigned char* __restrict__ bqh, unsigned char* __restrict__ bql,
    unsigned char* __restrict__ bph, unsigned char* __restrict__ bpl)
{
  int b = blockIdx.x;
  const int t = threadIdx.x;
  const int r = t & 127;
  const int c0 = (t >> 7) * 4;     // physical slots c0..c0+3
  if (b < 384){
    int nb = b >> 4, kt = b & 15;
    int n = nb*128 + r;
    int mat = n >> 10, h = (n >> 6) & 15, hs = n & 63;
    const float* W = (mat == 0) ? Wq : ((mat == 1) ? Wk : Wv);
    const float* src = W + (size_t)h*65536 + hs;     // + k*64
    unsigned char* ph = bqh + ((size_t)(nb*16 + kt))*16384 + r*128;
    unsigned char* pl = bql + ((size_t)(nb*16 + kt))*16384 + r*128;
    #pragma unroll
    for (int c = c0; c < c0 + 4; c++){
      int kk8 = c ^ (r & 7);
      f16x8 hi8, lo8;
      #pragma unroll
      for (int j = 0; j < 8; j++){
        _Float16 hi, lo; fsplit(src[(size_t)(kt*64 + kk8*8 + j)*64] * 1024.0f, hi, lo);
        hi8[j] = hi; lo8[j] = lo;
      }
      *(f16x8*)(ph + c*16) = hi8;
      *(f16x8*)(pl + c*16) = lo8;
    }
  } else {
    b -= 384;
    int nb = b >> 4, kt = b & 15;
    int n = nb*128 + r;
    unsigned char* ph = bph + ((size_t)(nb*16 + kt))*16384 + r*128;
    unsigned char* pl = bpl + ((size_t)(nb*16 + kt))*16384 + r*128;
    #pragma unroll
    for (int c = c0; c < c0 + 4; c++){
      int kk8 = c ^ (r & 7);
      f16x8 hi8, lo8;
      #pragma unroll
      for (int j = 0; j < 8; j++){
        _Float16 hi, lo; fsplit(Wp[(size_t)(kt*64 + kk8*8 + j)*DN + n] * 1024.0f, hi, lo);
        hi8[j] = hi; lo8[j] = lo;
      }
      *(f16x8*)(ph + c*16) = hi8;
      *(f16x8*)(pl + c*16) = lo8;
    }
  }
}

// ---------------- QKV GEMM: 128x128, fused 3-product split (one K pass) ----------------
// V (mat==2) is written TRANSPOSED: [b,h,hs,t] so attention can stage V^T vectorized.
__global__ __launch_bounds__(256) void qkv_gemm_kernel(
    const unsigned char* __restrict__ aph, const unsigned char* __restrict__ apl,
    const unsigned char* __restrict__ bqh, const unsigned char* __restrict__ bql,
    _Float16* __restrict__ qkvout)
{
  const int mb = blockIdx.x;    // 0..63
  const int nb = blockIdx.y;    // 0..23
  __shared__ __align__(16) unsigned char Ah[16384], Al[16384], Bh[16384], Bl[16384];
  const int t = threadIdx.x, w = t >> 6, lane = t & 63, lg = lane >> 4, lr = lane & 15;
  const int wr = w >> 1, wc = w & 1;
  const unsigned char* sb;
  unsigned char* dp;
  if (w == 0){ sb = aph + ((size_t)(mb*16))*16384; dp = Ah; }
  else if (w == 1){ sb = apl + ((size_t)(mb*16))*16384; dp = Al; }
  else if (w == 2){ sb = bqh + ((size_t)(nb*16))*16384; dp = Bh; }
  else { sb = bql + ((size_t)(nb*16))*16384; dp = Bl; }
  sb += lane*16;
  f32x4 acc[4][4] = {};
  for (int kt = 0; kt < 16; kt++){
    const unsigned char* s2 = sb + (size_t)kt*16384;
    #pragma unroll
    for (int j = 0; j < 16; j++) gload16(s2 + j*1024, dp + j*1024);
    __syncthreads();
    #pragma unroll
    for (int ks = 0; ks < 2; ks++){
      f16x8 ah[4], al[4], bh[4], bl[4];
      #pragma unroll
      for (int f = 0; f < 4; f++){
        int ra = wr*64 + f*16 + lr;
        int off = (ks*64 + lg*16) ^ ((ra & 7) << 4);
        ah[f] = *(const f16x8*)(Ah + ra*128 + off);
        al[f] = *(const f16x8*)(Al + ra*128 + off);
      }
      #pragma unroll
      for (int f = 0; f < 4; f++){
        int rb = wc*64 + f*16 + lr;
        int off = (ks*64 + lg*16) ^ ((rb & 7) << 4);
        bh[f] = *(const f16x8*)(Bh + rb*128 + off);
        bl[f] = *(const f16x8*)(Bl + rb*128 + off);
      }
      #pragma unroll
      for (int fm = 0; fm < 4; fm++)
      #pragma unroll
      for (int fn = 0; fn < 4; fn++){
        acc[fm][fn] = MFMA_F16(ah[fm], bh[fn], acc[fm][fn]);
        acc[fm][fn] = MFMA_F16(al[fm], bh[fn], acc[fm][fn]);
        acc[fm][fn] = MFMA_F16(ah[fm], bl[fn], acc[fm][fn]);
      }
    }
    __syncthreads();
  }
  #pragma unroll
  for (int fm = 0; fm < 4; fm++)
  #pragma unroll
  for (int fn = 0; fn < 4; fn++)
  #pragma unroll
  for (int rr = 0; rr < 4; rr++){
    int m = mb*128 + wr*64 + fm*16 + lg*4 + rr;
    int n = nb*128 + wc*64 + fn*16 + lr;
    int mat = n >> 10, h = (n >> 6) & 15, hs = n & 63;
    int bb = m >> 10, tt = m & 1023;
    _Float16* dsthi = qkvout + (size_t)mat * 2u * NQ;
    _Float16* dstlo = dsthi + NQ;
    size_t oi;
    if (mat == 2)  // V transposed: [b][h][hs][t]
      oi = (((size_t)(bb*HN + h))*HSN + hs)*TN + tt;
    else
      oi = (((size_t)(bb*HN + h))*TN + tt)*HSN + hs;
    _Float16 hi, lo; fsplit(acc[fm][fn][rr] * (1.0f/1024.0f), hi, lo);  // = 64*q
    dsthi[oi] = hi; dstlo[oi] = lo;
  }
}

// ---------------- flash attention (split f16, V^T input, XCD-grouped bh) ----------------
__global__ __launch_bounds__(256) void attn_kernel(
    const _Float16* __restrict__ qkv,
    _Float16* __restrict__ ohi_, _Float16* __restrict__ olo_)
{
  const _Float16* qhi = qkv;
  const _Float16* qlo = qkv + NQ;
  const _Float16* khi = qkv + 2u*NQ;
  const _Float16* klo = qkv + 3u*NQ;
  const _Float16* vhi = qkv + 4u*NQ;   // layout [b,h,hs,t]
  const _Float16* vlo = qkv + 5u*NQ;
  // XCD-locality permutation: HW round-robins linear block id across 8 XCDs.
  // Group so each XCD owns 16 contiguous bh values (its K/V stays in its L2).
  const int id   = blockIdx.x;         // 0..2047
  const int xcd  = id & 7;
  const int slot = id >> 3;            // 0..255
  const int bh   = xcd*16 + (slot & 15);   // 0..127, bijective
  const int qt   = slot >> 4;              // 0..15
  const size_t base = (size_t)bh * TN * HSN;   // same element count for V^T
  const int t = threadIdx.x, wid = t >> 6, lane = t & 63, lg = lane >> 4, lr = lane & 15;
  __shared__ _Float16 Khi[64][72], Klo[64][72], Vthi[64][72], Vtlo[64][72], Phi[64][72], Plo[64][72];
  f16x8 qh[2], ql[2];
  {
    const int qrow = qt*64 + wid*16 + lr;
    const _Float16* qp  = qhi + base + (size_t)qrow*HSN;
    const _Float16* qpl = qlo + base + (size_t)qrow*HSN;
    #pragma unroll
    for (int c = 0; c < 2; c++){
      qh[c] = *(const f16x8*)(qp  + c*32 + lg*8);
      ql[c] = *(const f16x8*)(qpl + c*32 + lg*8);
    }
  }
  f32x4 oacc[4] = {};
  float mrow[4], lsum[4];
  #pragma unroll
  for (int r = 0; r < 4; r++){ mrow[r] = -INFINITY; lsum[r] = 0.0f; }
  const int sr = t >> 2, sc = (t & 3) * 16;
  const float sscale = 1.0f / (4096.0f * 32.0f);
  for (int kvt = 0; kvt <= qt; kvt++){
    {
      const size_t gr = base + (size_t)(kvt*64 + sr)*HSN + sc;
      *(f16x8*)&Khi[sr][sc]     = *(const f16x8*)(khi + gr);
      *(f16x8*)&Khi[sr][sc + 8] = *(const f16x8*)(khi + gr + 8);
      *(f16x8*)&Klo[sr][sc]     = *(const f16x8*)(klo + gr);
      *(f16x8*)&Klo[sr][sc + 8] = *(const f16x8*)(klo + gr + 8);
      // V^T: row sr = hs, cols = t within tile (vectorized, no transpose)
      const size_t gv = base + (size_t)sr*TN + kvt*64 + sc;
      *(f16x8*)&Vthi[sr][sc]     = *(const f16x8*)(vhi + gv);
      *(f16x8*)&Vthi[sr][sc + 8] = *(const f16x8*)(vhi + gv + 8);
      *(f16x8*)&Vtlo[sr][sc]     = *(const f16x8*)(vlo + gv);
      *(f16x8*)&Vtlo[sr][sc + 8] = *(const f16x8*)(vlo + gv + 8);
    }
    __syncthreads();
    f32x4 sacc[4] = {};
    #pragma unroll
    for (int c = 0; c < 2; c++)
    #pragma unroll
    for (int fn = 0; fn < 4; fn++){
      f16x8 kh = *(const f16x8*)&Khi[fn*16 + lr][c*32 + lg*8];
      f16x8 kl = *(const f16x8*)&Klo[fn*16 + lr][c*32 + lg*8];
      sacc[fn] = MFMA_F16(qh[c], kh, sacc[fn]);
      sacc[fn] = MFMA_F16(qh[c], kl, sacc[fn]);
      sacc[fn] = MFMA_F16(ql[c], kh, sacc[fn]);
    }
    float sv[4][4], pmax[4];
    #pragma unroll
    for (int r = 0; r < 4; r++) pmax[r] = -INFINITY;
    const int qg0 = qt*64 + wid*16 + lg*4;
    #pragma unroll
    for (int fn = 0; fn < 4; fn++)
    #pragma unroll
    for (int r = 0; r < 4; r++){
      float xv = sacc[fn][r] * sscale;
      int kvg = kvt*64 + fn*16 + lr;
      xv = (kvg <= qg0 + r) ? xv : -INFINITY;
      sv[fn][r] = xv;
      pmax[r] = fmaxf(pmax[r], xv);
    }
    #pragma unroll
    for (int r = 0; r < 4; r++){
      #pragma unroll
      for (int m = 1; m < 16; m <<= 1) pmax[r] = fmaxf(pmax[r], __shfl_xor(pmax[r], m));
    }
    float alpha[4], mnew[4], psum[4];
    #pragma unroll
    for (int r = 0; r < 4; r++){
      mnew[r] = fmaxf(mrow[r], pmax[r]);
      alpha[r] = __expf(mrow[r] - mnew[r]);
      psum[r] = 0.0f;
    }
    #pragma unroll
    for (int fn = 0; fn < 4; fn++)
    #pragma unroll
    for (int r = 0; r < 4; r++){
      float p = __expf(sv[fn][r] - mnew[r]);
      psum[r] += p;
      _Float16 hi, lo; fsplit(p * 512.0f, hi, lo);
      Phi[wid*16 + lg*4 + r][fn*16 + lr] = hi;
      Plo[wid*16 + lg*4 + r][fn*16 + lr] = lo;
    }
    #pragma unroll
    for (int r = 0; r < 4; r++){
      #pragma unroll
      for (int m = 1; m < 16; m <<= 1) psum[r] += __shfl_xor(psum[r], m);
      lsum[r] = lsum[r]*alpha[r] + psum[r];
      mrow[r] = mnew[r];
    }
    #pragma unroll
    for (int fn = 0; fn < 4; fn++)
    #pragma unroll
    for (int r = 0; r < 4; r++) oacc[fn][r] *= alpha[r];
    #pragma unroll
    for (int c2 = 0; c2 < 2; c2++){
      f16x8 ph = *(const f16x8*)&Phi[wid*16 + lr][c2*32 + lg*8];
      f16x8 pl = *(const f16x8*)&Plo[wid*16 + lr][c2*32 + lg*8];
      #pragma unroll
      for (int fn = 0; fn < 4; fn++){
        f16x8 vh = *(const f16x8*)&Vthi[fn*16 + lr][c2*32 + lg*8];
        f16x8 vl = *(const f16x8*)&Vtlo[fn*16 + lr][c2*32 + lg*8];
        oacc[fn] = MFMA_F16(ph, vh, oacc[fn]);
        oacc[fn] = MFMA_F16(ph, vl, oacc[fn]);
        oacc[fn] = MFMA_F16(pl, vh, oacc[fn]);
      }
    }
    __syncthreads();
  }
  const int bb = bh >> 4, hh = bh & 15;
  #pragma unroll
  for (int fn = 0; fn < 4; fn++)
  #pragma unroll
  for (int r = 0; r < 4; r++){
    float ov = oacc[fn][r] / (32768.0f * lsum[r]);   // 512*64 scale
    int m = qt*64 + wid*16 + lg*4 + r;
    size_t oi = ((size_t)(bb*TN + m))*DN + hh*HSN + fn*16 + lr;
    _Float16 hi, lo; fsplit(ov * 64.0f, hi, lo);
    ohi_[oi] = hi; olo_[oi] = lo;
  }
}

// ---------------- proj GEMM + residual: 128x128, fused 3-product split -----------------
__global__ __launch_bounds__(256) void proj_gemm_kernel(
    const _Float16* __restrict__ ohi, const _Float16* __restrict__ olo,
    const unsigned char* __restrict__ bph, const unsigned char* __restrict__ bpl,
    const float* __restrict__ x, const float* __restrict__ bproj,
    float* __restrict__ out)
{
  const int mb = blockIdx.x;    // 0..63
  const int nb = blockIdx.y;    // 0..7
  __shared__ __align__(16) unsigned char Ah[16384], Al[16384], Bh[16384], Bl[16384];
  const int t = threadIdx.x, w = t >> 6, lane = t & 63, lg = lane >> 4, lr = lane & 15;
  const int wr = w >> 1, wc = w & 1;
  f32x4 acc[4][4] = {};
  const unsigned char* sbB = ((w == 2) ? bph : bpl) + ((size_t)(nb*16))*16384 + lane*16;
  unsigned char* dpB = (w == 2) ? Bh : Bl;
  const _Float16* aSrc = (w == 0) ? ohi : olo;
  unsigned char* dpA = (w == 0) ? Ah : Al;
  const int rA = lane >> 3;          // + j*8
  const int cA = lane & 7;
  for (int kt = 0; kt < 16; kt++){
    if (w < 2){
      #pragma unroll
      for (int j = 0; j < 16; j++){
        int r = rA + j*8;
        const unsigned char* s2 = (const unsigned char*)(aSrc + (size_t)(mb*128 + r)*DN)
                                  + kt*128 + ((cA ^ (r & 7)) << 4);
        gload16(s2, dpA + j*1024);
      }
    } else {
      const unsigned char* s2 = sbB + (size_t)kt*16384;
      #pragma unroll
      for (int j = 0; j < 16; j++) gload16(s2 + j*1024, dpB + j*1024);
    }
    __syncthreads();
    #pragma unroll
    for (int ks = 0; ks < 2; ks++){
      f16x8 ah[4], al[4], bh[4], bl[4];
      #pragma unroll
      for (int f = 0; f < 4; f++){
        int ra = wr*64 + f*16 + lr;
        int off = (ks*64 + lg*16) ^ ((ra & 7) << 4);
        ah[f] = *(const f16x8*)(Ah + ra*128 + off);
        al[f] = *(const f16x8*)(Al + ra*128 + off);
      }
      #pragma unroll
      for (int f = 0; f < 4; f++){
        int rb = wc*64 + f*16 + lr;
        int off = (ks*64 + lg*16) ^ ((rb & 7) << 4);
        bh[f] = *(const f16x8*)(Bh + rb*128 + off);
        bl[f] = *(const f16x8*)(Bl + rb*128 + off);
      }
      #pragma unroll
      for (int fm = 0; fm < 4; fm++)
      #pragma unroll
      for (int fn = 0; fn < 4; fn++){
        acc[fm][fn] = MFMA_F16(ah[fm], bh[fn], acc[fm][fn]);
        acc[fm][fn] = MFMA_F16(al[fm], bh[fn], acc[fm][fn]);
        acc[fm][fn] = MFMA_F16(ah[fm], bl[fn], acc[fm][fn]);
      }
    }
    __syncthreads();
  }
  #pragma unroll
  for (int fm = 0; fm < 4; fm++)
  #pragma unroll
  for (int fn = 0; fn < 4; fn++)
  #pragma unroll
  for (int rr = 0; rr < 4; rr++){
    int m = mb*128 + wr*64 + fm*16 + lg*4 + rr;
    int n = nb*128 + wc*64 + fn*16 + lr;
    size_t oi = (size_t)m*DN + n;
    out[oi] = x[oi] + acc[fm][fn][rr] * (1.0f/65536.0f) + bproj[n];
  }
}

// ---------------- router: LN2 (fp32) + logits + noisy top-2 + h2(bf16) ----------------
__global__ __launch_bounds__(256) void router_kernel(
    const float* __restrict__ x1, const float* __restrict__ g, const float* __restrict__ be,
    const float* __restrict__ Wr, const float* __restrict__ br,
    const float* __restrict__ Wn, const float* __restrict__ bn,
    const float* __restrict__ noise, unsigned short* __restrict__ h2bf,
    int* __restrict__ topk_e, float* __restrict__ topk_g, int* __restrict__ counts)
{
  const int token = blockIdx.x;
  const int t = threadIdx.x;
  __shared__ float redsum[4];
  __shared__ float red[64];
  float4 v = ((const float4*)(x1 + (size_t)token * DN))[t];
  float s = v.x + v.y + v.z + v.w;
  #pragma unroll
  for (int m = 32; m >= 1; m >>= 1) s += __shfl_xor(s, m);
  if ((t & 63) == 0) redsum[t >> 6] = s;
  __syncthreads();
  const float mu = (redsum[0] + redsum[1] + redsum[2] + redsum[3]) * (1.0f / DN);
  const float d0 = v.x - mu, d1 = v.y - mu, d2 = v.z - mu, d3 = v.w - mu;
  float s2 = d0*d0 + d1*d1 + d2*d2 + d3*d3;
  #pragma unroll
  for (int m = 32; m >= 1; m >>= 1) s2 += __shfl_xor(s2, m);
  __syncthreads();
  if ((t & 63) == 0) redsum[t >> 6] = s2;
  __syncthreads();
  const float var = (redsum[0] + redsum[1] + redsum[2] + redsum[3]) * (1.0f / DN);
  const float rs = 1.0f / sqrtf(var + 1e-5f);
  float4 gv = ((const float4*)g)[t];
  float4 bv = ((const float4*)be)[t];
  float h0 = d0*rs*gv.x + bv.x, h1v = d1*rs*gv.y + bv.y, h2v = d2*rs*gv.z + bv.z, h3 = d3*rs*gv.w + bv.w;
  ushort4 hb;
  hb.x = f2bf(h0); hb.y = f2bf(h1v); hb.z = f2bf(h2v); hb.w = f2bf(h3);
  *(ushort4*)(h2bf + (size_t)token*DN + t*4) = hb;
  float acc[16];
  const int j = t * 4;
  #pragma unroll
  for (int e = 0; e < 8; e++){
    acc[e]     = h0*Wr[(j+0)*8+e] + h1v*Wr[(j+1)*8+e] + h2v*Wr[(j+2)*8+e] + h3*Wr[(j+3)*8+e];
    acc[8 + e] = h0*Wn[(j+0)*8+e] + h1v*Wn[(j+1)*8+e] + h2v*Wn[(j+2)*8+e] + h3*Wn[(j+3)*8+e];
  }
  #pragma unroll
  for (int q = 0; q < 16; q++){
    #pragma unroll
    for (int m = 32; m >= 1; m >>= 1) acc[q] += __shfl_xor(acc[q], m);
  }
  if ((t & 63) == 0){
    #pragma unroll
    for (int q = 0; q < 16; q++) red[(t >> 6)*16 + q] = acc[q];
  }
  __syncthreads();
  if (t < 16) red[t] = red[t] + red[16 + t] + red[32 + t] + red[48 + t];
  __syncthreads();
  if (t == 0){
    float nz[8];
    #pragma unroll
    for (int e = 0; e < 8; e++){
      float logit = red[e] + br[e];
      float a = red[8 + e] + bn[e];
      float sp = (a > 20.0f) ? a : log1pf(expf(a));
      nz[e] = logit + noise[(size_t)token*EN + e] * sp;
    }
    float v1 = -INFINITY, v2 = -INFINITY; int i1 = 0, i2 = 0;
    #pragma unroll
    for (int e = 0; e < 8; e++){
      float z = nz[e];
      if (z > v1){ v2 = v1; i2 = i1; v1 = z; i1 = e; }
      else if (z > v2){ v2 = z; i2 = e; }
    }
    float e2 = expf(v2 - v1);
    float den = 1.0f + e2;
    topk_e[token*2]     = i1; topk_e[token*2 + 1] = i2;
    topk_g[token*2]     = 1.0f/den; topk_g[token*2 + 1] = e2/den;
    atomicAdd(&counts[i1], 1); atomicAdd(&counts[i2], 1);
  }
}

// 256-aligned expert segment offsets (moe tiles are 256 rows)
__global__ void scan_kernel(const int* __restrict__ counts, int* __restrict__ offs)
{
  if (threadIdx.x == 0 && blockIdx.x == 0){
    int a = 0;
    for (int e = 0; e < EN; e++){ offs[e] = a; a += (counts[e] + 255) & ~255; }
  }
}

__global__ __launch_bounds__(256) void scatter_kernel(
    const int* __restrict__ topk_e, const float* __restrict__ topk_g,
    const int* __restrict__ offs, int* __restrict__ fill,
    int* __restrict__ rows, float* __restrict__ grow)
{
  const int token = blockIdx.x*256 + threadIdx.x;
  #pragma unroll
  for (int i = 0; i < 2; i++){
    int e = topk_e[token*2 + i];
    int pos = offs[e] + atomicAdd(&fill[e], 1);
    rows[pos] = token;
    grow[pos] = topk_g[token*2 + i];
  }
}

// ---------------- expert weights -> 16KB LDS-image panels (bf16, swizzle baked) --------
__global__ __launch_bounds__(256) void wconv_kernel(
    const float* __restrict__ W1, const float* __restrict__ W2,
    unsigned char* __restrict__ w1p, unsigned char* __restrict__ w2p)
{
  int b = blockIdx.x;
  const float* W; unsigned char* pan; int Nd, kt, n;
  if (b < 2048){
    int e = b >> 8, rem = b & 255, nb2 = rem >> 4; kt = rem & 15;
    n = nb2*256 + threadIdx.x;                       // 0..4095
    W = W1 + (size_t)e * DN * DFN; Nd = DFN;
    pan = w1p + (((size_t)e*32 + (n >> 7))*16 + kt) * 16384;
  } else {
    b -= 2048;
    int e = b >> 8, rem = b & 255, nb2 = rem >> 6; kt = rem & 63;
    n = nb2*256 + threadIdx.x;                       // 0..1023
    W = W2 + (size_t)e * DFN * DN; Nd = DN;
    pan = w2p + (((size_t)e*8 + (n >> 7))*64 + kt) * 16384;
  }
  const int r = n & 127;
  #pragma unroll
  for (int kk8 = 0; kk8 < 8; kk8++){
    union { unsigned short u[8]; uint4 v; } buf;
    #pragma unroll
    for (int j = 0; j < 8; j++)
      buf.u[j] = f2bf(W[(size_t)(kt*64 + kk8*8 + j)*Nd + n]);
    *(uint4*)(pan + r*128 + ((kk8 ^ (r & 7)) << 4)) = buf.v;
  }
}

// ---------------- gather tokens into A panels: apnl[pb][kt16][16KB image] ----------------
__global__ __launch_bounds__(256) void agather_kernel(
    const unsigned short* __restrict__ h2bf, const int* __restrict__ rows,
    unsigned char* __restrict__ apnl)
{
  const int pb = blockIdx.x, kt = blockIdx.y;
  const int t = threadIdx.x;
  const int r = t >> 1, c0 = (t & 1) * 4;
  const int tok = rows[pb*128 + r];
  const unsigned char* src = (const unsigned char*)h2bf + (size_t)tok*2048 + kt*128;
  unsigned char* dst = apnl + ((size_t)pb*16 + kt)*16384 + r*128;
  #pragma unroll
  for (int i = 0; i < 4; i++){
    int c = c0 + i;
    *(uint4*)(dst + ((c ^ (r & 7)) << 4)) = *(const uint4*)(src + c*16);
  }
}

// ---------------- MoE GEMM1 (persistent, 2D-window, single-barrier, NT midP stores) ----
__global__ __launch_bounds__(512, 1) void moe1_kernel(
    const unsigned char* __restrict__ apnl, const unsigned char* __restrict__ w1p,
    const float* __restrict__ b1,
    const int* __restrict__ counts, const int* __restrict__ offs,
    unsigned short* __restrict__ midP)
{
  __shared__ __align__(16) unsigned char As[2][32768], Bs[2][32768];
  const int bid = blockIdx.x;
  const int t = threadIdx.x;
  const int w = t >> 6, lane = t & 63, lg = lane >> 4, lr = lane & 15;
  const int wm = w >> 2, wn = w & 3;
  const int sp = (w >> 1) & 1, sh = (w & 1) * 8192;
  const int e  = bid & 7;
  const int c  = bid >> 3;                 // CU slot within XCD, 0..31
  const int cnt = counts[e];
  const int off = offs[e];
  const int nmb = (cnt + 255) >> 8;
  const int nch = nmb * 16;
  for (int q = c; q < nch; q += 32){
    const int grp = q / (4*nmb);
    const int within = q - grp*4*nmb;
    const int mb = within >> 2;
    const int nb = grp*4 + (within & 3);   // 0..15 (256-col group)
    const int m0 = mb * 256;
    const int pb0 = (off + m0) >> 7;
    const unsigned char* sbase;
    unsigned char* dbase;
    if (w < 4){
      sbase = apnl + ((size_t)(pb0 + sp) * 16) * 16384 + sh + lane*16;
      dbase = &As[0][sp*16384 + sh];
    } else {
      sbase = w1p + ((size_t)(e*32 + nb*2 + sp) * 16) * 16384 + sh + lane*16;
      dbase = &Bs[0][sp*16384 + sh];
    }
    f32x4 acc[8][4] = {};
    auto stage = [&](int buf, int kt){
      const unsigned char* s2 = sbase + (size_t)kt * 16384;
      unsigned char* d = dbase + buf * 32768;
      #pragma unroll
      for (int j = 0; j < 8; j++) gload16(s2 + j*1024, d + j*1024);
    };
    auto compute = [&](int buf){
      const unsigned char* pA = &As[buf][wm*16384];
      const unsigned char* pB = &Bs[buf][(wn>>1)*16384];
      #pragma unroll
      for (int ks = 0; ks < 2; ks++){
        s16x8 b[4], a[8];
        #pragma unroll
        for (int f = 0; f < 4; f++){
          int rb = (wn&1)*64 + f*16 + lr;
          b[f] = *(const s16x8*)(pB + rb*128 + ((ks*64 + lg*16) ^ ((rb&7)<<4)));
        }
        #pragma unroll
        for (int f = 0; f < 8; f++){
          int ra = f*16 + lr;
          a[f] = *(const s16x8*)(pA + ra*128 + ((ks*64 + lg*16) ^ ((ra&7)<<4)));
        }
        #pragma unroll
        for (int fm = 0; fm < 8; fm++)
        #pragma unroll
        for (int fn = 0; fn < 4; fn++)
          acc[fm][fn] = MFMA_BF16(a[fm], b[fn], acc[fm][fn]);
      }
    };
    // T3-minimum single-barrier loop: stage(next) -> compute(cur) -> vmcnt(0)+barrier
    stage(0, 0);
    VMW_BAR(0);
    for (int kt = 0; kt < 16; kt += 2){
      stage(1, kt + 1);
      compute(0);
      VMW_BAR(0);
      if (kt + 2 < 16) stage(0, kt + 2);
      compute(1);
      VMW_BAR(0);
    }
    {
      unsigned char* Lp = ((wm == 0) ? (unsigned char*)As : (unsigned char*)Bs) + wn*16384;
      const float* b1e = b1 + (size_t)e*DFN + nb*256 + wn*64;
      #pragma unroll
      for (int fn = 0; fn < 4; fn++){
        float bias = b1e[fn*16 + lr];
        int col = fn*16 + lr;
        #pragma unroll
        for (int fm = 0; fm < 8; fm++)
        #pragma unroll
        for (int rr = 0; rr < 4; rr++){
          int r = fm*16 + lg*4 + rr;
          float v = fmaxf(acc[fm][fn][rr] + bias, 0.0f);
          *(unsigned short*)(Lp + r*128 + ((col ^ ((r & 7) << 3)) * 2)) = f2bf(v);
        }
      }
    }
    BAR();
    {
      int p = w >> 2, jj = w & 3;
      const u32x4* src = (const u32x4*)(((p == 0) ? (unsigned char*)As : (unsigned char*)Bs) + jj*16384);
      u32x4* dst = (u32x4*)((unsigned char*)midP + (((size_t)(pb0 + p)*64) + nb*4 + jj) * 16384);
      #pragma unroll
      for (int i = 0; i < 16; i++)
        __builtin_nontemporal_store(src[lane + i*64], &dst[lane + i*64]);
    }
    BAR();
  }
}

// ---------------- MoE GEMM2 (persistent, 2D-window, single-barrier, no setprio) --------
__global__ __launch_bounds__(512, 1) void moe2_kernel(
    const unsigned char* __restrict__ midP, const unsigned char* __restrict__ w2p,
    const float* __restrict__ b2,
    const int* __restrict__ counts, const int* __restrict__ offs,
    const int* __restrict__ rows, const float* __restrict__ grow,
    float* __restrict__ out)
{
  __shared__ __align__(16) unsigned char As[2][32768], Bs[2][32768];
  const int bid = blockIdx.x;
  const int t = threadIdx.x;
  const int w = t >> 6, lane = t & 63, lg = lane >> 4, lr = lane & 15;
  const int wm = w >> 2, wn = w & 3;
  const int sp = (w >> 1) & 1, sh = (w & 1) * 8192;
  const int e  = bid & 7;
  const int c  = bid >> 3;
  const int cnt = counts[e];
  const int off = offs[e];
  const int nmb = (cnt + 255) >> 8;
  const int nch = nmb * 4;
  for (int q = c; q < nch; q += 32){
    const int mb = q >> 2;
    const int nb = q & 3;
    const int m0 = mb * 256;
    const int pb0 = (off + m0) >> 7;
    const unsigned char* sbase;
    unsigned char* dbase;
    if (w < 4){
      sbase = midP + ((size_t)(pb0 + sp) * 64) * 16384 + sh + lane*16;
      dbase = &As[0][sp*16384 + sh];
    } else {
      sbase = w2p + ((size_t)(e*8 + nb*2 + sp) * 64) * 16384 + sh + lane*16;
      dbase = &Bs[0][sp*16384 + sh];
    }
    f32x4 acc[8][4] = {};
    auto stage = [&](int buf, int kt){
      const unsigned char* s2 = sbase + (size_t)kt * 16384;
      unsigned char* d = dbase + buf * 32768;
      #pragma unroll
      for (int j = 0; j < 8; j++) gload16(s2 + j*1024, d + j*1024);
    };
    auto compute = [&](int buf){
      const unsigned char* pA = &As[buf][wm*16384];
      const unsigned char* pB = &Bs[buf][(wn>>1)*16384];
      #pragma unroll
      for (int ks = 0; ks < 2; ks++){
        s16x8 b[4], a[8];
        #pragma unroll
        for (int f = 0; f < 4; f++){
          int rb = (wn&1)*64 + f*16 + lr;
          b[f] = *(const s16x8*)(pB + rb*128 + ((ks*64 + lg*16) ^ ((rb&7)<<4)));
        }
        #pragma unroll
        for (int f = 0; f < 8; f++){
          int ra = f*16 + lr;
          a[f] = *(const s16x8*)(pA + ra*128 + ((ks*64 + lg*16) ^ ((ra&7)<<4)));
        }
        #pragma unroll
        for (int fm = 0; fm < 8; fm++)
        #pragma unroll
        for (int fn = 0; fn < 4; fn++)
          acc[fm][fn] = MFMA_BF16(a[fm], b[fn], acc[fm][fn]);
      }
    };
    // T3-minimum single-barrier loop
    stage(0, 0);
    VMW_BAR(0);
    for (int kt = 0; kt < 64; kt += 2){
      stage(1, kt + 1);
      compute(0);
      VMW_BAR(0);
      if (kt + 2 < 64) stage(0, kt + 2);
      compute(1);
      VMW_BAR(0);
    }
    const float* b2e = b2 + (size_t)e*DN + nb*256 + wn*64;
    #pragma unroll
    for (int fm = 0; fm < 8; fm++)
    #pragma unroll
    for (int rr = 0; rr < 4; rr++){
      int ml = wm*128 + fm*16 + lg*4 + rr;
      if (m0 + ml < cnt){
        int gi = off + m0 + ml;
        int tok = rows[gi];
        float gt = grow[gi];
        #pragma unroll
        for (int fn = 0; fn < 4; fn++){
          int n = nb*256 + wn*64 + fn*16 + lr;
          atomicAdd(out + (size_t)tok*DN + n, gt*(acc[fm][fn][rr] + b2e[fn*16 + lr]));
        }
      }
    }
  }
}

// ---------------- launch ----------------
extern "C" void kernel_launch(void* const* d_in, const int* in_sizes, int n_in,
                              void* d_out, int out_size, void* d_ws, size_t ws_size,
                              hipStream_t stream) {
  (void)in_sizes; (void)n_in; (void)out_size; (void)ws_size;
  const float* x     = (const float*)d_in[0];
  const float* noise = (const float*)d_in[1];
  const float* Wq    = (const float*)d_in[2];
  const float* Wk    = (const float*)d_in[3];
  const float* Wv    = (const float*)d_in[4];
  const float* Wp    = (const float*)d_in[5];
  const float* bproj = (const float*)d_in[6];
  const float* ln1g  = (const float*)d_in[7];
  const float* ln1b  = (const float*)d_in[8];
  const float* ln2g  = (const float*)d_in[9];
  const float* ln2b  = (const float*)d_in[10];
  const float* Wr    = (const float*)d_in[11];
  const float* br    = (const float*)d_in[12];
  const float* Wn    = (const float*)d_in[13];
  const float* bn    = (const float*)d_in[14];
  const float* W1    = (const float*)d_in[15];
  const float* b1    = (const float*)d_in[16];
  const float* W2    = (const float*)d_in[17];
  const float* b2    = (const float*)d_in[18];
  float* out = (float*)d_out;

  char* w = (char*)d_ws;
  auto alloc = [&](size_t bytes) -> char* {
    char* p = w; w += (bytes + 255) & ~(size_t)255; return p;
  };
  // Region A: qkv split + o split during attention; reused as panelized `mid` during MoE.
  char* big = alloc((size_t)NPB * 64 * 16384);          // 151 MB >= 134.2 MB qkv need
  _Float16* qkvsplit = (_Float16*)big;
  _Float16* ohi = (_Float16*)(big + (size_t)6*NQ*2);
  _Float16* olo = ohi + NQ;
  unsigned short* midP = (unsigned short*)big;
  // Region B: attention temporaries (dead after proj); W1 panels overlay them afterwards.
  char* attn_tmp = w;
  unsigned char* aph = (unsigned char*)alloc((size_t)64*16*16384);   // h1 hi panels 16 MB
  unsigned char* apl = (unsigned char*)alloc((size_t)64*16*16384);   // h1 lo panels 16 MB
  unsigned char* bqh = (unsigned char*)alloc((size_t)24*16*16384);   // qkv W hi panels 6.3 MB
  unsigned char* bql = (unsigned char*)alloc((size_t)24*16*16384);
  unsigned char* bph = (unsigned char*)alloc((size_t)8*16*16384);    // proj W hi panels 2.1 MB
  unsigned char* bpl = (unsigned char*)alloc((size_t)8*16*16384);
  unsigned char* w1p = (unsigned char*)attn_tmp;        // 64 MiB panels overlay
  char* w1p_end = attn_tmp + (size_t)EN*DFN*DN*2;
  if (w < w1p_end) w = w1p_end;
  unsigned char* w2p = (unsigned char*)alloc((size_t)EN*DN*DFN*2);   // 64 MiB
  unsigned char* apnl = (unsigned char*)alloc((size_t)NPB*16*16384); // 37.7 MB
  unsigned short* h2bf = (unsigned short*)alloc((size_t)NTOK*DN*2);
  int*   topk_e = (int*)alloc(NTOK*2*sizeof(int));
  float* topk_g = (float*)alloc(NTOK*2*sizeof(float));
  int*   rowsA  = (int*)alloc((size_t)NPB*128*sizeof(int));
  float* growA  = (float*)alloc((size_t)NPB*128*sizeof(float));
  int*   cnts   = (int*)alloc(256);
  int*   fill   = cnts + 8;
  int*   offs   = cnts + 16;

  (void)hipMemsetAsync(cnts, 0, 64, stream);                  // counts + fill
  (void)hipMemsetAsync(rowsA, 0, (size_t)NPB*128*sizeof(int), stream);
  ln1_kernel<<<NTOK, 128, 0, stream>>>(x, ln1g, ln1b, aph, apl);
  wsplit_kernel<<<512, 256, 0, stream>>>(Wq, Wk, Wv, Wp, bqh, bql, bph, bpl);
  qkv_gemm_kernel<<<dim3(64, 24), 256, 0, stream>>>(aph, apl, bqh, bql, qkvsplit);
  attn_kernel<<<2048, 256, 0, stream>>>(qkvsplit, ohi, olo);
  proj_gemm_kernel<<<dim3(64, 8), 256, 0, stream>>>(ohi, olo, bph, bpl, x, bproj, out);
  // attn temporaries now dead -> overlay weight panels
  wconv_kernel<<<4096, 256, 0, stream>>>(W1, W2, w1p, w2p);
  router_kernel<<<NTOK, 256, 0, stream>>>(out, ln2g, ln2b, Wr, br, Wn, bn, noise,
                                          h2bf, topk_e, topk_g, cnts);
  scan_kernel<<<1, 64, 0, stream>>>(cnts, offs);
  scatter_kernel<<<NTOK/256, 256, 0, stream>>>(topk_e, topk_g, offs, fill, rowsA, growA);
  agather_kernel<<<dim3(NPB, 16), 256, 0, stream>>>(h2bf, rowsA, apnl);
  moe1_kernel<<<256, 512, 0, stream>>>(apnl, w1p, b1, cnts, offs, midP);
  moe2_kernel<<<256, 512, 0, stream>>>((const unsigned char*)midP, w2p, b2,
                                       cnts, offs, rowsA, growA, out);
}

// Round 22
// 1348.663 us; speedup vs baseline: 1.2101x; 1.0068x over previous
//
#include <hip/hip_runtime.h>
#include <hip/hip_bf16.h>
#include <math.h>

#define NTOK 8192
#define DN   1024
#define HN   16
#define HSN  64
#define EN   8
#define DFN  4096
#define TN   1024
#define NQ   8388608u   // B*T*D elements per q/k/v buffer
#define NPB  144        // max 128-row panels (16384 + 8*255 pad, 256-aligned segments)

typedef _Float16 f16x8 __attribute__((ext_vector_type(8)));
typedef _Float16 f16x4 __attribute__((ext_vector_type(4)));
typedef float    f32x4 __attribute__((ext_vector_type(4)));
typedef short    s16x8 __attribute__((ext_vector_type(8)));
typedef unsigned int u32x4 __attribute__((ext_vector_type(4)));

#define MFMA_F16(A,B,C)  __builtin_amdgcn_mfma_f32_16x16x32_f16((A),(B),(C),0,0,0)
#define MFMA_BF16(A,B,C) __builtin_amdgcn_mfma_f32_16x16x32_bf16((A),(B),(C),0,0,0)

__device__ __forceinline__ unsigned short f2bf(float f){
  union { float f; unsigned u; } v; v.f = f;
  unsigned r = v.u + 0x7fffu + ((v.u >> 16) & 1u);
  return (unsigned short)(r >> 16);
}
__device__ __forceinline__ void fsplit(float v, _Float16& hi, _Float16& lo){
  hi = (_Float16)v; lo = (_Float16)(v - (float)hi);
}
// async global->LDS, 16B per lane; LDS dest is wave-uniform base (+lane*16 implicit)
__device__ __forceinline__ void gload16(const void* g, void* l){
  __builtin_amdgcn_global_load_lds((const __attribute__((address_space(1))) unsigned int*)g,
                                   (__attribute__((address_space(3))) unsigned int*)l, 16, 0, 0);
}
#define BAR() __builtin_amdgcn_s_barrier()
#define VMW_BAR(N) do { \
  asm volatile("s_waitcnt vmcnt(" #N ")" ::: "memory"); \
  __builtin_amdgcn_s_barrier(); \
} while (0)

// ---------------- LN1: x -> h1 panel images (x64, hi/lo) ----------------
__global__ __launch_bounds__(128) void ln1_kernel(
    const float* __restrict__ x, const float* __restrict__ g, const float* __restrict__ be,
    unsigned char* __restrict__ aph, unsigned char* __restrict__ apl)
{
  const int row = blockIdx.x;
  const int t = threadIdx.x;             // 0..127, handles 8 cols
  __shared__ float red[2];
  float4 va = ((const float4*)(x + (size_t)row*DN))[t*2];
  float4 vb = ((const float4*)(x + (size_t)row*DN))[t*2+1];
  float s = va.x+va.y+va.z+va.w + vb.x+vb.y+vb.z+vb.w;
  #pragma unroll
  for (int m = 32; m >= 1; m >>= 1) s += __shfl_xor(s, m);
  if ((t & 63) == 0) red[t >> 6] = s;
  __syncthreads();
  const float mu = (red[0] + red[1]) * (1.0f / DN);
  float e[8] = { va.x-mu, va.y-mu, va.z-mu, va.w-mu, vb.x-mu, vb.y-mu, vb.z-mu, vb.w-mu };
  float s2 = 0.0f;
  #pragma unroll
  for (int i = 0; i < 8; i++) s2 += e[i]*e[i];
  #pragma unroll
  for (int m = 32; m >= 1; m >>= 1) s2 += __shfl_xor(s2, m);
  __syncthreads();
  if ((t & 63) == 0) red[t >> 6] = s2;
  __syncthreads();
  const float var = (red[0] + red[1]) * (1.0f / DN);
  const float rs = 1.0f / sqrtf(var + 1e-5f);
  float4 ga = ((const float4*)g)[t*2], gb = ((const float4*)g)[t*2+1];
  float4 ba = ((const float4*)be)[t*2], bb = ((const float4*)be)[t*2+1];
  float gg[8] = { ga.x,ga.y,ga.z,ga.w, gb.x,gb.y,gb.z,gb.w };
  float bbv[8] = { ba.x,ba.y,ba.z,ba.w, bb.x,bb.y,bb.z,bb.w };
  f16x8 hi8, lo8;
  #pragma unroll
  for (int i = 0; i < 8; i++){
    _Float16 hi, lo; fsplit((e[i]*rs*gg[i] + bbv[i]) * 64.0f, hi, lo);
    hi8[i] = hi; lo8[i] = lo;
  }
  const int pb = row >> 7, r = row & 127, kt = t >> 3, kk8 = t & 7;
  size_t po = ((size_t)(pb*16 + kt))*16384 + r*128 + (size_t)((kk8 ^ (r & 7)) << 4);
  *(f16x8*)(aph + po) = hi8;
  *(f16x8*)(apl + po) = lo8;
}

// ---------------- attention weights -> B panel images (x1024, hi/lo) ----------------
__global__ __launch_bounds__(256) void wsplit_kernel(
    const float* __restrict__ Wq, const float* __restrict__ Wk, const float* __restrict__ Wv,
    const float* __restrict__ Wp,
    unsigned char* __restrict__ bqh, unsigned char* __restrict__ bql,
    unsigned char* __restrict__ bph, unsigned char* __restrict__ bpl)
{
  int b = blockIdx.x;
  const int t = threadIdx.x;
  const int r = t & 127;
  const int c0 = (t >> 7) * 4;     // physical slots c0..c0+3
  if (b < 384){
    int nb = b >> 4, kt = b & 15;
    int n = nb*128 + r;
    int mat = n >> 10, h = (n >> 6) & 15, hs = n & 63;
    const float* W = (mat == 0) ? Wq : ((mat == 1) ? Wk : Wv);
    const float* src = W + (size_t)h*65536 + hs;     // + k*64
    unsigned char* ph = bqh + ((size_t)(nb*16 + kt))*16384 + r*128;
    unsigned char* pl = bql + ((size_t)(nb*16 + kt))*16384 + r*128;
    #pragma unroll
    for (int c = c0; c < c0 + 4; c++){
      int kk8 = c ^ (r & 7);
      f16x8 hi8, lo8;
      #pragma unroll
      for (int j = 0; j < 8; j++){
        _Float16 hi, lo; fsplit(src[(size_t)(kt*64 + kk8*8 + j)*64] * 1024.0f, hi, lo);
        hi8[j] = hi; lo8[j] = lo;
      }
      *(f16x8*)(ph + c*16) = hi8;
      *(f16x8*)(pl + c*16) = lo8;
    }
  } else {
    b -= 384;
    int nb = b >> 4, kt = b & 15;
    int n = nb*128 + r;
    unsigned char* ph = bph + ((size_t)(nb*16 + kt))*16384 + r*128;
    unsigned char* pl = bpl + ((size_t)(nb*16 + kt))*16384 + r*128;
    #pragma unroll
    for (int c = c0; c < c0 + 4; c++){
      int kk8 = c ^ (r & 7);
      f16x8 hi8, lo8;
      #pragma unroll
      for (int j = 0; j < 8; j++){
        _Float16 hi, lo; fsplit(Wp[(size_t)(kt*64 + kk8*8 + j)*DN + n] * 1024.0f, hi, lo);
        hi8[j] = hi; lo8[j] = lo;
      }
      *(f16x8*)(ph + c*16) = hi8;
      *(f16x8*)(pl + c*16) = lo8;
    }
  }
}

// ---------------- QKV GEMM: 128x128, fused 3-product split (one K pass) ----------------
// V (mat==2) is written TRANSPOSED: [b,h,hs,t] so attention can stage V^T vectorized.
__global__ __launch_bounds__(256) void qkv_gemm_kernel(
    const unsigned char* __restrict__ aph, const unsigned char* __restrict__ apl,
    const unsigned char* __restrict__ bqh, const unsigned char* __restrict__ bql,
    _Float16* __restrict__ qkvout)
{
  const int mb = blockIdx.x;    // 0..63
  const int nb = blockIdx.y;    // 0..23
  __shared__ __align__(16) unsigned char Ah[16384], Al[16384], Bh[16384], Bl[16384];
  const int t = threadIdx.x, w = t >> 6, lane = t & 63, lg = lane >> 4, lr = lane & 15;
  const int wr = w >> 1, wc = w & 1;
  const unsigned char* sb;
  unsigned char* dp;
  if (w == 0){ sb = aph + ((size_t)(mb*16))*16384; dp = Ah; }
  else if (w == 1){ sb = apl + ((size_t)(mb*16))*16384; dp = Al; }
  else if (w == 2){ sb = bqh + ((size_t)(nb*16))*16384; dp = Bh; }
  else { sb = bql + ((size_t)(nb*16))*16384; dp = Bl; }
  sb += lane*16;
  f32x4 acc[4][4] = {};
  for (int kt = 0; kt < 16; kt++){
    const unsigned char* s2 = sb + (size_t)kt*16384;
    #pragma unroll
    for (int j = 0; j < 16; j++) gload16(s2 + j*1024, dp + j*1024);
    __syncthreads();
    #pragma unroll
    for (int ks = 0; ks < 2; ks++){
      f16x8 ah[4], al[4], bh[4], bl[4];
      #pragma unroll
      for (int f = 0; f < 4; f++){
        int ra = wr*64 + f*16 + lr;
        int off = (ks*64 + lg*16) ^ ((ra & 7) << 4);
        ah[f] = *(const f16x8*)(Ah + ra*128 + off);
        al[f] = *(const f16x8*)(Al + ra*128 + off);
      }
      #pragma unroll
      for (int f = 0; f < 4; f++){
        int rb = wc*64 + f*16 + lr;
        int off = (ks*64 + lg*16) ^ ((rb & 7) << 4);
        bh[f] = *(const f16x8*)(Bh + rb*128 + off);
        bl[f] = *(const f16x8*)(Bl + rb*128 + off);
      }
      #pragma unroll
      for (int fm = 0; fm < 4; fm++)
      #pragma unroll
      for (int fn = 0; fn < 4; fn++){
        acc[fm][fn] = MFMA_F16(ah[fm], bh[fn], acc[fm][fn]);
        acc[fm][fn] = MFMA_F16(al[fm], bh[fn], acc[fm][fn]);
        acc[fm][fn] = MFMA_F16(ah[fm], bl[fn], acc[fm][fn]);
      }
    }
    __syncthreads();
  }
  #pragma unroll
  for (int fm = 0; fm < 4; fm++)
  #pragma unroll
  for (int fn = 0; fn < 4; fn++)
  #pragma unroll
  for (int rr = 0; rr < 4; rr++){
    int m = mb*128 + wr*64 + fm*16 + lg*4 + rr;
    int n = nb*128 + wc*64 + fn*16 + lr;
    int mat = n >> 10, h = (n >> 6) & 15, hs = n & 63;
    int bb = m >> 10, tt = m & 1023;
    _Float16* dsthi = qkvout + (size_t)mat * 2u * NQ;
    _Float16* dstlo = dsthi + NQ;
    size_t oi;
    if (mat == 2)  // V transposed: [b][h][hs][t]
      oi = (((size_t)(bb*HN + h))*HSN + hs)*TN + tt;
    else
      oi = (((size_t)(bb*HN + h))*TN + tt)*HSN + hs;
    _Float16 hi, lo; fsplit(acc[fm][fn][rr] * (1.0f/1024.0f), hi, lo);  // = 64*q
    dsthi[oi] = hi; dstlo[oi] = lo;
  }
}

// ---------------- flash attention (split f16, V^T input, XCD-grouped bh, LJF qt) -------
__global__ __launch_bounds__(256) void attn_kernel(
    const _Float16* __restrict__ qkv,
    _Float16* __restrict__ ohi_, _Float16* __restrict__ olo_)
{
  const _Float16* qhi = qkv;
  const _Float16* qlo = qkv + NQ;
  const _Float16* khi = qkv + 2u*NQ;
  const _Float16* klo = qkv + 3u*NQ;
  const _Float16* vhi = qkv + 4u*NQ;   // layout [b,h,hs,t]
  const _Float16* vlo = qkv + 5u*NQ;
  // XCD-locality permutation + longest-job-first over qt (causal imbalance: work ~ qt+1).
  const int id   = blockIdx.x;         // 0..2047
  const int xcd  = id & 7;
  const int slot = id >> 3;            // 0..255
  const int bh   = xcd*16 + (slot & 15);   // 0..127, bijective
  const int qt   = 15 - (slot >> 4);       // 15..0 — heavy blocks dispatched first
  const size_t base = (size_t)bh * TN * HSN;   // same element count for V^T
  const int t = threadIdx.x, wid = t >> 6, lane = t & 63, lg = lane >> 4, lr = lane & 15;
  __shared__ _Float16 Khi[64][72], Klo[64][72], Vthi[64][72], Vtlo[64][72], Phi[64][72], Plo[64][72];
  f16x8 qh[2], ql[2];
  {
    const int qrow = qt*64 + wid*16 + lr;
    const _Float16* qp  = qhi + base + (size_t)qrow*HSN;
    const _Float16* qpl = qlo + base + (size_t)qrow*HSN;
    #pragma unroll
    for (int c = 0; c < 2; c++){
      qh[c] = *(const f16x8*)(qp  + c*32 + lg*8);
      ql[c] = *(const f16x8*)(qpl + c*32 + lg*8);
    }
  }
  f32x4 oacc[4] = {};
  float mrow[4], lsum[4];
  #pragma unroll
  for (int r = 0; r < 4; r++){ mrow[r] = -INFINITY; lsum[r] = 0.0f; }
  const int sr = t >> 2, sc = (t & 3) * 16;
  const float sscale = 1.0f / (4096.0f * 32.0f);
  for (int kvt = 0; kvt <= qt; kvt++){
    {
      const size_t gr = base + (size_t)(kvt*64 + sr)*HSN + sc;
      *(f16x8*)&Khi[sr][sc]     = *(const f16x8*)(khi + gr);
      *(f16x8*)&Khi[sr][sc + 8] = *(const f16x8*)(khi + gr + 8);
      *(f16x8*)&Klo[sr][sc]     = *(const f16x8*)(klo + gr);
      *(f16x8*)&Klo[sr][sc + 8] = *(const f16x8*)(klo + gr + 8);
      // V^T: row sr = hs, cols = t within tile (vectorized, no transpose)
      const size_t gv = base + (size_t)sr*TN + kvt*64 + sc;
      *(f16x8*)&Vthi[sr][sc]     = *(const f16x8*)(vhi + gv);
      *(f16x8*)&Vthi[sr][sc + 8] = *(const f16x8*)(vhi + gv + 8);
      *(f16x8*)&Vtlo[sr][sc]     = *(const f16x8*)(vlo + gv);
      *(f16x8*)&Vtlo[sr][sc + 8] = *(const f16x8*)(vlo + gv + 8);
    }
    __syncthreads();
    f32x4 sacc[4] = {};
    #pragma unroll
    for (int c = 0; c < 2; c++)
    #pragma unroll
    for (int fn = 0; fn < 4; fn++){
      f16x8 kh = *(const f16x8*)&Khi[fn*16 + lr][c*32 + lg*8];
      f16x8 kl = *(const f16x8*)&Klo[fn*16 + lr][c*32 + lg*8];
      sacc[fn] = MFMA_F16(qh[c], kh, sacc[fn]);
      sacc[fn] = MFMA_F16(qh[c], kl, sacc[fn]);
      sacc[fn] = MFMA_F16(ql[c], kh, sacc[fn]);
    }
    float sv[4][4], pmax[4];
    #pragma unroll
    for (int r = 0; r < 4; r++) pmax[r] = -INFINITY;
    const int qg0 = qt*64 + wid*16 + lg*4;
    #pragma unroll
    for (int fn = 0; fn < 4; fn++)
    #pragma unroll
    for (int r = 0; r < 4; r++){
      float xv = sacc[fn][r] * sscale;
      int kvg = kvt*64 + fn*16 + lr;
      xv = (kvg <= qg0 + r) ? xv : -INFINITY;
      sv[fn][r] = xv;
      pmax[r] = fmaxf(pmax[r], xv);
    }
    #pragma unroll
    for (int r = 0; r < 4; r++){
      #pragma unroll
      for (int m = 1; m < 16; m <<= 1) pmax[r] = fmaxf(pmax[r], __shfl_xor(pmax[r], m));
    }
    float alpha[4], mnew[4], psum[4];
    #pragma unroll
    for (int r = 0; r < 4; r++){
      mnew[r] = fmaxf(mrow[r], pmax[r]);
      alpha[r] = __expf(mrow[r] - mnew[r]);
      psum[r] = 0.0f;
    }
    #pragma unroll
    for (int fn = 0; fn < 4; fn++)
    #pragma unroll
    for (int r = 0; r < 4; r++){
      float p = __expf(sv[fn][r] - mnew[r]);
      psum[r] += p;
      _Float16 hi, lo; fsplit(p * 512.0f, hi, lo);
      Phi[wid*16 + lg*4 + r][fn*16 + lr] = hi;
      Plo[wid*16 + lg*4 + r][fn*16 + lr] = lo;
    }
    #pragma unroll
    for (int r = 0; r < 4; r++){
      #pragma unroll
      for (int m = 1; m < 16; m <<= 1) psum[r] += __shfl_xor(psum[r], m);
      lsum[r] = lsum[r]*alpha[r] + psum[r];
      mrow[r] = mnew[r];
    }
    #pragma unroll
    for (int fn = 0; fn < 4; fn++)
    #pragma unroll
    for (int r = 0; r < 4; r++) oacc[fn][r] *= alpha[r];
    #pragma unroll
    for (int c2 = 0; c2 < 2; c2++){
      f16x8 ph = *(const f16x8*)&Phi[wid*16 + lr][c2*32 + lg*8];
      f16x8 pl = *(const f16x8*)&Plo[wid*16 + lr][c2*32 + lg*8];
      #pragma unroll
      for (int fn = 0; fn < 4; fn++){
        f16x8 vh = *(const f16x8*)&Vthi[fn*16 + lr][c2*32 + lg*8];
        f16x8 vl = *(const f16x8*)&Vtlo[fn*16 + lr][c2*32 + lg*8];
        oacc[fn] = MFMA_F16(ph, vh, oacc[fn]);
        oacc[fn] = MFMA_F16(ph, vl, oacc[fn]);
        oacc[fn] = MFMA_F16(pl, vh, oacc[fn]);
      }
    }
    __syncthreads();
  }
  const int bb = bh >> 4, hh = bh & 15;
  #pragma unroll
  for (int fn = 0; fn < 4; fn++)
  #pragma unroll
  for (int r = 0; r < 4; r++){
    float ov = oacc[fn][r] / (32768.0f * lsum[r]);   // 512*64 scale
    int m = qt*64 + wid*16 + lg*4 + r;
    size_t oi = ((size_t)(bb*TN + m))*DN + hh*HSN + fn*16 + lr;
    _Float16 hi, lo; fsplit(ov * 64.0f, hi, lo);
    ohi_[oi] = hi; olo_[oi] = lo;
  }
}

// ---------------- proj GEMM + residual: 128x128, fused 3-product split -----------------
__global__ __launch_bounds__(256) void proj_gemm_kernel(
    const _Float16* __restrict__ ohi, const _Float16* __restrict__ olo,
    const unsigned char* __restrict__ bph, const unsigned char* __restrict__ bpl,
    const float* __restrict__ x, const float* __restrict__ bproj,
    float* __restrict__ out)
{
  const int mb = blockIdx.x;    // 0..63
  const int nb = blockIdx.y;    // 0..7
  __shared__ __align__(16) unsigned char Ah[16384], Al[16384], Bh[16384], Bl[16384];
  const int t = threadIdx.x, w = t >> 6, lane = t & 63, lg = lane >> 4, lr = lane & 15;
  const int wr = w >> 1, wc = w & 1;
  f32x4 acc[4][4] = {};
  const unsigned char* sbB = ((w == 2) ? bph : bpl) + ((size_t)(nb*16))*16384 + lane*16;
  unsigned char* dpB = (w == 2) ? Bh : Bl;
  const _Float16* aSrc = (w == 0) ? ohi : olo;
  unsigned char* dpA = (w == 0) ? Ah : Al;
  const int rA = lane >> 3;          // + j*8
  const int cA = lane & 7;
  for (int kt = 0; kt < 16; kt++){
    if (w < 2){
      #pragma unroll
      for (int j = 0; j < 16; j++){
        int r = rA + j*8;
        const unsigned char* s2 = (const unsigned char*)(aSrc + (size_t)(mb*128 + r)*DN)
                                  + kt*128 + ((cA ^ (r & 7)) << 4);
        gload16(s2, dpA + j*1024);
      }
    } else {
      const unsigned char* s2 = sbB + (size_t)kt*16384;
      #pragma unroll
      for (int j = 0; j < 16; j++) gload16(s2 + j*1024, dpB + j*1024);
    }
    __syncthreads();
    #pragma unroll
    for (int ks = 0; ks < 2; ks++){
      f16x8 ah[4], al[4], bh[4], bl[4];
      #pragma unroll
      for (int f = 0; f < 4; f++){
        int ra = wr*64 + f*16 + lr;
        int off = (ks*64 + lg*16) ^ ((ra & 7) << 4);
        ah[f] = *(const f16x8*)(Ah + ra*128 + off);
        al[f] = *(const f16x8*)(Al + ra*128 + off);
      }
      #pragma unroll
      for (int f = 0; f < 4; f++){
        int rb = wc*64 + f*16 + lr;
        int off = (ks*64 + lg*16) ^ ((rb & 7) << 4);
        bh[f] = *(const f16x8*)(Bh + rb*128 + off);
        bl[f] = *(const f16x8*)(Bl + rb*128 + off);
      }
      #pragma unroll
      for (int fm = 0; fm < 4; fm++)
      #pragma unroll
      for (int fn = 0; fn < 4; fn++){
        acc[fm][fn] = MFMA_F16(ah[fm], bh[fn], acc[fm][fn]);
        acc[fm][fn] = MFMA_F16(al[fm], bh[fn], acc[fm][fn]);
        acc[fm][fn] = MFMA_F16(ah[fm], bl[fn], acc[fm][fn]);
      }
    }
    __syncthreads();
  }
  #pragma unroll
  for (int fm = 0; fm < 4; fm++)
  #pragma unroll
  for (int fn = 0; fn < 4; fn++)
  #pragma unroll
  for (int rr = 0; rr < 4; rr++){
    int m = mb*128 + wr*64 + fm*16 + lg*4 + rr;
    int n = nb*128 + wc*64 + fn*16 + lr;
    size_t oi = (size_t)m*DN + n;
    out[oi] = x[oi] + acc[fm][fn][rr] * (1.0f/65536.0f) + bproj[n];
  }
}

// ---------------- router: LN2 (fp32) + logits + noisy top-2 + h2(bf16) ----------------
__global__ __launch_bounds__(256) void router_kernel(
    const float* __restrict__ x1, const float* __restrict__ g, const float* __restrict__ be,
    const float* __restrict__ Wr, const float* __restrict__ br,
    const float* __restrict__ Wn, const float* __restrict__ bn,
    const float* __restrict__ noise, unsigned short* __restrict__ h2bf,
    int* __restrict__ topk_e, float* __restrict__ topk_g, int* __restrict__ counts)
{
  const int token = blockIdx.x;
  const int t = threadIdx.x;
  __shared__ float redsum[4];
  __shared__ float red[64];
  float4 v = ((const float4*)(x1 + (size_t)token * DN))[t];
  float s = v.x + v.y + v.z + v.w;
  #pragma unroll
  for (int m = 32; m >= 1; m >>= 1) s += __shfl_xor(s, m);
  if ((t & 63) == 0) redsum[t >> 6] = s;
  __syncthreads();
  const float mu = (redsum[0] + redsum[1] + redsum[2] + redsum[3]) * (1.0f / DN);
  const float d0 = v.x - mu, d1 = v.y - mu, d2 = v.z - mu, d3 = v.w - mu;
  float s2 = d0*d0 + d1*d1 + d2*d2 + d3*d3;
  #pragma unroll
  for (int m = 32; m >= 1; m >>= 1) s2 += __shfl_xor(s2, m);
  __syncthreads();
  if ((t & 63) == 0) redsum[t >> 6] = s2;
  __syncthreads();
  const float var = (redsum[0] + redsum[1] + redsum[2] + redsum[3]) * (1.0f / DN);
  const float rs = 1.0f / sqrtf(var + 1e-5f);
  float4 gv = ((const float4*)g)[t];
  float4 bv = ((const float4*)be)[t];
  float h0 = d0*rs*gv.x + bv.x, h1v = d1*rs*gv.y + bv.y, h2v = d2*rs*gv.z + bv.z, h3 = d3*rs*gv.w + bv.w;
  ushort4 hb;
  hb.x = f2bf(h0); hb.y = f2bf(h1v); hb.z = f2bf(h2v); hb.w = f2bf(h3);
  *(ushort4*)(h2bf + (size_t)token*DN + t*4) = hb;
  float acc[16];
  const int j = t * 4;
  #pragma unroll
  for (int e = 0; e < 8; e++){
    acc[e]     = h0*Wr[(j+0)*8+e] + h1v*Wr[(j+1)*8+e] + h2v*Wr[(j+2)*8+e] + h3*Wr[(j+3)*8+e];
    acc[8 + e] = h0*Wn[(j+0)*8+e] + h1v*Wn[(j+1)*8+e] + h2v*Wn[(j+2)*8+e] + h3*Wn[(j+3)*8+e];
  }
  #pragma unroll
  for (int q = 0; q < 16; q++){
    #pragma unroll
    for (int m = 32; m >= 1; m >>= 1) acc[q] += __shfl_xor(acc[q], m);
  }
  if ((t & 63) == 0){
    #pragma unroll
    for (int q = 0; q < 16; q++) red[(t >> 6)*16 + q] = acc[q];
  }
  __syncthreads();
  if (t < 16) red[t] = red[t] + red[16 + t] + red[32 + t] + red[48 + t];
  __syncthreads();
  if (t == 0){
    float nz[8];
    #pragma unroll
    for (int e = 0; e < 8; e++){
      float logit = red[e] + br[e];
      float a = red[8 + e] + bn[e];
      float sp = (a > 20.0f) ? a : log1pf(expf(a));
      nz[e] = logit + noise[(size_t)token*EN + e] * sp;
    }
    float v1 = -INFINITY, v2 = -INFINITY; int i1 = 0, i2 = 0;
    #pragma unroll
    for (int e = 0; e < 8; e++){
      float z = nz[e];
      if (z > v1){ v2 = v1; i2 = i1; v1 = z; i1 = e; }
      else if (z > v2){ v2 = z; i2 = e; }
    }
    float e2 = expf(v2 - v1);
    float den = 1.0f + e2;
    topk_e[token*2]     = i1; topk_e[token*2 + 1] = i2;
    topk_g[token*2]     = 1.0f/den; topk_g[token*2 + 1] = e2/den;
    atomicAdd(&counts[i1], 1); atomicAdd(&counts[i2], 1);
  }
}

// 256-aligned expert segment offsets (moe tiles are 256 rows)
__global__ void scan_kernel(const int* __restrict__ counts, int* __restrict__ offs)
{
  if (threadIdx.x == 0 && blockIdx.x == 0){
    int a = 0;
    for (int e = 0; e < EN; e++){ offs[e] = a; a += (counts[e] + 255) & ~255; }
  }
}

__global__ __launch_bounds__(256) void scatter_kernel(
    const int* __restrict__ topk_e, const float* __restrict__ topk_g,
    const int* __restrict__ offs, int* __restrict__ fill,
    int* __restrict__ rows, float* __restrict__ grow)
{
  const int token = blockIdx.x*256 + threadIdx.x;
  #pragma unroll
  for (int i = 0; i < 2; i++){
    int e = topk_e[token*2 + i];
    int pos = offs[e] + atomicAdd(&fill[e], 1);
    rows[pos] = token;
    grow[pos] = topk_g[token*2 + i];
  }
}

// ---------------- expert weights -> 16KB LDS-image panels (bf16, swizzle baked) --------
__global__ __launch_bounds__(256) void wconv_kernel(
    const float* __restrict__ W1, const float* __restrict__ W2,
    unsigned char* __restrict__ w1p, unsigned char* __restrict__ w2p)
{
  int b = blockIdx.x;
  const float* W; unsigned char* pan; int Nd, kt, n;
  if (b < 2048){
    int e = b >> 8, rem = b & 255, nb2 = rem >> 4; kt = rem & 15;
    n = nb2*256 + threadIdx.x;                       // 0..4095
    W = W1 + (size_t)e * DN * DFN; Nd = DFN;
    pan = w1p + (((size_t)e*32 + (n >> 7))*16 + kt) * 16384;
  } else {
    b -= 2048;
    int e = b >> 8, rem = b & 255, nb2 = rem >> 6; kt = rem & 63;
    n = nb2*256 + threadIdx.x;                       // 0..1023
    W = W2 + (size_t)e * DFN * DN; Nd = DN;
    pan = w2p + (((size_t)e*8 + (n >> 7))*64 + kt) * 16384;
  }
  const int r = n & 127;
  #pragma unroll
  for (int kk8 = 0; kk8 < 8; kk8++){
    union { unsigned short u[8]; uint4 v; } buf;
    #pragma unroll
    for (int j = 0; j < 8; j++)
      buf.u[j] = f2bf(W[(size_t)(kt*64 + kk8*8 + j)*Nd + n]);
    *(uint4*)(pan + r*128 + ((kk8 ^ (r & 7)) << 4)) = buf.v;
  }
}

// ---------------- gather tokens into A panels: apnl[pb][kt16][16KB image] ----------------
__global__ __launch_bounds__(256) void agather_kernel(
    const unsigned short* __restrict__ h2bf, const int* __restrict__ rows,
    unsigned char* __restrict__ apnl)
{
  const int pb = blockIdx.x, kt = blockIdx.y;
  const int t = threadIdx.x;
  const int r = t >> 1, c0 = (t & 1) * 4;
  const int tok = rows[pb*128 + r];
  const unsigned char* src = (const unsigned char*)h2bf + (size_t)tok*2048 + kt*128;
  unsigned char* dst = apnl + ((size_t)pb*16 + kt)*16384 + r*128;
  #pragma unroll
  for (int i = 0; i < 4; i++){
    int c = c0 + i;
    *(uint4*)(dst + ((c ^ (r & 7)) << 4)) = *(const uint4*)(src + c*16);
  }
}

// ---------------- MoE GEMM1 (persistent, 2D-window, single-barrier, NT midP stores) ----
__global__ __launch_bounds__(512, 1) void moe1_kernel(
    const unsigned char* __restrict__ apnl, const unsigned char* __restrict__ w1p,
    const float* __restrict__ b1,
    const int* __restrict__ counts, const int* __restrict__ offs,
    unsigned short* __restrict__ midP)
{
  __shared__ __align__(16) unsigned char As[2][32768], Bs[2][32768];
  const int bid = blockIdx.x;
  const int t = threadIdx.x;
  const int w = t >> 6, lane = t & 63, lg = lane >> 4, lr = lane & 15;
  const int wm = w >> 2, wn = w & 3;
  const int sp = (w >> 1) & 1, sh = (w & 1) * 8192;
  const int e  = bid & 7;
  const int c  = bid >> 3;                 // CU slot within XCD, 0..31
  const int cnt = counts[e];
  const int off = offs[e];
  const int nmb = (cnt + 255) >> 8;
  const int nch = nmb * 16;
  for (int q = c; q < nch; q += 32){
    const int grp = q / (4*nmb);
    const int within = q - grp*4*nmb;
    const int mb = within >> 2;
    const int nb = grp*4 + (within & 3);   // 0..15 (256-col group)
    const int m0 = mb * 256;
    const int pb0 = (off + m0) >> 7;
    const unsigned char* sbase;
    unsigned char* dbase;
    if (w < 4){
      sbase = apnl + ((size_t)(pb0 + sp) * 16) * 16384 + sh + lane*16;
      dbase = &As[0][sp*16384 + sh];
    } else {
      sbase = w1p + ((size_t)(e*32 + nb*2 + sp) * 16) * 16384 + sh + lane*16;
      dbase = &Bs[0][sp*16384 + sh];
    }
    f32x4 acc[8][4] = {};
    auto stage = [&](int buf, int kt){
      const unsigned char* s2 = sbase + (size_t)kt * 16384;
      unsigned char* d = dbase + buf * 32768;
      #pragma unroll
      for (int j = 0; j < 8; j++) gload16(s2 + j*1024, d + j*1024);
    };
    auto compute = [&](int buf){
      const unsigned char* pA = &As[buf][wm*16384];
      const unsigned char* pB = &Bs[buf][(wn>>1)*16384];
      #pragma unroll
      for (int ks = 0; ks < 2; ks++){
        s16x8 b[4], a[8];
        #pragma unroll
        for (int f = 0; f < 4; f++){
          int rb = (wn&1)*64 + f*16 + lr;
          b[f] = *(const s16x8*)(pB + rb*128 + ((ks*64 + lg*16) ^ ((rb&7)<<4)));
        }
        #pragma unroll
        for (int f = 0; f < 8; f++){
          int ra = f*16 + lr;
          a[f] = *(const s16x8*)(pA + ra*128 + ((ks*64 + lg*16) ^ ((ra&7)<<4)));
        }
        #pragma unroll
        for (int fm = 0; fm < 8; fm++)
        #pragma unroll
        for (int fn = 0; fn < 4; fn++)
          acc[fm][fn] = MFMA_BF16(a[fm], b[fn], acc[fm][fn]);
      }
    };
    // T3-minimum single-barrier loop: stage(next) -> compute(cur) -> vmcnt(0)+barrier
    stage(0, 0);
    VMW_BAR(0);
    for (int kt = 0; kt < 16; kt += 2){
      stage(1, kt + 1);
      compute(0);
      VMW_BAR(0);
      if (kt + 2 < 16) stage(0, kt + 2);
      compute(1);
      VMW_BAR(0);
    }
    {
      unsigned char* Lp = ((wm == 0) ? (unsigned char*)As : (unsigned char*)Bs) + wn*16384;
      const float* b1e = b1 + (size_t)e*DFN + nb*256 + wn*64;
      #pragma unroll
      for (int fn = 0; fn < 4; fn++){
        float bias = b1e[fn*16 + lr];
        int col = fn*16 + lr;
        #pragma unroll
        for (int fm = 0; fm < 8; fm++)
        #pragma unroll
        for (int rr = 0; rr < 4; rr++){
          int r = fm*16 + lg*4 + rr;
          float v = fmaxf(acc[fm][fn][rr] + bias, 0.0f);
          *(unsigned short*)(Lp + r*128 + ((col ^ ((r & 7) << 3)) * 2)) = f2bf(v);
        }
      }
    }
    BAR();
    {
      int p = w >> 2, jj = w & 3;
      const u32x4* src = (const u32x4*)(((p == 0) ? (unsigned char*)As : (unsigned char*)Bs) + jj*16384);
      u32x4* dst = (u32x4*)((unsigned char*)midP + (((size_t)(pb0 + p)*64) + nb*4 + jj) * 16384);
      #pragma unroll
      for (int i = 0; i < 16; i++)
        __builtin_nontemporal_store(src[lane + i*64], &dst[lane + i*64]);
    }
    BAR();
  }
}

// ---------------- MoE GEMM2 (persistent, 2D-window, single-barrier, no setprio) --------
__global__ __launch_bounds__(512, 1) void moe2_kernel(
    const unsigned char* __restrict__ midP, const unsigned char* __restrict__ w2p,
    const float* __restrict__ b2,
    const int* __restrict__ counts, const int* __restrict__ offs,
    const int* __restrict__ rows, const float* __restrict__ grow,
    float* __restrict__ out)
{
  __shared__ __align__(16) unsigned char As[2][32768], Bs[2][32768];
  const int bid = blockIdx.x;
  const int t = threadIdx.x;
  const int w = t >> 6, lane = t & 63, lg = lane >> 4, lr = lane & 15;
  const int wm = w >> 2, wn = w & 3;
  const int sp = (w >> 1) & 1, sh = (w & 1) * 8192;
  const int e  = bid & 7;
  const int c  = bid >> 3;
  const int cnt = counts[e];
  const int off = offs[e];
  const int nmb = (cnt + 255) >> 8;
  const int nch = nmb * 4;
  for (int q = c; q < nch; q += 32){
    const int mb = q >> 2;
    const int nb = q & 3;
    const int m0 = mb * 256;
    const int pb0 = (off + m0) >> 7;
    const unsigned char* sbase;
    unsigned char* dbase;
    if (w < 4){
      sbase = midP + ((size_t)(pb0 + sp) * 64) * 16384 + sh + lane*16;
      dbase = &As[0][sp*16384 + sh];
    } else {
      sbase = w2p + ((size_t)(e*8 + nb*2 + sp) * 64) * 16384 + sh + lane*16;
      dbase = &Bs[0][sp*16384 + sh];
    }
    f32x4 acc[8][4] = {};
    auto stage = [&](int buf, int kt){
      const unsigned char* s2 = sbase + (size_t)kt * 16384;
      unsigned char* d = dbase + buf * 32768;
      #pragma unroll
      for (int j = 0; j < 8; j++) gload16(s2 + j*1024, d + j*1024);
    };
    auto compute = [&](int buf){
      const unsigned char* pA = &As[buf][wm*16384];
      const unsigned char* pB = &Bs[buf][(wn>>1)*16384];
      #pragma unroll
      for (int ks = 0; ks < 2; ks++){
        s16x8 b[4], a[8];
        #pragma unroll
        for (int f = 0; f < 4; f++){
          int rb = (wn&1)*64 + f*16 + lr;
          b[f] = *(const s16x8*)(pB + rb*128 + ((ks*64 + lg*16) ^ ((rb&7)<<4)));
        }
        #pragma unroll
        for (int f = 0; f < 8; f++){
          int ra = f*16 + lr;
          a[f] = *(const s16x8*)(pA + ra*128 + ((ks*64 + lg*16) ^ ((ra&7)<<4)));
        }
        #pragma unroll
        for (int fm = 0; fm < 8; fm++)
        #pragma unroll
        for (int fn = 0; fn < 4; fn++)
          acc[fm][fn] = MFMA_BF16(a[fm], b[fn], acc[fm][fn]);
      }
    };
    // T3-minimum single-barrier loop
    stage(0, 0);
    VMW_BAR(0);
    for (int kt = 0; kt < 64; kt += 2){
      stage(1, kt + 1);
      compute(0);
      VMW_BAR(0);
      if (kt + 2 < 64) stage(0, kt + 2);
      compute(1);
      VMW_BAR(0);
    }
    const float* b2e = b2 + (size_t)e*DN + nb*256 + wn*64;
    #pragma unroll
    for (int fm = 0; fm < 8; fm++)
    #pragma unroll
    for (int rr = 0; rr < 4; rr++){
      int ml = wm*128 + fm*16 + lg*4 + rr;
      if (m0 + ml < cnt){
        int gi = off + m0 + ml;
        int tok = rows[gi];
        float gt = grow[gi];
        #pragma unroll
        for (int fn = 0; fn < 4; fn++){
          int n = nb*256 + wn*64 + fn*16 + lr;
          atomicAdd(out + (size_t)tok*DN + n, gt*(acc[fm][fn][rr] + b2e[fn*16 + lr]));
        }
      }
    }
  }
}

// ---------------- launch ----------------
extern "C" void kernel_launch(void* const* d_in, const int* in_sizes, int n_in,
                              void* d_out, int out_size, void* d_ws, size_t ws_size,
                              hipStream_t stream) {
  (void)in_sizes; (void)n_in; (void)out_size; (void)ws_size;
  const float* x     = (const float*)d_in[0];
  const float* noise = (const float*)d_in[1];
  const float* Wq    = (const float*)d_in[2];
  const float* Wk    = (const float*)d_in[3];
  const float* Wv    = (const float*)d_in[4];
  const float* Wp    = (const float*)d_in[5];
  const float* bproj = (const float*)d_in[6];
  const float* ln1g  = (const float*)d_in[7];
  const float* ln1b  = (const float*)d_in[8];
  const float* ln2g  = (const float*)d_in[9];
  const float* ln2b  = (const float*)d_in[10];
  const float* Wr    = (const float*)d_in[11];
  const float* br    = (const float*)d_in[12];
  const float* Wn    = (const float*)d_in[13];
  const float* bn    = (const float*)d_in[14];
  const float* W1    = (const float*)d_in[15];
  const float* b1    = (const float*)d_in[16];
  const float* W2    = (const float*)d_in[17];
  const float* b2    = (const float*)d_in[18];
  float* out = (float*)d_out;

  char* w = (char*)d_ws;
  auto alloc = [&](size_t bytes) -> char* {
    char* p = w; w += (bytes + 255) & ~(size_t)255; return p;
  };
  // Region A: qkv split + o split during attention; reused as panelized `mid` during MoE.
  char* big = alloc((size_t)NPB * 64 * 16384);          // 151 MB >= 134.2 MB qkv need
  _Float16* qkvsplit = (_Float16*)big;
  _Float16* ohi = (_Float16*)(big + (size_t)6*NQ*2);
  _Float16* olo = ohi + NQ;
  unsigned short* midP = (unsigned short*)big;
  // Region B: attention temporaries (dead after proj); W1 panels overlay them afterwards.
  char* attn_tmp = w;
  unsigned char* aph = (unsigned char*)alloc((size_t)64*16*16384);   // h1 hi panels 16 MB
  unsigned char* apl = (unsigned char*)alloc((size_t)64*16*16384);   // h1 lo panels 16 MB
  unsigned char* bqh = (unsigned char*)alloc((size_t)24*16*16384);   // qkv W hi panels 6.3 MB
  unsigned char* bql = (unsigned char*)alloc((size_t)24*16*16384);
  unsigned char* bph = (unsigned char*)alloc((size_t)8*16*16384);    // proj W hi panels 2.1 MB
  unsigned char* bpl = (unsigned char*)alloc((size_t)8*16*16384);
  unsigned char* w1p = (unsigned char*)attn_tmp;        // 64 MiB panels overlay
  char* w1p_end = attn_tmp + (size_t)EN*DFN*DN*2;
  if (w < w1p_end) w = w1p_end;
  unsigned char* w2p = (unsigned char*)alloc((size_t)EN*DN*DFN*2);   // 64 MiB
  unsigned char* apnl = (unsigned char*)alloc((size_t)NPB*16*16384); // 37.7 MB
  unsigned short* h2bf = (unsigned short*)alloc((size_t)NTOK*DN*2);
  int*   topk_e = (int*)alloc(NTOK*2*sizeof(int));
  float* topk_g = (float*)alloc(NTOK*2*sizeof(float));
  int*   rowsA  = (int*)alloc((size_t)NPB*128*sizeof(int));
  float* growA  = (float*)alloc((size_t)NPB*128*sizeof(float));
  int*   cnts   = (int*)alloc(256);
  int*   fill   = cnts + 8;
  int*   offs   = cnts + 16;

  (void)hipMemsetAsync(cnts, 0, 64, stream);                  // counts + fill
  (void)hipMemsetAsync(rowsA, 0, (size_t)NPB*128*sizeof(int), stream);
  ln1_kernel<<<NTOK, 128, 0, stream>>>(x, ln1g, ln1b, aph, apl);
  wsplit_kernel<<<512, 256, 0, stream>>>(Wq, Wk, Wv, Wp, bqh, bql, bph, bpl);
  qkv_gemm_kernel<<<dim3(64, 24), 256, 0, stream>>>(aph, apl, bqh, bql, qkvsplit);
  attn_kernel<<<2048, 256, 0, stream>>>(qkvsplit, ohi, olo);
  proj_gemm_kernel<<<dim3(64, 8), 256, 0, stream>>>(ohi, olo, bph, bpl, x, bproj, out);
  // attn temporaries now dead -> overlay weight panels
  wconv_kernel<<<4096, 256, 0, stream>>>(W1, W2, w1p, w2p);
  router_kernel<<<NTOK, 256, 0, stream>>>(out, ln2g, ln2b, Wr, br, Wn, bn, noise,
                                          h2bf, topk_e, topk_g, cnts);
  scan_kernel<<<1, 64, 0, stream>>>(cnts, offs);
  scatter_kernel<<<NTOK/256, 256, 0, stream>>>(topk_e, topk_g, offs, fill, rowsA, growA);
  agather_kernel<<<dim3(NPB, 16), 256, 0, stream>>>(h2bf, rowsA, apnl);
  moe1_kernel<<<256, 512, 0, stream>>>(apnl, w1p, b1, cnts, offs, midP);
  moe2_kernel<<<256, 512, 0, stream>>>((const unsigned char*)midP, w2p, b2,
                                       cnts, offs, rowsA, growA, out);
}